// Round 1
// baseline (1617.127 us; speedup 1.0000x reference)
//
#include <hip/hip_runtime.h>
#include <math.h>

// ---------------------------------------------------------------------------
// PointCloudPerceiverChannelsEncoder — round 0: correctness-first f32 pipeline
// B=8, N=8192, NDIM=2, WIDTH=128, HEADS=4 (dh=32), LATENT_D=128,
// N_POINT=128, N_SAMPLE=8, RADIUS=0.2, PATCH=8, MAX_DEG=15 (POS_DIM=62),
// SELF_LAYERS=3
// ---------------------------------------------------------------------------

namespace {

constexpr int BB = 8;
constexpr int NP = 8192;
constexpr int WD = 128;
constexpr int POSD = 62;
constexpr float R2C = 0.04f;                      // float(0.2**2)
constexpr float QSCALE = 0.17677669529663687f;    // 1/sqrt(32)
constexpr float HALFPI = 1.5707963705062866f;     // float(0.5*pi)

// ---------------- posenc + pe GEMM: emb[65536][128] -------------------------
__global__ __launch_bounds__(256) void k_posenc(
    const float* __restrict__ pts, const float* __restrict__ pew,
    const float* __restrict__ peb, float* __restrict__ emb) {
  __shared__ float pw[POSD * WD];    // 31744 floats
  __shared__ float pos[16][POSD];
  const int tid = threadIdx.x;
  const int base = blockIdx.x * 16;  // flat point index over B*N
  for (int i = tid; i < POSD * WD; i += 256) pw[i] = pew[i];
  for (int i = tid; i < 16 * POSD; i += 256) {
    int p = i / POSD, j = i % POSD;
    const float* pp = pts + (size_t)(base + p) * 2;
    float v;
    if (j < 2) {
      v = pp[j];
    } else if (j < 32) {
      int t = j - 2;
      v = sinf(pp[t & 1] * (float)(1 << (t >> 1)));
    } else {
      int t = j - 32;
      v = sinf(pp[t & 1] * (float)(1 << (t >> 1)) + HALFPI);
    }
    pos[p][j] = v;
  }
  __syncthreads();
  for (int i = tid; i < 16 * WD; i += 256) {
    int p = i >> 7, c = i & 127;
    float acc = peb[c];
#pragma unroll
    for (int j = 0; j < POSD; ++j) acc += pos[p][j] * pw[j * WD + c];
    emb[(size_t)(base + p) * WD + c] = acc;
  }
}

// ---------------- ball query: first 8 indices (ascending) within radius ----
__global__ __launch_bounds__(64) void k_ballquery(
    const float* __restrict__ pts, int* __restrict__ idxo) {
  const int blk = blockIdx.x;           // b*128 + i
  const int b = blk >> 7, i = blk & 127;
  const int lane = threadIdx.x;
  __shared__ int sidx[8];
  const float cx = pts[((size_t)b * NP + i) * 2];
  const float cy = pts[((size_t)b * NP + i) * 2 + 1];
  int cnt = 0;
  for (int j0 = 0; j0 < NP; j0 += 64) {
    int j = j0 + lane;
    float dx = pts[((size_t)b * NP + j) * 2] - cx;
    float dy = pts[((size_t)b * NP + j) * 2 + 1] - cy;
    // force plain f32 mul+add (no fma contraction) to match reference rounding
    float d2 = __fadd_rn(__fmul_rn(dx, dx), __fmul_rn(dy, dy));
    bool ok = !(d2 > R2C);
    unsigned long long m = __ballot(ok);
    int ord = cnt + __popcll(m & ((1ull << lane) - 1ull));
    if (ok && ord < 8) sidx[ord] = j;
    cnt += (int)__popcll(m);
    if (cnt >= 8) break;
  }
  __syncthreads();
  if (lane < 8) {
    int v = (lane < cnt) ? sidx[lane] : sidx[0];
    idxo[blk * 8 + lane] = v;
  }
}

// ---------------- gather + conv1 + conv2 + mean -> data_tokens -------------
__global__ __launch_bounds__(128) void k_gconv(
    const float* __restrict__ pts, const float* __restrict__ emb,
    const int* __restrict__ idxs, const float* __restrict__ w1,
    const float* __restrict__ b1, const float* __restrict__ w2,
    const float* __restrict__ b2, float* __restrict__ dtok) {
  const int blk = blockIdx.x;          // b*128 + i
  const int b = blk >> 7, i = blk & 127;
  const int c = threadIdx.x;           // out channel 0..127
  __shared__ float f[8][130];
  __shared__ float y1[9][128];
  __shared__ int sid[8];
  if (c < 8) sid[c] = idxs[blk * 8 + c];
  __syncthreads();
  for (int s = 0; s < 8; ++s) {
    int j = sid[s];
    f[s][2 + c] = emb[((size_t)b * NP + j) * WD + c];
    if (c < 2)
      f[s][c] = pts[((size_t)b * NP + j) * 2 + c] -
                pts[((size_t)b * NP + i) * 2 + c];
  }
  __syncthreads();
  // conv1: H 8 -> 9, circular pad 4: out[h] = sum_p w[p]*x[(h+p+4)&7]
  float acc[9];
  {
    float bb = b1[c];
#pragma unroll
    for (int h = 0; h < 9; ++h) acc[h] = bb;
  }
  for (int cin = 0; cin < 130; ++cin) {
    float fr[8];
#pragma unroll
    for (int s = 0; s < 8; ++s) fr[s] = f[s][cin];
    const float* wr = w1 + ((size_t)c * 130 + cin) * 8;
    float wv[8];
#pragma unroll
    for (int p = 0; p < 8; ++p) wv[p] = wr[p];
#pragma unroll
    for (int p = 0; p < 8; ++p)
#pragma unroll
      for (int h = 0; h < 9; ++h) acc[h] += wv[p] * fr[(h + p + 4) & 7];
  }
#pragma unroll
  for (int h = 0; h < 9; ++h) {
    float x = acc[h];
    y1[h][c] = x / (1.f + expf(-x));   // silu
  }
  __syncthreads();
  // conv2: H 9 -> 10, circular pad 4: out[h] = sum_p w[p]*x[(h+p-4) mod 9]
  float a2[10];
  {
    float bb = b2[c];
#pragma unroll
    for (int h = 0; h < 10; ++h) a2[h] = bb;
  }
  for (int cin = 0; cin < 128; ++cin) {
    float g[9];
#pragma unroll
    for (int s = 0; s < 9; ++s) g[s] = y1[s][cin];
    const float* wr = w2 + ((size_t)c * 128 + cin) * 8;
    float wv[8];
#pragma unroll
    for (int p = 0; p < 8; ++p) wv[p] = wr[p];
#pragma unroll
    for (int p = 0; p < 8; ++p)
#pragma unroll
      for (int h = 0; h < 10; ++h) a2[h] += wv[p] * g[(h + p + 5) % 9];
  }
  float s = 0.f;
#pragma unroll
  for (int h = 0; h < 10; ++h) {
    float x = a2[h];
    s += x / (1.f + expf(-x));
  }
  dtok[((size_t)b * 128 + i) * WD + c] = s / 10.0f;
}

// ---------------- concat(data_tokens, broadcast latents) -------------------
__global__ __launch_bounds__(128) void k_concat(
    const float* __restrict__ dtok, const float* __restrict__ otok,
    float* __restrict__ h0) {
  const int blk = blockIdx.x;          // b*256 + t
  const int b = blk >> 8, t = blk & 255, c = threadIdx.x;
  float v = (t < 128) ? dtok[((size_t)b * 128 + t) * WD + c]
                      : otok[(size_t)(t - 128) * WD + c];
  h0[(size_t)blk * WD + c] = v;
}

// ---------------- LayerNorm (width 128), optional strided source -----------
// srow = (row/keep)*(keep+skip) + skip + row%keep   (keep=rows,skip=0 => id)
__global__ __launch_bounds__(64) void k_ln(
    const float* __restrict__ src, float* __restrict__ dst,
    const float* __restrict__ g, const float* __restrict__ bta, int keep,
    int skip) {
  const int row = blockIdx.x;
  const int srow = (row / keep) * (keep + skip) + skip + (row % keep);
  const int lane = threadIdx.x;
  const float2 x2 = *(const float2*)(src + (size_t)srow * WD + lane * 2);
  float s = x2.x + x2.y;
  float sq = x2.x * x2.x + x2.y * x2.y;
#pragma unroll
  for (int o = 1; o < 64; o <<= 1) {
    s += __shfl_xor(s, o);
    sq += __shfl_xor(sq, o);
  }
  float m = s * (1.f / 128.f);
  float var = fmaxf(sq * (1.f / 128.f) - m * m, 0.f);
  float r = 1.0f / sqrtf(var + 1e-5f);
  int c = lane * 2;
  float2 o2;
  o2.x = (x2.x - m) * r * g[c] + bta[c];
  o2.y = (x2.y - m) * r * g[c + 1] + bta[c + 1];
  *(float2*)(dst + (size_t)row * WD + c) = o2;
}

// ---------------- fused LN + KV projection (65536 x 128 @ 128 x 256) -------
__global__ __launch_bounds__(256) void k_kvln(
    const float* __restrict__ emb, const float* __restrict__ g,
    const float* __restrict__ bt, const float* __restrict__ wkv,
    const float* __restrict__ bkv, float* __restrict__ kbuf,
    float* __restrict__ vbuf) {
  __shared__ float xn[64 * 129];
  const int tid = threadIdx.x;
  const size_t p0 = (size_t)blockIdx.x * 64;
  for (int i = tid; i < 64 * 128; i += 256) {
    int r = i >> 7, cc = i & 127;
    xn[r * 129 + cc] = emb[(p0 + r) * WD + cc];
  }
  __syncthreads();
  if (tid < 64) {
    float s = 0.f, sq = 0.f;
    for (int k2 = 0; k2 < 128; ++k2) {
      float v = xn[tid * 129 + k2];
      s += v;
      sq += v * v;
    }
    float m = s * (1.f / 128.f);
    float var = fmaxf(sq * (1.f / 128.f) - m * m, 0.f);
    float r = 1.f / sqrtf(var + 1e-5f);
    for (int k2 = 0; k2 < 128; ++k2)
      xn[tid * 129 + k2] = (xn[tid * 129 + k2] - m) * r * g[k2] + bt[k2];
  }
  __syncthreads();
  const int w = tid >> 6, l = tid & 63;
  float4 acc[16];
#pragma unroll
  for (int p = 0; p < 16; ++p) acc[p] = make_float4(0.f, 0.f, 0.f, 0.f);
  for (int k2 = 0; k2 < 128; ++k2) {
    float4 wv = *(const float4*)(wkv + (size_t)k2 * 256 + l * 4);
#pragma unroll
    for (int p = 0; p < 16; ++p) {
      float a = xn[(w * 16 + p) * 129 + k2];
      acc[p].x += a * wv.x;
      acc[p].y += a * wv.y;
      acc[p].z += a * wv.z;
      acc[p].w += a * wv.w;
    }
  }
  float4 bv = *(const float4*)(bkv + l * 4);
#pragma unroll
  for (int p = 0; p < 16; ++p) {
    float4 o;
    o.x = acc[p].x + bv.x;
    o.y = acc[p].y + bv.y;
    o.z = acc[p].z + bv.z;
    o.w = acc[p].w + bv.w;
    size_t row = p0 + w * 16 + p;
    if (l < 32)
      *(float4*)(kbuf + row * WD + l * 4) = o;
    else
      *(float4*)(vbuf + row * WD + (l - 32) * 4) = o;
  }
}

// ---------------- flash-style attention, Tq=256, heads=4, dh=32 ------------
// grid = B*4*8 (8 q-tiles of 32); block = 256
__global__ __launch_bounds__(256) void k_attn(
    const float* __restrict__ Q, int qs, const float* __restrict__ K, int ks,
    const float* __restrict__ V, int vs, float* __restrict__ O, int Tk) {
  const int bx = blockIdx.x;
  const int qt = bx & 7, h = (bx >> 3) & 3, b = bx >> 5;
  const int tid = threadIdx.x;
  __shared__ float4 vlds4[64 * 9];     // row stride 36 floats (16B aligned)
  __shared__ float qlds[32 * 33];
  __shared__ float klds[64 * 33];
  __shared__ float plds[32 * 66];
  for (int i = tid; i < 32 * 32; i += 256) {
    int r = i >> 5, d = i & 31;
    qlds[r * 33 + d] =
        Q[(size_t)(b * 256 + qt * 32 + r) * qs + h * 32 + d] * QSCALE;
  }
  __syncthreads();
  const int qq = tid >> 3, g = tid & 7;
  float qreg[32];
#pragma unroll
  for (int d = 0; d < 32; ++d) qreg[d] = qlds[qq * 33 + d];
  float4 o4 = make_float4(0.f, 0.f, 0.f, 0.f);
  float mrun = -1e30f, lrun = 0.f;
  for (int kt = 0; kt < Tk; kt += 64) {
    __syncthreads();  // previous tile fully consumed
    for (int i = tid; i < 64 * 32; i += 256) {
      int r = i >> 5, d = i & 31;
      klds[r * 33 + d] = K[(size_t)(b * Tk + kt + r) * ks + h * 32 + d];
      ((float*)vlds4)[r * 36 + d] = V[(size_t)(b * Tk + kt + r) * vs + h * 32 + d];
    }
    __syncthreads();
    float sc[8];
#pragma unroll
    for (int jj = 0; jj < 8; ++jj) {
      int kk = g * 8 + jj;
      float s = 0.f;
#pragma unroll
      for (int d = 0; d < 32; ++d) s += qreg[d] * klds[kk * 33 + d];
      sc[jj] = s;
    }
    float tm = sc[0];
#pragma unroll
    for (int jj = 1; jj < 8; ++jj) tm = fmaxf(tm, sc[jj]);
    tm = fmaxf(tm, __shfl_xor(tm, 1));
    tm = fmaxf(tm, __shfl_xor(tm, 2));
    tm = fmaxf(tm, __shfl_xor(tm, 4));
    float mnew = fmaxf(mrun, tm);
    float alpha = expf(mrun - mnew);
    float psum = 0.f;
#pragma unroll
    for (int jj = 0; jj < 8; ++jj) {
      float p = expf(sc[jj] - mnew);
      plds[qq * 66 + g * 8 + jj] = p;
      psum += p;
    }
    psum += __shfl_xor(psum, 1);
    psum += __shfl_xor(psum, 2);
    psum += __shfl_xor(psum, 4);
    lrun = lrun * alpha + psum;
    mrun = mnew;
    o4.x *= alpha;
    o4.y *= alpha;
    o4.z *= alpha;
    o4.w *= alpha;
    __syncthreads();  // plds visible
    for (int k2 = 0; k2 < 64; ++k2) {
      float p = plds[qq * 66 + k2];
      float4 vv = vlds4[k2 * 9 + g];
      o4.x += p * vv.x;
      o4.y += p * vv.y;
      o4.z += p * vv.z;
      o4.w += p * vv.w;
    }
  }
  float inv = 1.f / lrun;
  size_t orow = (size_t)(b * 256 + qt * 32 + qq);
  float4 res = make_float4(o4.x * inv, o4.y * inv, o4.z * inv, o4.w * inv);
  *(float4*)(O + orow * WD + h * 32 + g * 4) = res;
}

// ---------------- generic GEMM: D[M,N] = act(A[M,K] @ W[K,N] + bias) + res -
// grid = M/32, block = 256; NV = N/64; act: 0 none, 1 gelu(exact), 2 tanh
template <int NV>
__global__ __launch_bounds__(256) void k_gemm(
    const float* __restrict__ A, int lda, const float* __restrict__ Wt,
    const float* __restrict__ bias, const float* __restrict__ res, int ldres,
    float* __restrict__ D, int ldd, int K, int act) {
  __shared__ float alds[32 * 132];
  const int tid = threadIdx.x;
  const int row0 = blockIdx.x * 32;
  const int w = tid >> 6, l = tid & 63;
  constexpr int N = NV * 64;
  float acc[8][NV];
#pragma unroll
  for (int r = 0; r < 8; ++r)
#pragma unroll
    for (int j = 0; j < NV; ++j) acc[r][j] = 0.f;
  for (int kt = 0; kt < K; kt += 128) {
    __syncthreads();
    for (int i = tid; i < 32 * 128; i += 256) {
      int r = i >> 7, cc = i & 127;
      alds[r * 132 + cc] = A[(size_t)(row0 + r) * lda + kt + cc];
    }
    __syncthreads();
    for (int k2 = 0; k2 < 128; ++k2) {
      float wv[NV];
#pragma unroll
      for (int j = 0; j < NV; ++j) wv[j] = Wt[(size_t)(kt + k2) * N + l + 64 * j];
#pragma unroll
      for (int r = 0; r < 8; ++r) {
        float a = alds[(w * 8 + r) * 132 + k2];
#pragma unroll
        for (int j = 0; j < NV; ++j) acc[r][j] += a * wv[j];
      }
    }
  }
#pragma unroll
  for (int r = 0; r < 8; ++r) {
    size_t row = row0 + w * 8 + r;
#pragma unroll
    for (int j = 0; j < NV; ++j) {
      int col = l + 64 * j;
      float x = acc[r][j] + bias[col];
      if (act == 1) x = 0.5f * x * (1.0f + erff(x * 0.7071067811865476f));
      else if (act == 2) x = tanhf(x);
      if (res != nullptr) x += res[row * ldres + col];
      D[row * ldd + col] = x;
    }
  }
}

}  // namespace

// ---------------------------------------------------------------------------
extern "C" void kernel_launch(void* const* d_in, const int* in_sizes, int n_in,
                              void* d_out, int out_size, void* d_ws,
                              size_t ws_size, hipStream_t stream) {
  const float* pts      = (const float*)d_in[0];
  const float* pe_w     = (const float*)d_in[1];
  const float* pe_b     = (const float*)d_in[2];
  const float* conv1_w  = (const float*)d_in[3];
  const float* conv1_b  = (const float*)d_in[4];
  const float* conv2_w  = (const float*)d_in[5];
  const float* conv2_b  = (const float*)d_in[6];
  const float* otok     = (const float*)d_in[7];
  const float* ln_pre_s = (const float*)d_in[8];
  const float* ln_pre_b = (const float*)d_in[9];
  const float* c_ln1_s  = (const float*)d_in[10];
  const float* c_ln1_b  = (const float*)d_in[11];
  const float* c_ln2_s  = (const float*)d_in[12];
  const float* c_ln2_b  = (const float*)d_in[13];
  const float* c_q_w    = (const float*)d_in[14];
  const float* c_q_b    = (const float*)d_in[15];
  const float* c_kv_w   = (const float*)d_in[16];
  const float* c_kv_b   = (const float*)d_in[17];
  const float* c_proj_w = (const float*)d_in[18];
  const float* c_proj_b = (const float*)d_in[19];
  const float* c_ln3_s  = (const float*)d_in[20];
  const float* c_ln3_b  = (const float*)d_in[21];
  const float* c_mlp1_w = (const float*)d_in[22];
  const float* c_mlp1_b = (const float*)d_in[23];
  const float* c_mlp2_w = (const float*)d_in[24];
  const float* c_mlp2_b = (const float*)d_in[25];
  const float* s_ln1_s  = (const float*)d_in[26];
  const float* s_ln1_b  = (const float*)d_in[27];
  const float* s_qkv_w  = (const float*)d_in[28];
  const float* s_qkv_b  = (const float*)d_in[29];
  const float* s_proj_w = (const float*)d_in[30];
  const float* s_proj_b = (const float*)d_in[31];
  const float* s_ln2_s  = (const float*)d_in[32];
  const float* s_ln2_b  = (const float*)d_in[33];
  const float* s_mlp1_w = (const float*)d_in[34];
  const float* s_mlp1_b = (const float*)d_in[35];
  const float* s_mlp2_w = (const float*)d_in[36];
  const float* s_mlp2_b = (const float*)d_in[37];
  const float* lnpost_s = (const float*)d_in[38];
  const float* lnpost_b = (const float*)d_in[39];
  const float* out_w    = (const float*)d_in[40];
  const float* out_b    = (const float*)d_in[41];

  char* ws = (char*)d_ws;
  constexpr size_t SZ_EMB = (size_t)65536 * 128 * 4;  // 32 MB
  float* emb  = (float*)(ws);
  float* kbuf = (float*)(ws + SZ_EMB);
  float* vbuf = (float*)(ws + 2 * SZ_EMB);
  int*   idx  = (int*)(ws + 3 * SZ_EMB);
  float* dtok = (float*)(ws + 3 * SZ_EMB + 65536);
  float* hbuf = (float*)(ws + 3 * SZ_EMB + 65536 + 524288);
  float* tmp  = (float*)(ws + 3 * SZ_EMB + 65536 + 524288 + 1048576);
  float* qbuf = (float*)(ws + 3 * SZ_EMB + 65536 + 524288 + 2 * 1048576);
  float* att  = (float*)(ws + 3 * SZ_EMB + 65536 + 524288 + 3 * 1048576);
  float* mid  = (float*)(ws + 3 * SZ_EMB + 65536 + 524288 + 4 * 1048576);
  float* qkv  = (float*)(ws + 3 * SZ_EMB + 65536 + 524288 + 4 * 1048576 + 4194304);

  // 1) dataset_emb
  k_posenc<<<4096, 256, 0, stream>>>(pts, pe_w, pe_b, emb);
  // 2) ball query
  k_ballquery<<<1024, 64, 0, stream>>>(pts, idx);
  // 3) gather + conv stack -> data_tokens
  k_gconv<<<1024, 128, 0, stream>>>(pts, emb, idx, conv1_w, conv1_b, conv2_w,
                                    conv2_b, dtok);
  // 4) concat + ln_pre -> h
  k_concat<<<2048, 128, 0, stream>>>(dtok, otok, tmp);
  k_ln<<<2048, 64, 0, stream>>>(tmp, hbuf, ln_pre_s, ln_pre_b, 2048, 0);
  // 5) K,V from dataset_emb (fused LN)
  k_kvln<<<1024, 256, 0, stream>>>(emb, c_ln2_s, c_ln2_b, c_kv_w, c_kv_b, kbuf,
                                   vbuf);
  // 6) cross attention block
  k_ln<<<2048, 64, 0, stream>>>(hbuf, tmp, c_ln1_s, c_ln1_b, 2048, 0);
  k_gemm<2><<<64, 256, 0, stream>>>(tmp, 128, c_q_w, c_q_b, nullptr, 0, qbuf,
                                    128, 128, 0);
  k_attn<<<256, 256, 0, stream>>>(qbuf, 128, kbuf, 128, vbuf, 128, att, 8192);
  k_gemm<2><<<64, 256, 0, stream>>>(att, 128, c_proj_w, c_proj_b, hbuf, 128,
                                    hbuf, 128, 128, 0);
  k_ln<<<2048, 64, 0, stream>>>(hbuf, tmp, c_ln3_s, c_ln3_b, 2048, 0);
  k_gemm<8><<<64, 256, 0, stream>>>(tmp, 128, c_mlp1_w, c_mlp1_b, nullptr, 0,
                                    mid, 512, 128, 1);
  k_gemm<2><<<64, 256, 0, stream>>>(mid, 512, c_mlp2_w, c_mlp2_b, hbuf, 128,
                                    hbuf, 128, 512, 0);
  // 7) self-attention blocks
  for (int i = 0; i < 3; ++i) {
    k_ln<<<2048, 64, 0, stream>>>(hbuf, tmp, s_ln1_s + i * 128,
                                  s_ln1_b + i * 128, 2048, 0);
    k_gemm<6><<<64, 256, 0, stream>>>(tmp, 128, s_qkv_w + (size_t)i * 128 * 384,
                                      s_qkv_b + i * 384, nullptr, 0, qkv, 384,
                                      128, 0);
    k_attn<<<256, 256, 0, stream>>>(qkv, 384, qkv + 128, 384, qkv + 256, 384,
                                    att, 256);
    k_gemm<2><<<64, 256, 0, stream>>>(att, 128, s_proj_w + (size_t)i * 16384,
                                      s_proj_b + i * 128, hbuf, 128, hbuf, 128,
                                      128, 0);
    k_ln<<<2048, 64, 0, stream>>>(hbuf, tmp, s_ln2_s + i * 128,
                                  s_ln2_b + i * 128, 2048, 0);
    k_gemm<8><<<64, 256, 0, stream>>>(tmp, 128, s_mlp1_w + (size_t)i * 65536,
                                      s_mlp1_b + i * 512, nullptr, 0, mid, 512,
                                      128, 1);
    k_gemm<2><<<64, 256, 0, stream>>>(mid, 512, s_mlp2_w + (size_t)i * 65536,
                                      s_mlp2_b + i * 128, hbuf, 128, hbuf, 128,
                                      512, 0);
  }
  // 8) final LN (last 128 tokens) + output head with tanh
  k_ln<<<1024, 64, 0, stream>>>(hbuf, tmp, lnpost_s, lnpost_b, 128, 128);
  k_gemm<2><<<32, 256, 0, stream>>>(tmp, 128, out_w, out_b, nullptr, 0,
                                    (float*)d_out, 128, 128, 2);
}

// Round 2
// 1233.220 us; speedup vs baseline: 1.3113x; 1.3113x over previous
//
#include <hip/hip_runtime.h>
#include <math.h>

// ---------------------------------------------------------------------------
// PointCloudPerceiverChannelsEncoder — round 1: split-K flash attention
// (cross-attn was 710us at 12% occupancy: 256 blocks = 1 wave/SIMD. Split the
//  8192-key axis into 16 chunks -> 4096 blocks, then combine partials.)
// ---------------------------------------------------------------------------

namespace {

constexpr int BB = 8;
constexpr int NP = 8192;
constexpr int WD = 128;
constexpr int POSD = 62;
constexpr float R2C = 0.04f;                      // float(0.2**2)
constexpr float QSCALE = 0.17677669529663687f;    // 1/sqrt(32)
constexpr float HALFPI = 1.5707963705062866f;     // float(0.5*pi)

// ---------------- posenc + pe GEMM: emb[65536][128] -------------------------
__global__ __launch_bounds__(256) void k_posenc(
    const float* __restrict__ pts, const float* __restrict__ pew,
    const float* __restrict__ peb, float* __restrict__ emb) {
  __shared__ float pw[POSD * WD];    // 31744 floats
  __shared__ float pos[16][POSD];
  const int tid = threadIdx.x;
  const int base = blockIdx.x * 16;  // flat point index over B*N
  for (int i = tid; i < POSD * WD; i += 256) pw[i] = pew[i];
  for (int i = tid; i < 16 * POSD; i += 256) {
    int p = i / POSD, j = i % POSD;
    const float* pp = pts + (size_t)(base + p) * 2;
    float v;
    if (j < 2) {
      v = pp[j];
    } else if (j < 32) {
      int t = j - 2;
      v = sinf(pp[t & 1] * (float)(1 << (t >> 1)));
    } else {
      int t = j - 32;
      v = sinf(pp[t & 1] * (float)(1 << (t >> 1)) + HALFPI);
    }
    pos[p][j] = v;
  }
  __syncthreads();
  for (int i = tid; i < 16 * WD; i += 256) {
    int p = i >> 7, c = i & 127;
    float acc = peb[c];
#pragma unroll
    for (int j = 0; j < POSD; ++j) acc += pos[p][j] * pw[j * WD + c];
    emb[(size_t)(base + p) * WD + c] = acc;
  }
}

// ---------------- ball query: first 8 indices (ascending) within radius ----
__global__ __launch_bounds__(64) void k_ballquery(
    const float* __restrict__ pts, int* __restrict__ idxo) {
  const int blk = blockIdx.x;           // b*128 + i
  const int b = blk >> 7, i = blk & 127;
  const int lane = threadIdx.x;
  __shared__ int sidx[8];
  const float cx = pts[((size_t)b * NP + i) * 2];
  const float cy = pts[((size_t)b * NP + i) * 2 + 1];
  int cnt = 0;
  for (int j0 = 0; j0 < NP; j0 += 64) {
    int j = j0 + lane;
    float dx = pts[((size_t)b * NP + j) * 2] - cx;
    float dy = pts[((size_t)b * NP + j) * 2 + 1] - cy;
    float d2 = __fadd_rn(__fmul_rn(dx, dx), __fmul_rn(dy, dy));
    bool ok = !(d2 > R2C);
    unsigned long long m = __ballot(ok);
    int ord = cnt + __popcll(m & ((1ull << lane) - 1ull));
    if (ok && ord < 8) sidx[ord] = j;
    cnt += (int)__popcll(m);
    if (cnt >= 8) break;
  }
  __syncthreads();
  if (lane < 8) {
    int v = (lane < cnt) ? sidx[lane] : sidx[0];
    idxo[blk * 8 + lane] = v;
  }
}

// ---------------- gather + conv1 + conv2 + mean -> data_tokens -------------
__global__ __launch_bounds__(128) void k_gconv(
    const float* __restrict__ pts, const float* __restrict__ emb,
    const int* __restrict__ idxs, const float* __restrict__ w1,
    const float* __restrict__ b1, const float* __restrict__ w2,
    const float* __restrict__ b2, float* __restrict__ dtok) {
  const int blk = blockIdx.x;          // b*128 + i
  const int b = blk >> 7, i = blk & 127;
  const int c = threadIdx.x;           // out channel 0..127
  __shared__ float f[8][130];
  __shared__ float y1[9][128];
  __shared__ int sid[8];
  if (c < 8) sid[c] = idxs[blk * 8 + c];
  __syncthreads();
  for (int s = 0; s < 8; ++s) {
    int j = sid[s];
    f[s][2 + c] = emb[((size_t)b * NP + j) * WD + c];
    if (c < 2)
      f[s][c] = pts[((size_t)b * NP + j) * 2 + c] -
                pts[((size_t)b * NP + i) * 2 + c];
  }
  __syncthreads();
  // conv1: H 8 -> 9, circular pad 4: out[h] = sum_p w[p]*x[(h+p+4)&7]
  float acc[9];
  {
    float bb = b1[c];
#pragma unroll
    for (int h = 0; h < 9; ++h) acc[h] = bb;
  }
  for (int cin = 0; cin < 130; ++cin) {
    float fr[8];
#pragma unroll
    for (int s = 0; s < 8; ++s) fr[s] = f[s][cin];
    const float* wr = w1 + ((size_t)c * 130 + cin) * 8;
    float wv[8];
#pragma unroll
    for (int p = 0; p < 8; ++p) wv[p] = wr[p];
#pragma unroll
    for (int p = 0; p < 8; ++p)
#pragma unroll
      for (int h = 0; h < 9; ++h) acc[h] += wv[p] * fr[(h + p + 4) & 7];
  }
#pragma unroll
  for (int h = 0; h < 9; ++h) {
    float x = acc[h];
    y1[h][c] = x / (1.f + expf(-x));   // silu
  }
  __syncthreads();
  // conv2: H 9 -> 10, circular pad 4: out[h] = sum_p w[p]*x[(h+p-4) mod 9]
  float a2[10];
  {
    float bb = b2[c];
#pragma unroll
    for (int h = 0; h < 10; ++h) a2[h] = bb;
  }
  for (int cin = 0; cin < 128; ++cin) {
    float g[9];
#pragma unroll
    for (int s = 0; s < 9; ++s) g[s] = y1[s][cin];
    const float* wr = w2 + ((size_t)c * 128 + cin) * 8;
    float wv[8];
#pragma unroll
    for (int p = 0; p < 8; ++p) wv[p] = wr[p];
#pragma unroll
    for (int p = 0; p < 8; ++p)
#pragma unroll
      for (int h = 0; h < 10; ++h) a2[h] += wv[p] * g[(h + p + 5) % 9];
  }
  float s = 0.f;
#pragma unroll
  for (int h = 0; h < 10; ++h) {
    float x = a2[h];
    s += x / (1.f + expf(-x));
  }
  dtok[((size_t)b * 128 + i) * WD + c] = s / 10.0f;
}

// ---------------- concat(data_tokens, broadcast latents) -------------------
__global__ __launch_bounds__(128) void k_concat(
    const float* __restrict__ dtok, const float* __restrict__ otok,
    float* __restrict__ h0) {
  const int blk = blockIdx.x;          // b*256 + t
  const int b = blk >> 8, t = blk & 255, c = threadIdx.x;
  float v = (t < 128) ? dtok[((size_t)b * 128 + t) * WD + c]
                      : otok[(size_t)(t - 128) * WD + c];
  h0[(size_t)blk * WD + c] = v;
}

// ---------------- LayerNorm (width 128), optional strided source -----------
__global__ __launch_bounds__(64) void k_ln(
    const float* __restrict__ src, float* __restrict__ dst,
    const float* __restrict__ g, const float* __restrict__ bta, int keep,
    int skip) {
  const int row = blockIdx.x;
  const int srow = (row / keep) * (keep + skip) + skip + (row % keep);
  const int lane = threadIdx.x;
  const float2 x2 = *(const float2*)(src + (size_t)srow * WD + lane * 2);
  float s = x2.x + x2.y;
  float sq = x2.x * x2.x + x2.y * x2.y;
#pragma unroll
  for (int o = 1; o < 64; o <<= 1) {
    s += __shfl_xor(s, o);
    sq += __shfl_xor(sq, o);
  }
  float m = s * (1.f / 128.f);
  float var = fmaxf(sq * (1.f / 128.f) - m * m, 0.f);
  float r = 1.0f / sqrtf(var + 1e-5f);
  int c = lane * 2;
  float2 o2;
  o2.x = (x2.x - m) * r * g[c] + bta[c];
  o2.y = (x2.y - m) * r * g[c + 1] + bta[c + 1];
  *(float2*)(dst + (size_t)row * WD + c) = o2;
}

// ---------------- fused LN + KV projection (65536 x 128 @ 128 x 256) -------
__global__ __launch_bounds__(256) void k_kvln(
    const float* __restrict__ emb, const float* __restrict__ g,
    const float* __restrict__ bt, const float* __restrict__ wkv,
    const float* __restrict__ bkv, float* __restrict__ kbuf,
    float* __restrict__ vbuf) {
  __shared__ float xn[64 * 129];
  const int tid = threadIdx.x;
  const size_t p0 = (size_t)blockIdx.x * 64;
  for (int i = tid; i < 64 * 128; i += 256) {
    int r = i >> 7, cc = i & 127;
    xn[r * 129 + cc] = emb[(p0 + r) * WD + cc];
  }
  __syncthreads();
  if (tid < 64) {
    float s = 0.f, sq = 0.f;
    for (int k2 = 0; k2 < 128; ++k2) {
      float v = xn[tid * 129 + k2];
      s += v;
      sq += v * v;
    }
    float m = s * (1.f / 128.f);
    float var = fmaxf(sq * (1.f / 128.f) - m * m, 0.f);
    float r = 1.f / sqrtf(var + 1e-5f);
    for (int k2 = 0; k2 < 128; ++k2)
      xn[tid * 129 + k2] = (xn[tid * 129 + k2] - m) * r * g[k2] + bt[k2];
  }
  __syncthreads();
  const int w = tid >> 6, l = tid & 63;
  float4 acc[16];
#pragma unroll
  for (int p = 0; p < 16; ++p) acc[p] = make_float4(0.f, 0.f, 0.f, 0.f);
  for (int k2 = 0; k2 < 128; ++k2) {
    float4 wv = *(const float4*)(wkv + (size_t)k2 * 256 + l * 4);
#pragma unroll
    for (int p = 0; p < 16; ++p) {
      float a = xn[(w * 16 + p) * 129 + k2];
      acc[p].x += a * wv.x;
      acc[p].y += a * wv.y;
      acc[p].z += a * wv.z;
      acc[p].w += a * wv.w;
    }
  }
  float4 bv = *(const float4*)(bkv + l * 4);
#pragma unroll
  for (int p = 0; p < 16; ++p) {
    float4 o;
    o.x = acc[p].x + bv.x;
    o.y = acc[p].y + bv.y;
    o.z = acc[p].z + bv.z;
    o.w = acc[p].w + bv.w;
    size_t row = p0 + w * 16 + p;
    if (l < 32)
      *(float4*)(kbuf + row * WD + l * 4) = o;
    else
      *(float4*)(vbuf + row * WD + (l - 32) * 4) = o;
  }
}

// ---------------- split-K flash attention, partial pass --------------------
// grid = B*H*8*S  (8 q-tiles of 32, S key-chunks); block = 256
// Writes unnormalized o (32x32), plus per-row (m, l) to ml.
__global__ __launch_bounds__(256) void k_attn_part(
    const float* __restrict__ Q, int qs, const float* __restrict__ K, int ks,
    const float* __restrict__ V, int vs, float* __restrict__ opart,
    float* __restrict__ ml, int Tk, int S) {
  const int bx = blockIdx.x;
  const int s = bx % S;
  const int rest = bx / S;
  const int qt = rest & 7, h = (rest >> 3) & 3, b = rest >> 5;
  const int chunk = Tk / S;
  const int kt0 = s * chunk;
  const int tid = threadIdx.x;
  __shared__ float4 vlds4[64 * 9];     // row stride 36 floats
  __shared__ float qlds[32 * 33];
  __shared__ float klds[64 * 33];
  __shared__ float plds[32 * 66];
  for (int i = tid; i < 32 * 32; i += 256) {
    int r = i >> 5, d = i & 31;
    qlds[r * 33 + d] =
        Q[(size_t)(b * 256 + qt * 32 + r) * qs + h * 32 + d] * QSCALE;
  }
  __syncthreads();
  const int qq = tid >> 3, g = tid & 7;
  float qreg[32];
#pragma unroll
  for (int d = 0; d < 32; ++d) qreg[d] = qlds[qq * 33 + d];
  float4 o4 = make_float4(0.f, 0.f, 0.f, 0.f);
  float mrun = -1e30f, lrun = 0.f;
  for (int kt = kt0; kt < kt0 + chunk; kt += 64) {
    __syncthreads();
    for (int i = tid; i < 64 * 32; i += 256) {
      int r = i >> 5, d = i & 31;
      klds[r * 33 + d] = K[(size_t)(b * Tk + kt + r) * ks + h * 32 + d];
      ((float*)vlds4)[r * 36 + d] = V[(size_t)(b * Tk + kt + r) * vs + h * 32 + d];
    }
    __syncthreads();
    float sc[8];
#pragma unroll
    for (int jj = 0; jj < 8; ++jj) {
      int kk = g * 8 + jj;
      float sacc = 0.f;
#pragma unroll
      for (int d = 0; d < 32; ++d) sacc += qreg[d] * klds[kk * 33 + d];
      sc[jj] = sacc;
    }
    float tm = sc[0];
#pragma unroll
    for (int jj = 1; jj < 8; ++jj) tm = fmaxf(tm, sc[jj]);
    tm = fmaxf(tm, __shfl_xor(tm, 1));
    tm = fmaxf(tm, __shfl_xor(tm, 2));
    tm = fmaxf(tm, __shfl_xor(tm, 4));
    float mnew = fmaxf(mrun, tm);
    float alpha = expf(mrun - mnew);
    float psum = 0.f;
#pragma unroll
    for (int jj = 0; jj < 8; ++jj) {
      float p = expf(sc[jj] - mnew);
      plds[qq * 66 + g * 8 + jj] = p;
      psum += p;
    }
    psum += __shfl_xor(psum, 1);
    psum += __shfl_xor(psum, 2);
    psum += __shfl_xor(psum, 4);
    lrun = lrun * alpha + psum;
    mrun = mnew;
    o4.x *= alpha;
    o4.y *= alpha;
    o4.z *= alpha;
    o4.w *= alpha;
    __syncthreads();
    for (int k2 = 0; k2 < 64; ++k2) {
      float p = plds[qq * 66 + k2];
      float4 vv = vlds4[k2 * 9 + g];
      o4.x += p * vv.x;
      o4.y += p * vv.y;
      o4.z += p * vv.z;
      o4.w += p * vv.w;
    }
  }
  // unnormalized partial out + (m,l)
  *(float4*)(opart + (size_t)bx * 1024 + qq * 32 + g * 4) = o4;
  if (g == 0) {
    ml[(size_t)bx * 64 + qq * 2 + 0] = mrun;
    ml[(size_t)bx * 64 + qq * 2 + 1] = lrun;
  }
}

// ---------------- combine S partials -> O ----------------------------------
// grid = B*H*8; block = 256 (thread = q*8+g, float4 of d)
__global__ __launch_bounds__(256) void k_attn_comb(
    const float* __restrict__ opart, const float* __restrict__ ml,
    float* __restrict__ O, int S) {
  const int bx = blockIdx.x;           // (b*4+h)*8+qt
  const int qt = bx & 7, h = (bx >> 3) & 3, b = bx >> 5;
  const int tid = threadIdx.x;
  const int qq = tid >> 3, g = tid & 7;
  const size_t base = (size_t)bx * S;
  float M = -1e30f;
  for (int s = 0; s < S; ++s) M = fmaxf(M, ml[(base + s) * 64 + qq * 2]);
  float L = 0.f;
  float4 o4 = make_float4(0.f, 0.f, 0.f, 0.f);
  for (int s = 0; s < S; ++s) {
    float ms = ml[(base + s) * 64 + qq * 2];
    float ls = ml[(base + s) * 64 + qq * 2 + 1];
    float w = expf(ms - M);
    L += ls * w;
    float4 p4 = *(const float4*)(opart + (base + s) * 1024 + qq * 32 + g * 4);
    o4.x += w * p4.x;
    o4.y += w * p4.y;
    o4.z += w * p4.z;
    o4.w += w * p4.w;
  }
  float inv = 1.f / L;
  size_t orow = (size_t)(b * 256 + qt * 32 + qq);
  float4 res = make_float4(o4.x * inv, o4.y * inv, o4.z * inv, o4.w * inv);
  *(float4*)(O + orow * WD + h * 32 + g * 4) = res;
}

// ---------------- generic GEMM: D[M,N] = act(A[M,K] @ W[K,N] + bias) + res -
template <int NV>
__global__ __launch_bounds__(256) void k_gemm(
    const float* __restrict__ A, int lda, const float* __restrict__ Wt,
    const float* __restrict__ bias, const float* __restrict__ res, int ldres,
    float* __restrict__ D, int ldd, int K, int act) {
  __shared__ float alds[32 * 132];
  const int tid = threadIdx.x;
  const int row0 = blockIdx.x * 32;
  const int w = tid >> 6, l = tid & 63;
  constexpr int N = NV * 64;
  float acc[8][NV];
#pragma unroll
  for (int r = 0; r < 8; ++r)
#pragma unroll
    for (int j = 0; j < NV; ++j) acc[r][j] = 0.f;
  for (int kt = 0; kt < K; kt += 128) {
    __syncthreads();
    for (int i = tid; i < 32 * 128; i += 256) {
      int r = i >> 7, cc = i & 127;
      alds[r * 132 + cc] = A[(size_t)(row0 + r) * lda + kt + cc];
    }
    __syncthreads();
    for (int k2 = 0; k2 < 128; ++k2) {
      float wv[NV];
#pragma unroll
      for (int j = 0; j < NV; ++j) wv[j] = Wt[(size_t)(kt + k2) * N + l + 64 * j];
#pragma unroll
      for (int r = 0; r < 8; ++r) {
        float a = alds[(w * 8 + r) * 132 + k2];
#pragma unroll
        for (int j = 0; j < NV; ++j) acc[r][j] += a * wv[j];
      }
    }
  }
#pragma unroll
  for (int r = 0; r < 8; ++r) {
    size_t row = row0 + w * 8 + r;
#pragma unroll
    for (int j = 0; j < NV; ++j) {
      int col = l + 64 * j;
      float x = acc[r][j] + bias[col];
      if (act == 1) x = 0.5f * x * (1.0f + erff(x * 0.7071067811865476f));
      else if (act == 2) x = tanhf(x);
      if (res != nullptr) x += res[row * ldres + col];
      D[row * ldd + col] = x;
    }
  }
}

}  // namespace

// ---------------------------------------------------------------------------
extern "C" void kernel_launch(void* const* d_in, const int* in_sizes, int n_in,
                              void* d_out, int out_size, void* d_ws,
                              size_t ws_size, hipStream_t stream) {
  const float* pts      = (const float*)d_in[0];
  const float* pe_w     = (const float*)d_in[1];
  const float* pe_b     = (const float*)d_in[2];
  const float* conv1_w  = (const float*)d_in[3];
  const float* conv1_b  = (const float*)d_in[4];
  const float* conv2_w  = (const float*)d_in[5];
  const float* conv2_b  = (const float*)d_in[6];
  const float* otok     = (const float*)d_in[7];
  const float* ln_pre_s = (const float*)d_in[8];
  const float* ln_pre_b = (const float*)d_in[9];
  const float* c_ln1_s  = (const float*)d_in[10];
  const float* c_ln1_b  = (const float*)d_in[11];
  const float* c_ln2_s  = (const float*)d_in[12];
  const float* c_ln2_b  = (const float*)d_in[13];
  const float* c_q_w    = (const float*)d_in[14];
  const float* c_q_b    = (const float*)d_in[15];
  const float* c_kv_w   = (const float*)d_in[16];
  const float* c_kv_b   = (const float*)d_in[17];
  const float* c_proj_w = (const float*)d_in[18];
  const float* c_proj_b = (const float*)d_in[19];
  const float* c_ln3_s  = (const float*)d_in[20];
  const float* c_ln3_b  = (const float*)d_in[21];
  const float* c_mlp1_w = (const float*)d_in[22];
  const float* c_mlp1_b = (const float*)d_in[23];
  const float* c_mlp2_w = (const float*)d_in[24];
  const float* c_mlp2_b = (const float*)d_in[25];
  const float* s_ln1_s  = (const float*)d_in[26];
  const float* s_ln1_b  = (const float*)d_in[27];
  const float* s_qkv_w  = (const float*)d_in[28];
  const float* s_qkv_b  = (const float*)d_in[29];
  const float* s_proj_w = (const float*)d_in[30];
  const float* s_proj_b = (const float*)d_in[31];
  const float* s_ln2_s  = (const float*)d_in[32];
  const float* s_ln2_b  = (const float*)d_in[33];
  const float* s_mlp1_w = (const float*)d_in[34];
  const float* s_mlp1_b = (const float*)d_in[35];
  const float* s_mlp2_w = (const float*)d_in[36];
  const float* s_mlp2_b = (const float*)d_in[37];
  const float* lnpost_s = (const float*)d_in[38];
  const float* lnpost_b = (const float*)d_in[39];
  const float* out_w    = (const float*)d_in[40];
  const float* out_b    = (const float*)d_in[41];

  char* ws = (char*)d_ws;
  constexpr size_t SZ_EMB = (size_t)65536 * 128 * 4;  // 32 MB
  float* emb  = (float*)(ws);
  float* kbuf = (float*)(ws + SZ_EMB);
  float* vbuf = (float*)(ws + 2 * SZ_EMB);
  int*   idx  = (int*)(ws + 3 * SZ_EMB);
  float* dtok = (float*)(ws + 3 * SZ_EMB + 65536);
  float* hbuf = (float*)(ws + 3 * SZ_EMB + 65536 + 524288);
  float* tmp  = (float*)(ws + 3 * SZ_EMB + 65536 + 524288 + 1048576);
  float* qbuf = (float*)(ws + 3 * SZ_EMB + 65536 + 524288 + 2 * 1048576);
  float* att  = (float*)(ws + 3 * SZ_EMB + 65536 + 524288 + 3 * 1048576);
  float* mid  = (float*)(ws + 3 * SZ_EMB + 65536 + 524288 + 4 * 1048576);
  float* qkv  = (float*)(ws + 3 * SZ_EMB + 65536 + 524288 + 4 * 1048576 + 4194304);
  // attention partials overlay the emb region (emb dead after k_kvln/k_gconv):
  // opart: up to 4096 * 1024 floats = 16 MB; ml: 4096 * 64 floats = 1 MB
  float* opart = (float*)(ws);
  float* mlb   = (float*)(ws + 20 * 1024 * 1024);

  // 1) dataset_emb
  k_posenc<<<4096, 256, 0, stream>>>(pts, pe_w, pe_b, emb);
  // 2) ball query
  k_ballquery<<<1024, 64, 0, stream>>>(pts, idx);
  // 3) gather + conv stack -> data_tokens
  k_gconv<<<1024, 128, 0, stream>>>(pts, emb, idx, conv1_w, conv1_b, conv2_w,
                                    conv2_b, dtok);
  // 4) concat + ln_pre -> h
  k_concat<<<2048, 128, 0, stream>>>(dtok, otok, tmp);
  k_ln<<<2048, 64, 0, stream>>>(tmp, hbuf, ln_pre_s, ln_pre_b, 2048, 0);
  // 5) K,V from dataset_emb (fused LN)  [last reader of emb]
  k_kvln<<<1024, 256, 0, stream>>>(emb, c_ln2_s, c_ln2_b, c_kv_w, c_kv_b, kbuf,
                                   vbuf);
  // 6) cross attention block (split-K: S=16 chunks of 512 keys)
  k_ln<<<2048, 64, 0, stream>>>(hbuf, tmp, c_ln1_s, c_ln1_b, 2048, 0);
  k_gemm<2><<<64, 256, 0, stream>>>(tmp, 128, c_q_w, c_q_b, nullptr, 0, qbuf,
                                    128, 128, 0);
  k_attn_part<<<4096, 256, 0, stream>>>(qbuf, 128, kbuf, 128, vbuf, 128, opart,
                                        mlb, 8192, 16);
  k_attn_comb<<<256, 256, 0, stream>>>(opart, mlb, att, 16);
  k_gemm<2><<<64, 256, 0, stream>>>(att, 128, c_proj_w, c_proj_b, hbuf, 128,
                                    hbuf, 128, 128, 0);
  k_ln<<<2048, 64, 0, stream>>>(hbuf, tmp, c_ln3_s, c_ln3_b, 2048, 0);
  k_gemm<8><<<64, 256, 0, stream>>>(tmp, 128, c_mlp1_w, c_mlp1_b, nullptr, 0,
                                    mid, 512, 128, 1);
  k_gemm<2><<<64, 256, 0, stream>>>(mid, 512, c_mlp2_w, c_mlp2_b, hbuf, 128,
                                    hbuf, 128, 512, 0);
  // 7) self-attention blocks (split S=2 chunks of 128 keys)
  for (int i = 0; i < 3; ++i) {
    k_ln<<<2048, 64, 0, stream>>>(hbuf, tmp, s_ln1_s + i * 128,
                                  s_ln1_b + i * 128, 2048, 0);
    k_gemm<6><<<64, 256, 0, stream>>>(tmp, 128, s_qkv_w + (size_t)i * 128 * 384,
                                      s_qkv_b + i * 384, nullptr, 0, qkv, 384,
                                      128, 0);
    k_attn_part<<<512, 256, 0, stream>>>(qkv, 384, qkv + 128, 384, qkv + 256,
                                         384, opart, mlb, 256, 2);
    k_attn_comb<<<256, 256, 0, stream>>>(opart, mlb, att, 2);
    k_gemm<2><<<64, 256, 0, stream>>>(att, 128, s_proj_w + (size_t)i * 16384,
                                      s_proj_b + i * 128, hbuf, 128, hbuf, 128,
                                      128, 0);
    k_ln<<<2048, 64, 0, stream>>>(hbuf, tmp, s_ln2_s + i * 128,
                                  s_ln2_b + i * 128, 2048, 0);
    k_gemm<8><<<64, 256, 0, stream>>>(tmp, 128, s_mlp1_w + (size_t)i * 65536,
                                      s_mlp1_b + i * 512, nullptr, 0, mid, 512,
                                      128, 1);
    k_gemm<2><<<64, 256, 0, stream>>>(mid, 512, s_mlp2_w + (size_t)i * 65536,
                                      s_mlp2_b + i * 128, hbuf, 128, hbuf, 128,
                                      512, 0);
  }
  // 8) final LN (last 128 tokens) + output head with tanh
  k_ln<<<1024, 64, 0, stream>>>(hbuf, tmp, lnpost_s, lnpost_b, 128, 128);
  k_gemm<2><<<32, 256, 0, stream>>>(tmp, 128, out_w, out_b, nullptr, 0,
                                    (float*)d_out, 128, 128, 2);
}

// Round 3
// 937.567 us; speedup vs baseline: 1.7248x; 1.3153x over previous
//
#include <hip/hip_runtime.h>
#include <math.h>

// ---------------------------------------------------------------------------
// PointCloudPerceiverChannelsEncoder — round 2: bf16 MFMA attention + LN-fused
// GEMMs. B=8, N=8192, W=128, HEADS=4 (dh=32), LATENT=128, SELF_LAYERS=3.
// ---------------------------------------------------------------------------

namespace {

constexpr int NP = 8192;
constexpr int WD = 128;
constexpr int POSD = 62;
constexpr float R2C = 0.04f;
constexpr float QSCALE = 0.17677669529663687f;    // 1/sqrt(32)
constexpr float HALFPI = 1.5707963705062866f;

typedef __bf16 bf16x8 __attribute__((ext_vector_type(8)));
typedef float f32x4 __attribute__((ext_vector_type(4)));
union U16B { uint4 u; bf16x8 h; unsigned short s[8]; };

// ---------------- posenc + pe GEMM: emb[65536][128] -------------------------
__global__ __launch_bounds__(256) void k_posenc(
    const float* __restrict__ pts, const float* __restrict__ pew,
    const float* __restrict__ peb, float* __restrict__ emb) {
  __shared__ float pw[POSD * WD];
  __shared__ float pos[16][POSD];
  const int tid = threadIdx.x;
  const int base = blockIdx.x * 16;
  for (int i = tid; i < POSD * WD; i += 256) pw[i] = pew[i];
  for (int i = tid; i < 16 * POSD; i += 256) {
    int p = i / POSD, j = i % POSD;
    const float* pp = pts + (size_t)(base + p) * 2;
    float v;
    if (j < 2) {
      v = pp[j];
    } else if (j < 32) {
      int t = j - 2;
      v = sinf(pp[t & 1] * (float)(1 << (t >> 1)));
    } else {
      int t = j - 32;
      v = sinf(pp[t & 1] * (float)(1 << (t >> 1)) + HALFPI);
    }
    pos[p][j] = v;
  }
  __syncthreads();
  for (int i = tid; i < 16 * WD; i += 256) {
    int p = i >> 7, c = i & 127;
    float acc = peb[c];
#pragma unroll
    for (int j = 0; j < POSD; ++j) acc += pos[p][j] * pw[j * WD + c];
    emb[(size_t)(base + p) * WD + c] = acc;
  }
}

// ---------------- ball query: first 8 indices (ascending) within radius ----
__global__ __launch_bounds__(64) void k_ballquery(
    const float* __restrict__ pts, int* __restrict__ idxo) {
  const int blk = blockIdx.x;
  const int b = blk >> 7, i = blk & 127;
  const int lane = threadIdx.x;
  __shared__ int sidx[8];
  const float cx = pts[((size_t)b * NP + i) * 2];
  const float cy = pts[((size_t)b * NP + i) * 2 + 1];
  int cnt = 0;
  for (int j0 = 0; j0 < NP; j0 += 64) {
    int j = j0 + lane;
    float dx = pts[((size_t)b * NP + j) * 2] - cx;
    float dy = pts[((size_t)b * NP + j) * 2 + 1] - cy;
    float d2 = __fadd_rn(__fmul_rn(dx, dx), __fmul_rn(dy, dy));
    bool ok = !(d2 > R2C);
    unsigned long long m = __ballot(ok);
    int ord = cnt + __popcll(m & ((1ull << lane) - 1ull));
    if (ok && ord < 8) sidx[ord] = j;
    cnt += (int)__popcll(m);
    if (cnt >= 8) break;
  }
  __syncthreads();
  if (lane < 8) {
    int v = (lane < cnt) ? sidx[lane] : sidx[0];
    idxo[blk * 8 + lane] = v;
  }
}

// ---------------- gather + conv1 + conv2 + mean -> data_tokens -------------
__global__ __launch_bounds__(128) void k_gconv(
    const float* __restrict__ pts, const float* __restrict__ emb,
    const int* __restrict__ idxs, const float* __restrict__ w1,
    const float* __restrict__ b1, const float* __restrict__ w2,
    const float* __restrict__ b2, float* __restrict__ dtok) {
  const int blk = blockIdx.x;
  const int b = blk >> 7, i = blk & 127;
  const int c = threadIdx.x;
  __shared__ float f[8][130];
  __shared__ float y1[9][128];
  __shared__ int sid[8];
  if (c < 8) sid[c] = idxs[blk * 8 + c];
  __syncthreads();
  for (int s = 0; s < 8; ++s) {
    int j = sid[s];
    f[s][2 + c] = emb[((size_t)b * NP + j) * WD + c];
    if (c < 2)
      f[s][c] = pts[((size_t)b * NP + j) * 2 + c] -
                pts[((size_t)b * NP + i) * 2 + c];
  }
  __syncthreads();
  float acc[9];
  {
    float bb = b1[c];
#pragma unroll
    for (int h = 0; h < 9; ++h) acc[h] = bb;
  }
  for (int cin = 0; cin < 130; ++cin) {
    float fr[8];
#pragma unroll
    for (int s = 0; s < 8; ++s) fr[s] = f[s][cin];
    const float* wr = w1 + ((size_t)c * 130 + cin) * 8;
    float wv[8];
#pragma unroll
    for (int p = 0; p < 8; ++p) wv[p] = wr[p];
#pragma unroll
    for (int p = 0; p < 8; ++p)
#pragma unroll
      for (int h = 0; h < 9; ++h) acc[h] += wv[p] * fr[(h + p + 4) & 7];
  }
#pragma unroll
  for (int h = 0; h < 9; ++h) {
    float x = acc[h];
    y1[h][c] = x / (1.f + expf(-x));
  }
  __syncthreads();
  float a2[10];
  {
    float bb = b2[c];
#pragma unroll
    for (int h = 0; h < 10; ++h) a2[h] = bb;
  }
  for (int cin = 0; cin < 128; ++cin) {
    float g[9];
#pragma unroll
    for (int s = 0; s < 9; ++s) g[s] = y1[s][cin];
    const float* wr = w2 + ((size_t)c * 128 + cin) * 8;
    float wv[8];
#pragma unroll
    for (int p = 0; p < 8; ++p) wv[p] = wr[p];
#pragma unroll
    for (int p = 0; p < 8; ++p)
#pragma unroll
      for (int h = 0; h < 10; ++h) a2[h] += wv[p] * g[(h + p + 5) % 9];
  }
  float s = 0.f;
#pragma unroll
  for (int h = 0; h < 10; ++h) {
    float x = a2[h];
    s += x / (1.f + expf(-x));
  }
  dtok[((size_t)b * 128 + i) * WD + c] = s / 10.0f;
}

// ---------------- concat(data_tokens, latents) + ln_pre -> h ---------------
__global__ __launch_bounds__(64) void k_concat_ln(
    const float* __restrict__ dtok, const float* __restrict__ otok,
    const float* __restrict__ g, const float* __restrict__ bta,
    float* __restrict__ h0) {
  const int row = blockIdx.x;          // b*256 + t
  const int b = row >> 8, t = row & 255;
  const int lane = threadIdx.x;
  const float* src = (t < 128) ? (dtok + ((size_t)b * 128 + t) * WD)
                               : (otok + (size_t)(t - 128) * WD);
  const float2 x2 = *(const float2*)(src + lane * 2);
  float s = x2.x + x2.y;
  float sq = x2.x * x2.x + x2.y * x2.y;
#pragma unroll
  for (int o = 1; o < 64; o <<= 1) {
    s += __shfl_xor(s, o);
    sq += __shfl_xor(sq, o);
  }
  float m = s * (1.f / 128.f);
  float var = fmaxf(sq * (1.f / 128.f) - m * m, 0.f);
  float r = 1.0f / sqrtf(var + 1e-5f);
  int c = lane * 2;
  float2 o2;
  o2.x = (x2.x - m) * r * g[c] + bta[c];
  o2.y = (x2.y - m) * r * g[c + 1] + bta[c + 1];
  *(float2*)(h0 + (size_t)row * WD + c) = o2;
}

// ---------------- fused LN + KV projection (65536 x 128 @ 128 x 256) -------
__global__ __launch_bounds__(256) void k_kvln(
    const float* __restrict__ emb, const float* __restrict__ g,
    const float* __restrict__ bt, const float* __restrict__ wkv,
    const float* __restrict__ bkv, float* __restrict__ kbuf,
    float* __restrict__ vbuf) {
  __shared__ float xn[64 * 129];
  const int tid = threadIdx.x;
  const size_t p0 = (size_t)blockIdx.x * 64;
  for (int i = tid; i < 64 * 128; i += 256) {
    int r = i >> 7, cc = i & 127;
    xn[r * 129 + cc] = emb[(p0 + r) * WD + cc];
  }
  __syncthreads();
  if (tid < 64) {
    float s = 0.f, sq = 0.f;
    for (int k2 = 0; k2 < 128; ++k2) {
      float v = xn[tid * 129 + k2];
      s += v;
      sq += v * v;
    }
    float m = s * (1.f / 128.f);
    float var = fmaxf(sq * (1.f / 128.f) - m * m, 0.f);
    float r = 1.f / sqrtf(var + 1e-5f);
    for (int k2 = 0; k2 < 128; ++k2)
      xn[tid * 129 + k2] = (xn[tid * 129 + k2] - m) * r * g[k2] + bt[k2];
  }
  __syncthreads();
  const int w = tid >> 6, l = tid & 63;
  float4 acc[16];
#pragma unroll
  for (int p = 0; p < 16; ++p) acc[p] = make_float4(0.f, 0.f, 0.f, 0.f);
  for (int k2 = 0; k2 < 128; ++k2) {
    float4 wv = *(const float4*)(wkv + (size_t)k2 * 256 + l * 4);
#pragma unroll
    for (int p = 0; p < 16; ++p) {
      float a = xn[(w * 16 + p) * 129 + k2];
      acc[p].x += a * wv.x;
      acc[p].y += a * wv.y;
      acc[p].z += a * wv.z;
      acc[p].w += a * wv.w;
    }
  }
  float4 bv = *(const float4*)(bkv + l * 4);
#pragma unroll
  for (int p = 0; p < 16; ++p) {
    float4 o;
    o.x = acc[p].x + bv.x;
    o.y = acc[p].y + bv.y;
    o.z = acc[p].z + bv.z;
    o.w = acc[p].w + bv.w;
    size_t row = p0 + w * 16 + p;
    if (l < 32)
      *(float4*)(kbuf + row * WD + l * 4) = o;
    else
      *(float4*)(vbuf + row * WD + (l - 32) * 4) = o;
  }
}

// ---------------- MFMA bf16 flash attention (maxless), split-K -------------
// grid = B*H*S; block = 256 (4 waves). Each block: all 256 q, chunk CH keys.
// Wave w handles q rows [w*64, w*64+64) as 4 qsubs of 16.
// Partials: opart[bx][256][32] f32 (unnormalized), lbuf[bx][256] = sum(exp).
__global__ __launch_bounds__(256) void k_attn_mfma(
    const float* __restrict__ Q, int qs, const float* __restrict__ K, int ks,
    const float* __restrict__ V, int vs, float* __restrict__ opart,
    float* __restrict__ lbuf, int Tk, int S, int CH) {
  const int bx = blockIdx.x;
  const int s = bx % S;
  const int bh = bx / S;
  const int h = bh & 3, b = bh >> 2;
  const int tid = threadIdx.x;
  const int w = tid >> 6, lane = tid & 63;
  const int l15 = lane & 15, l16 = lane >> 4;

  __shared__ unsigned short Kb[64 * 32];   // bf16, row-major [k][d]
  __shared__ unsigned short Vt[32 * 68];   // bf16, transposed [d][k], pad 68
  __shared__ float Pl[4][16 * 72];         // per-wave P, stride 72

  // Q fragments (A-operand): lane holds Q[q0+m*16+l15][l16*8+j]*QSCALE
  bf16x8 qf[4];
#pragma unroll
  for (int m = 0; m < 4; ++m) {
    const float* qp = Q + (size_t)(b * 256 + w * 64 + m * 16 + l15) * qs +
                      h * 32 + l16 * 8;
    float4 a = *(const float4*)qp;
    float4 bq = *(const float4*)(qp + 4);
    U16B u;
    u.h[0] = (__bf16)(a.x * QSCALE);
    u.h[1] = (__bf16)(a.y * QSCALE);
    u.h[2] = (__bf16)(a.z * QSCALE);
    u.h[3] = (__bf16)(a.w * QSCALE);
    u.h[4] = (__bf16)(bq.x * QSCALE);
    u.h[5] = (__bf16)(bq.y * QSCALE);
    u.h[6] = (__bf16)(bq.z * QSCALE);
    u.h[7] = (__bf16)(bq.w * QSCALE);
    qf[m] = u.h;
  }

  f32x4 o[4][2];
#pragma unroll
  for (int m = 0; m < 4; ++m)
#pragma unroll
    for (int d = 0; d < 2; ++d) o[m][d] = (f32x4){0.f, 0.f, 0.f, 0.f};
  float lacc[4][4];
#pragma unroll
  for (int m = 0; m < 4; ++m)
#pragma unroll
    for (int r = 0; r < 4; ++r) lacc[m][r] = 0.f;

  const int kt0 = s * CH;
  for (int kt = kt0; kt < kt0 + CH; kt += 64) {
    __syncthreads();
    // stage K (row-major bf16) and V (transposed bf16)
    {
      const int r = tid >> 2, c0 = (tid & 3) * 8;
      const float* kp = K + (size_t)(b * Tk + kt + r) * ks + h * 32 + c0;
      float4 a = *(const float4*)kp;
      float4 bb = *(const float4*)(kp + 4);
      U16B uk;
      uk.h[0] = (__bf16)a.x;  uk.h[1] = (__bf16)a.y;
      uk.h[2] = (__bf16)a.z;  uk.h[3] = (__bf16)a.w;
      uk.h[4] = (__bf16)bb.x; uk.h[5] = (__bf16)bb.y;
      uk.h[6] = (__bf16)bb.z; uk.h[7] = (__bf16)bb.w;
      *(uint4*)&Kb[r * 32 + c0] = uk.u;
      const float* vp = V + (size_t)(b * Tk + kt + r) * vs + h * 32 + c0;
      float4 va = *(const float4*)vp;
      float4 vb = *(const float4*)(vp + 4);
      U16B uv;
      uv.h[0] = (__bf16)va.x; uv.h[1] = (__bf16)va.y;
      uv.h[2] = (__bf16)va.z; uv.h[3] = (__bf16)va.w;
      uv.h[4] = (__bf16)vb.x; uv.h[5] = (__bf16)vb.y;
      uv.h[6] = (__bf16)vb.z; uv.h[7] = (__bf16)vb.w;
#pragma unroll
      for (int j = 0; j < 8; ++j) Vt[(c0 + j) * 68 + r] = uv.s[j];
    }
    __syncthreads();

    // K fragments (B-operand): lane holds K[ks*16+l15][l16*8+j]
    bf16x8 kf[4];
#pragma unroll
    for (int ksb = 0; ksb < 4; ++ksb) {
      U16B u;
      u.u = *(const uint4*)&Kb[(ksb * 16 + l15) * 32 + l16 * 8];
      kf[ksb] = u.h;
    }
    // V fragments (B-operand): lane holds V[kc*32+l16*8+j][dsub*16+l15]
    bf16x8 vf[2][2];
#pragma unroll
    for (int kc = 0; kc < 2; ++kc)
#pragma unroll
      for (int d = 0; d < 2; ++d) {
        const unsigned short* vp =
            &Vt[(l15 + 16 * d) * 68 + kc * 32 + l16 * 8];
        U16B u;
        *(uint2*)&u.s[0] = *(const uint2*)vp;
        *(uint2*)&u.s[4] = *(const uint2*)(vp + 4);
        vf[kc][d] = u.h;
      }

#pragma unroll
    for (int m = 0; m < 4; ++m) {
      const f32x4 zf = {0.f, 0.f, 0.f, 0.f};
      f32x4 sf[4];
#pragma unroll
      for (int ksb = 0; ksb < 4; ++ksb)
        sf[ksb] = __builtin_amdgcn_mfma_f32_16x16x32_bf16(qf[m], kf[ksb], zf,
                                                          0, 0, 0);
      // maxless softmax: p = exp(score), row-sum across 16 lanes (cols)
      float pv[4][4];
      float ps[4] = {0.f, 0.f, 0.f, 0.f};
#pragma unroll
      for (int ksb = 0; ksb < 4; ++ksb)
#pragma unroll
        for (int r = 0; r < 4; ++r) {
          float p = expf(sf[ksb][r]);
          pv[ksb][r] = p;
          ps[r] += p;
        }
#pragma unroll
      for (int r = 0; r < 4; ++r) {
        float v = ps[r];
        v += __shfl_xor(v, 1);
        v += __shfl_xor(v, 2);
        v += __shfl_xor(v, 4);
        v += __shfl_xor(v, 8);
        lacc[m][r] += v;
      }
      // write P to per-wave LDS, re-read in A-fragment layout
#pragma unroll
      for (int ksb = 0; ksb < 4; ++ksb)
#pragma unroll
        for (int r = 0; r < 4; ++r)
          Pl[w][(l16 * 4 + r) * 72 + ksb * 16 + l15] = pv[ksb][r];
      asm volatile("s_waitcnt lgkmcnt(0)" ::: "memory");
      bf16x8 pa[2];
#pragma unroll
      for (int kc = 0; kc < 2; ++kc) {
        const float* pr = &Pl[w][l15 * 72 + l16 * 8 + kc * 32];
        float4 p0 = *(const float4*)pr;
        float4 p1 = *(const float4*)(pr + 4);
        U16B u;
        u.h[0] = (__bf16)p0.x; u.h[1] = (__bf16)p0.y;
        u.h[2] = (__bf16)p0.z; u.h[3] = (__bf16)p0.w;
        u.h[4] = (__bf16)p1.x; u.h[5] = (__bf16)p1.y;
        u.h[6] = (__bf16)p1.z; u.h[7] = (__bf16)p1.w;
        pa[kc] = u.h;
      }
#pragma unroll
      for (int kc = 0; kc < 2; ++kc)
#pragma unroll
        for (int d = 0; d < 2; ++d)
          o[m][d] = __builtin_amdgcn_mfma_f32_16x16x32_bf16(pa[kc], vf[kc][d],
                                                            o[m][d], 0, 0, 0);
    }
  }

  // write partials
  const size_t ob = (size_t)bx * 8192;
#pragma unroll
  for (int m = 0; m < 4; ++m) {
    int qrow = w * 64 + m * 16 + l16 * 4;
#pragma unroll
    for (int r = 0; r < 4; ++r) {
#pragma unroll
      for (int d = 0; d < 2; ++d)
        opart[ob + (qrow + r) * 32 + d * 16 + l15] = o[m][d][r];
      if (l15 == 0) lbuf[(size_t)bx * 256 + qrow + r] = lacc[m][r];
    }
  }
}

// ---------------- combine S partials -> O ----------------------------------
// grid = B*H*8; block = 256 (thread = qq*8+g, float4 of d)
__global__ __launch_bounds__(256) void k_attn_comb(
    const float* __restrict__ opart, const float* __restrict__ lbuf,
    float* __restrict__ O, int S) {
  const int bx = blockIdx.x;
  const int qt = bx & 7, h = (bx >> 3) & 3, b = bx >> 5;
  const int tid = threadIdx.x;
  const int qq = tid >> 3, g = tid & 7;
  const int q = qt * 32 + qq;
  const int pb = (b * 4 + h) * S;
  float L = 0.f;
  float4 o4 = make_float4(0.f, 0.f, 0.f, 0.f);
  for (int s = 0; s < S; ++s) {
    L += lbuf[(size_t)(pb + s) * 256 + q];
    float4 p4 = *(const float4*)(opart + (size_t)(pb + s) * 8192 + q * 32 + g * 4);
    o4.x += p4.x;
    o4.y += p4.y;
    o4.z += p4.z;
    o4.w += p4.w;
  }
  float inv = 1.f / L;
  size_t orow = (size_t)(b * 256 + q);
  float4 res = make_float4(o4.x * inv, o4.y * inv, o4.z * inv, o4.w * inv);
  *(float4*)(O + orow * WD + h * 32 + g * 4) = res;
}

// ---------------- GEMM: D[M,N] = act(LN?(A)[M,K] @ W[K,N] + bias) + res ----
// grid = M/32, block = 256; NV = N/64; act: 0 none, 1 gelu, 2 tanh.
// LN (when lnS != null, requires K==128): per-row LayerNorm of staged tile.
// A source row mapping: srow = (row/keep)*(keep+skip) + skip + row%keep.
template <int NV>
__global__ __launch_bounds__(256) void k_gemm(
    const float* __restrict__ A, int lda, const float* __restrict__ Wt,
    const float* __restrict__ bias, const float* __restrict__ res, int ldres,
    float* __restrict__ D, int ldd, int K, int act,
    const float* __restrict__ lnS, const float* __restrict__ lnB, int keep,
    int skip) {
  __shared__ float alds[32 * 132];
  const int tid = threadIdx.x;
  const int row0 = blockIdx.x * 32;
  const int w = tid >> 6, l = tid & 63;
  constexpr int N = NV * 64;
  float acc[8][NV];
#pragma unroll
  for (int r = 0; r < 8; ++r)
#pragma unroll
    for (int j = 0; j < NV; ++j) acc[r][j] = 0.f;
  for (int kt = 0; kt < K; kt += 128) {
    __syncthreads();
    for (int i = tid; i < 32 * 128; i += 256) {
      int r = i >> 7, cc = i & 127;
      int grow = row0 + r;
      int srow = (grow / keep) * (keep + skip) + skip + grow % keep;
      alds[r * 132 + cc] = A[(size_t)srow * lda + kt + cc];
    }
    __syncthreads();
    if (lnS != nullptr && kt == 0) {
      const int r = tid >> 3, part = tid & 7;
      float s = 0.f, sq = 0.f;
#pragma unroll
      for (int c = part * 16; c < part * 16 + 16; ++c) {
        float v = alds[r * 132 + c];
        s += v;
        sq += v * v;
      }
      s += __shfl_xor(s, 1);  sq += __shfl_xor(sq, 1);
      s += __shfl_xor(s, 2);  sq += __shfl_xor(sq, 2);
      s += __shfl_xor(s, 4);  sq += __shfl_xor(sq, 4);
      float m = s * (1.f / 128.f);
      float var = fmaxf(sq * (1.f / 128.f) - m * m, 0.f);
      float rinv = 1.0f / sqrtf(var + 1e-5f);
#pragma unroll
      for (int c = part * 16; c < part * 16 + 16; ++c)
        alds[r * 132 + c] = (alds[r * 132 + c] - m) * rinv * lnS[c] + lnB[c];
      __syncthreads();
    }
    for (int k2 = 0; k2 < 128; ++k2) {
      float wv[NV];
#pragma unroll
      for (int j = 0; j < NV; ++j) wv[j] = Wt[(size_t)(kt + k2) * N + l + 64 * j];
#pragma unroll
      for (int r = 0; r < 8; ++r) {
        float a = alds[(w * 8 + r) * 132 + k2];
#pragma unroll
        for (int j = 0; j < NV; ++j) acc[r][j] += a * wv[j];
      }
    }
  }
#pragma unroll
  for (int r = 0; r < 8; ++r) {
    size_t row = row0 + w * 8 + r;
#pragma unroll
    for (int j = 0; j < NV; ++j) {
      int col = l + 64 * j;
      float x = acc[r][j] + bias[col];
      if (act == 1) x = 0.5f * x * (1.0f + erff(x * 0.7071067811865476f));
      else if (act == 2) x = tanhf(x);
      if (res != nullptr) x += res[row * ldres + col];
      D[row * ldd + col] = x;
    }
  }
}

}  // namespace

// ---------------------------------------------------------------------------
extern "C" void kernel_launch(void* const* d_in, const int* in_sizes, int n_in,
                              void* d_out, int out_size, void* d_ws,
                              size_t ws_size, hipStream_t stream) {
  const float* pts      = (const float*)d_in[0];
  const float* pe_w     = (const float*)d_in[1];
  const float* pe_b     = (const float*)d_in[2];
  const float* conv1_w  = (const float*)d_in[3];
  const float* conv1_b  = (const float*)d_in[4];
  const float* conv2_w  = (const float*)d_in[5];
  const float* conv2_b  = (const float*)d_in[6];
  const float* otok     = (const float*)d_in[7];
  const float* ln_pre_s = (const float*)d_in[8];
  const float* ln_pre_b = (const float*)d_in[9];
  const float* c_ln1_s  = (const float*)d_in[10];
  const float* c_ln1_b  = (const float*)d_in[11];
  const float* c_ln2_s  = (const float*)d_in[12];
  const float* c_ln2_b  = (const float*)d_in[13];
  const float* c_q_w    = (const float*)d_in[14];
  const float* c_q_b    = (const float*)d_in[15];
  const float* c_kv_w   = (const float*)d_in[16];
  const float* c_kv_b   = (const float*)d_in[17];
  const float* c_proj_w = (const float*)d_in[18];
  const float* c_proj_b = (const float*)d_in[19];
  const float* c_ln3_s  = (const float*)d_in[20];
  const float* c_ln3_b  = (const float*)d_in[21];
  const float* c_mlp1_w = (const float*)d_in[22];
  const float* c_mlp1_b = (const float*)d_in[23];
  const float* c_mlp2_w = (const float*)d_in[24];
  const float* c_mlp2_b = (const float*)d_in[25];
  const float* s_ln1_s  = (const float*)d_in[26];
  const float* s_ln1_b  = (const float*)d_in[27];
  const float* s_qkv_w  = (const float*)d_in[28];
  const float* s_qkv_b  = (const float*)d_in[29];
  const float* s_proj_w = (const float*)d_in[30];
  const float* s_proj_b = (const float*)d_in[31];
  const float* s_ln2_s  = (const float*)d_in[32];
  const float* s_ln2_b  = (const float*)d_in[33];
  const float* s_mlp1_w = (const float*)d_in[34];
  const float* s_mlp1_b = (const float*)d_in[35];
  const float* s_mlp2_w = (const float*)d_in[36];
  const float* s_mlp2_b = (const float*)d_in[37];
  const float* lnpost_s = (const float*)d_in[38];
  const float* lnpost_b = (const float*)d_in[39];
  const float* out_w    = (const float*)d_in[40];
  const float* out_b    = (const float*)d_in[41];

  char* ws = (char*)d_ws;
  constexpr size_t SZ_EMB = (size_t)65536 * 128 * 4;  // 32 MB
  float* emb  = (float*)(ws);
  float* kbuf = (float*)(ws + SZ_EMB);
  float* vbuf = (float*)(ws + 2 * SZ_EMB);
  int*   idx  = (int*)(ws + 3 * SZ_EMB);
  float* dtok = (float*)(ws + 3 * SZ_EMB + 65536);
  float* hbuf = (float*)(ws + 3 * SZ_EMB + 65536 + 524288);
  float* qbuf = (float*)(ws + 3 * SZ_EMB + 65536 + 524288 + 2 * 1048576);
  float* att  = (float*)(ws + 3 * SZ_EMB + 65536 + 524288 + 3 * 1048576);
  float* mid  = (float*)(ws + 3 * SZ_EMB + 65536 + 524288 + 4 * 1048576);
  float* qkv  = (float*)(ws + 3 * SZ_EMB + 65536 + 524288 + 4 * 1048576 + 4194304);
  // attention partials overlay the emb region (emb dead after k_kvln):
  // opart: up to 512 * 8192 f32 = 16.8 MB; lbuf at +24 MB (512*256 f32)
  float* opart = (float*)(ws);
  float* lbuf  = (float*)(ws + 24 * 1024 * 1024);

  const int IDK = 1 << 28;  // identity row mapping for LN-fused GEMMs

  // 1) dataset_emb
  k_posenc<<<4096, 256, 0, stream>>>(pts, pe_w, pe_b, emb);
  // 2) ball query
  k_ballquery<<<1024, 64, 0, stream>>>(pts, idx);
  // 3) gather + conv stack -> data_tokens
  k_gconv<<<1024, 128, 0, stream>>>(pts, emb, idx, conv1_w, conv1_b, conv2_w,
                                    conv2_b, dtok);
  // 4) concat + ln_pre -> h
  k_concat_ln<<<2048, 64, 0, stream>>>(dtok, otok, ln_pre_s, ln_pre_b, hbuf);
  // 5) K,V from dataset_emb (fused LN) [last reader of emb]
  k_kvln<<<1024, 256, 0, stream>>>(emb, c_ln2_s, c_ln2_b, c_kv_w, c_kv_b, kbuf,
                                   vbuf);
  // 6) cross attention block (MFMA, S=16 chunks of 512 keys)
  k_gemm<2><<<64, 256, 0, stream>>>(hbuf, 128, c_q_w, c_q_b, nullptr, 0, qbuf,
                                    128, 128, 0, c_ln1_s, c_ln1_b, IDK, 0);
  k_attn_mfma<<<512, 256, 0, stream>>>(qbuf, 128, kbuf, 128, vbuf, 128, opart,
                                       lbuf, 8192, 16, 512);
  k_attn_comb<<<256, 256, 0, stream>>>(opart, lbuf, att, 16);
  k_gemm<2><<<64, 256, 0, stream>>>(att, 128, c_proj_w, c_proj_b, hbuf, 128,
                                    hbuf, 128, 128, 0, nullptr, nullptr, IDK, 0);
  k_gemm<8><<<64, 256, 0, stream>>>(hbuf, 128, c_mlp1_w, c_mlp1_b, nullptr, 0,
                                    mid, 512, 128, 1, c_ln3_s, c_ln3_b, IDK, 0);
  k_gemm<2><<<64, 256, 0, stream>>>(mid, 512, c_mlp2_w, c_mlp2_b, hbuf, 128,
                                    hbuf, 128, 512, 0, nullptr, nullptr, IDK, 0);
  // 7) self-attention blocks (MFMA, S=4 chunks of 64 keys)
  for (int i = 0; i < 3; ++i) {
    k_gemm<6><<<64, 256, 0, stream>>>(hbuf, 128, s_qkv_w + (size_t)i * 128 * 384,
                                      s_qkv_b + i * 384, nullptr, 0, qkv, 384,
                                      128, 0, s_ln1_s + i * 128,
                                      s_ln1_b + i * 128, IDK, 0);
    k_attn_mfma<<<128, 256, 0, stream>>>(qkv, 384, qkv + 128, 384, qkv + 256,
                                         384, opart, lbuf, 256, 4, 64);
    k_attn_comb<<<256, 256, 0, stream>>>(opart, lbuf, att, 4);
    k_gemm<2><<<64, 256, 0, stream>>>(att, 128, s_proj_w + (size_t)i * 16384,
                                      s_proj_b + i * 128, hbuf, 128, hbuf, 128,
                                      128, 0, nullptr, nullptr, IDK, 0);
    k_gemm<8><<<64, 256, 0, stream>>>(hbuf, 128, s_mlp1_w + (size_t)i * 65536,
                                      s_mlp1_b + i * 512, nullptr, 0, mid, 512,
                                      128, 1, s_ln2_s + i * 128,
                                      s_ln2_b + i * 128, IDK, 0);
    k_gemm<2><<<64, 256, 0, stream>>>(mid, 512, s_mlp2_w + (size_t)i * 65536,
                                      s_mlp2_b + i * 128, hbuf, 128, hbuf, 128,
                                      512, 0, nullptr, nullptr, IDK, 0);
  }
  // 8) final LN (last 128 tokens of each batch) + output head with tanh
  k_gemm<2><<<32, 256, 0, stream>>>(hbuf, 128, out_w, out_b, nullptr, 0,
                                    (float*)d_out, 128, 128, 2, lnpost_s,
                                    lnpost_b, 128, 128);
}

// Round 4
// 687.008 us; speedup vs baseline: 2.3539x; 1.3647x over previous
//
#include <hip/hip_runtime.h>
#include <math.h>

// ---------------------------------------------------------------------------
// PointCloudPerceiverChannelsEncoder — round 3:
//  - gconv: transposed (coalesced) weights + 2 points/block
//  - posenc: no weight staging, coalesced L2 reads, 32 pts/block
//  - gemm: 16-row tiles, col-chunk grid.y, k-unroll 4
// ---------------------------------------------------------------------------

namespace {

constexpr int NP = 8192;
constexpr int WD = 128;
constexpr int POSD = 62;
constexpr float R2C = 0.04f;
constexpr float QSCALE = 0.17677669529663687f;    // 1/sqrt(32)
constexpr float HALFPI = 1.5707963705062866f;

typedef __bf16 bf16x8 __attribute__((ext_vector_type(8)));
typedef float f32x4 __attribute__((ext_vector_type(4)));
union U16B { uint4 u; bf16x8 h; unsigned short s[8]; };

// ---------------- posenc + pe GEMM: emb[65536][128] -------------------------
// 32 points/block, grid 2048. pe_w read coalesced from L2 (no LDS staging).
__global__ __launch_bounds__(256) void k_posenc(
    const float* __restrict__ pts, const float* __restrict__ pew,
    const float* __restrict__ peb, float* __restrict__ emb) {
  __shared__ float posT[62][36];     // [j][point], stride 36 (16B-aligned rows)
  const int tid = threadIdx.x;
  const int base = blockIdx.x * 32;
  for (int i = tid; i < 32 * POSD; i += 256) {
    int p = i / POSD, j = i % POSD;
    const float* pp = pts + (size_t)(base + p) * 2;
    float v;
    if (j < 2) {
      v = pp[j];
    } else if (j < 32) {
      int t = j - 2;
      v = sinf(pp[t & 1] * (float)(1 << (t >> 1)));
    } else {
      int t = j - 32;
      v = sinf(pp[t & 1] * (float)(1 << (t >> 1)) + HALFPI);
    }
    posT[j][p] = v;
  }
  __syncthreads();
  const int c = tid & 127, pg = tid >> 7;   // pg in {0,1}: 16 points each
  float acc[16];
  const float bias = peb[c];
#pragma unroll
  for (int k = 0; k < 16; ++k) acc[k] = bias;
  for (int j = 0; j < POSD; ++j) {
    float w = pew[j * WD + c];
    const float4 p0 = *(const float4*)&posT[j][pg * 16];
    const float4 p1 = *(const float4*)&posT[j][pg * 16 + 4];
    const float4 p2 = *(const float4*)&posT[j][pg * 16 + 8];
    const float4 p3 = *(const float4*)&posT[j][pg * 16 + 12];
    acc[0] += p0.x * w;  acc[1] += p0.y * w;
    acc[2] += p0.z * w;  acc[3] += p0.w * w;
    acc[4] += p1.x * w;  acc[5] += p1.y * w;
    acc[6] += p1.z * w;  acc[7] += p1.w * w;
    acc[8] += p2.x * w;  acc[9] += p2.y * w;
    acc[10] += p2.z * w; acc[11] += p2.w * w;
    acc[12] += p3.x * w; acc[13] += p3.y * w;
    acc[14] += p3.z * w; acc[15] += p3.w * w;
  }
#pragma unroll
  for (int k = 0; k < 16; ++k)
    emb[(size_t)(base + pg * 16 + k) * WD + c] = acc[k];
}

// ---------------- weight transpose: w[128][CIN][8] -> wt[CIN*8][128] -------
__global__ __launch_bounds__(256) void k_tr_w(
    const float* __restrict__ w, float* __restrict__ wt, int cin8) {
  int i = blockIdx.x * 256 + threadIdx.x;   // over 128*cin8
  if (i < 128 * cin8) {
    int c = i / cin8, rem = i % cin8;
    wt[rem * 128 + c] = w[i];
  }
}

// ---------------- ball query: first 8 indices (ascending) within radius ----
__global__ __launch_bounds__(64) void k_ballquery(
    const float* __restrict__ pts, int* __restrict__ idxo) {
  const int blk = blockIdx.x;
  const int b = blk >> 7, i = blk & 127;
  const int lane = threadIdx.x;
  __shared__ int sidx[8];
  const float cx = pts[((size_t)b * NP + i) * 2];
  const float cy = pts[((size_t)b * NP + i) * 2 + 1];
  int cnt = 0;
  for (int j0 = 0; j0 < NP; j0 += 64) {
    int j = j0 + lane;
    float dx = pts[((size_t)b * NP + j) * 2] - cx;
    float dy = pts[((size_t)b * NP + j) * 2 + 1] - cy;
    float d2 = __fadd_rn(__fmul_rn(dx, dx), __fmul_rn(dy, dy));
    bool ok = !(d2 > R2C);
    unsigned long long m = __ballot(ok);
    int ord = cnt + __popcll(m & ((1ull << lane) - 1ull));
    if (ok && ord < 8) sidx[ord] = j;
    cnt += (int)__popcll(m);
    if (cnt >= 8) break;
  }
  __syncthreads();
  if (lane < 8) {
    int v = (lane < cnt) ? sidx[lane] : sidx[0];
    idxo[blk * 8 + lane] = v;
  }
}

// ---------------- gather + conv1 + conv2 + mean -> data_tokens -------------
// 2 points/block, 256 threads (tid>>7 = point, tid&127 = out channel).
// Weights pre-transposed: w1t[(cin*8+p)*128 + c] (coalesced in c).
__global__ __launch_bounds__(256) void k_gconv(
    const float* __restrict__ pts, const float* __restrict__ emb,
    const int* __restrict__ idxs, const float* __restrict__ w1t,
    const float* __restrict__ b1, const float* __restrict__ w2t,
    const float* __restrict__ b2, float* __restrict__ dtok) {
  const int blk = blockIdx.x;          // b*64 + ip  (points i0=2*ip, +1)
  const int b = blk >> 6;
  const int i0 = (blk & 63) * 2;
  const int tid = threadIdx.x;
  const int c = tid & 127, sp = tid >> 7;
  __shared__ float f[2][8][130];
  __shared__ float y1[2][9][128];
  __shared__ int sid[2][8];
  if (tid < 16) {
    int spx = tid >> 3, s = tid & 7;
    sid[spx][s] = idxs[(blk * 2 + spx) * 8 + s];
  }
  __syncthreads();
  for (int it = tid; it < 16 * 128; it += 256) {
    int pr = it >> 7, cc = it & 127;
    int spx = pr >> 3, s = pr & 7;
    f[spx][s][2 + cc] = emb[((size_t)b * NP + sid[spx][s]) * WD + cc];
  }
  if (tid < 32) {
    int spx = tid >> 4, s = (tid >> 1) & 7, d = tid & 1;
    f[spx][s][d] = pts[((size_t)b * NP + sid[spx][s]) * 2 + d] -
                   pts[((size_t)b * NP + i0 + spx) * 2 + d];
  }
  __syncthreads();
  // conv1: out[h] = sum_p w[p]*x[(h+p+4)&7], h in 0..9
  float acc[9];
  {
    const float bb = b1[c];
#pragma unroll
    for (int h = 0; h < 9; ++h) acc[h] = bb;
  }
  for (int cin = 0; cin < 130; ++cin) {
    float wv[8];
#pragma unroll
    for (int p = 0; p < 8; ++p) wv[p] = w1t[(cin * 8 + p) * 128 + c];
    float fr[8];
#pragma unroll
    for (int s = 0; s < 8; ++s) fr[s] = f[sp][s][cin];
#pragma unroll
    for (int p = 0; p < 8; ++p)
#pragma unroll
      for (int h = 0; h < 9; ++h) acc[h] += wv[p] * fr[(h + p + 4) & 7];
  }
#pragma unroll
  for (int h = 0; h < 9; ++h) {
    float x = acc[h];
    y1[sp][h][c] = x / (1.f + expf(-x));   // silu
  }
  __syncthreads();
  // conv2: out[h] = sum_p w[p]*y[(h+p+5)%9], h in 0..10
  float a2[10];
  {
    const float bb = b2[c];
#pragma unroll
    for (int h = 0; h < 10; ++h) a2[h] = bb;
  }
  for (int cin = 0; cin < 128; ++cin) {
    float wv[8];
#pragma unroll
    for (int p = 0; p < 8; ++p) wv[p] = w2t[(cin * 8 + p) * 128 + c];
    float g[9];
#pragma unroll
    for (int s = 0; s < 9; ++s) g[s] = y1[sp][s][cin];
#pragma unroll
    for (int p = 0; p < 8; ++p)
#pragma unroll
      for (int h = 0; h < 10; ++h) a2[h] += wv[p] * g[(h + p + 5) % 9];
  }
  float s = 0.f;
#pragma unroll
  for (int h = 0; h < 10; ++h) {
    float x = a2[h];
    s += x / (1.f + expf(-x));
  }
  dtok[((size_t)b * 128 + i0 + sp) * WD + c] = s / 10.0f;
}

// ---------------- concat(data_tokens, latents) + ln_pre -> h ---------------
__global__ __launch_bounds__(64) void k_concat_ln(
    const float* __restrict__ dtok, const float* __restrict__ otok,
    const float* __restrict__ g, const float* __restrict__ bta,
    float* __restrict__ h0) {
  const int row = blockIdx.x;          // b*256 + t
  const int b = row >> 8, t = row & 255;
  const int lane = threadIdx.x;
  const float* src = (t < 128) ? (dtok + ((size_t)b * 128 + t) * WD)
                               : (otok + (size_t)(t - 128) * WD);
  const float2 x2 = *(const float2*)(src + lane * 2);
  float s = x2.x + x2.y;
  float sq = x2.x * x2.x + x2.y * x2.y;
#pragma unroll
  for (int o = 1; o < 64; o <<= 1) {
    s += __shfl_xor(s, o);
    sq += __shfl_xor(sq, o);
  }
  float m = s * (1.f / 128.f);
  float var = fmaxf(sq * (1.f / 128.f) - m * m, 0.f);
  float r = 1.0f / sqrtf(var + 1e-5f);
  int c = lane * 2;
  float2 o2;
  o2.x = (x2.x - m) * r * g[c] + bta[c];
  o2.y = (x2.y - m) * r * g[c + 1] + bta[c + 1];
  *(float2*)(h0 + (size_t)row * WD + c) = o2;
}

// ---------------- fused LN + KV projection (65536 x 128 @ 128 x 256) -------
__global__ __launch_bounds__(256) void k_kvln(
    const float* __restrict__ emb, const float* __restrict__ g,
    const float* __restrict__ bt, const float* __restrict__ wkv,
    const float* __restrict__ bkv, float* __restrict__ kbuf,
    float* __restrict__ vbuf) {
  __shared__ float xn[64 * 129];
  const int tid = threadIdx.x;
  const size_t p0 = (size_t)blockIdx.x * 64;
  for (int i = tid; i < 64 * 128; i += 256) {
    int r = i >> 7, cc = i & 127;
    xn[r * 129 + cc] = emb[(p0 + r) * WD + cc];
  }
  __syncthreads();
  if (tid < 64) {
    float s = 0.f, sq = 0.f;
    for (int k2 = 0; k2 < 128; ++k2) {
      float v = xn[tid * 129 + k2];
      s += v;
      sq += v * v;
    }
    float m = s * (1.f / 128.f);
    float var = fmaxf(sq * (1.f / 128.f) - m * m, 0.f);
    float r = 1.f / sqrtf(var + 1e-5f);
    for (int k2 = 0; k2 < 128; ++k2)
      xn[tid * 129 + k2] = (xn[tid * 129 + k2] - m) * r * g[k2] + bt[k2];
  }
  __syncthreads();
  const int w = tid >> 6, l = tid & 63;
  float4 acc[16];
#pragma unroll
  for (int p = 0; p < 16; ++p) acc[p] = make_float4(0.f, 0.f, 0.f, 0.f);
  for (int k2 = 0; k2 < 128; ++k2) {
    float4 wv = *(const float4*)(wkv + (size_t)k2 * 256 + l * 4);
#pragma unroll
    for (int p = 0; p < 16; ++p) {
      float a = xn[(w * 16 + p) * 129 + k2];
      acc[p].x += a * wv.x;
      acc[p].y += a * wv.y;
      acc[p].z += a * wv.z;
      acc[p].w += a * wv.w;
    }
  }
  float4 bv = *(const float4*)(bkv + l * 4);
#pragma unroll
  for (int p = 0; p < 16; ++p) {
    float4 o;
    o.x = acc[p].x + bv.x;
    o.y = acc[p].y + bv.y;
    o.z = acc[p].z + bv.z;
    o.w = acc[p].w + bv.w;
    size_t row = p0 + w * 16 + p;
    if (l < 32)
      *(float4*)(kbuf + row * WD + l * 4) = o;
    else
      *(float4*)(vbuf + row * WD + (l - 32) * 4) = o;
  }
}

// ---------------- MFMA bf16 flash attention (maxless), split-K -------------
__global__ __launch_bounds__(256) void k_attn_mfma(
    const float* __restrict__ Q, int qs, const float* __restrict__ K, int ks,
    const float* __restrict__ V, int vs, float* __restrict__ opart,
    float* __restrict__ lbuf, int Tk, int S, int CH) {
  const int bx = blockIdx.x;
  const int s = bx % S;
  const int bh = bx / S;
  const int h = bh & 3, b = bh >> 2;
  const int tid = threadIdx.x;
  const int w = tid >> 6, lane = tid & 63;
  const int l15 = lane & 15, l16 = lane >> 4;

  __shared__ unsigned short Kb[64 * 32];
  __shared__ unsigned short Vt[32 * 68];
  __shared__ float Pl[4][16 * 72];

  bf16x8 qf[4];
#pragma unroll
  for (int m = 0; m < 4; ++m) {
    const float* qp = Q + (size_t)(b * 256 + w * 64 + m * 16 + l15) * qs +
                      h * 32 + l16 * 8;
    float4 a = *(const float4*)qp;
    float4 bq = *(const float4*)(qp + 4);
    U16B u;
    u.h[0] = (__bf16)(a.x * QSCALE);
    u.h[1] = (__bf16)(a.y * QSCALE);
    u.h[2] = (__bf16)(a.z * QSCALE);
    u.h[3] = (__bf16)(a.w * QSCALE);
    u.h[4] = (__bf16)(bq.x * QSCALE);
    u.h[5] = (__bf16)(bq.y * QSCALE);
    u.h[6] = (__bf16)(bq.z * QSCALE);
    u.h[7] = (__bf16)(bq.w * QSCALE);
    qf[m] = u.h;
  }

  f32x4 o[4][2];
#pragma unroll
  for (int m = 0; m < 4; ++m)
#pragma unroll
    for (int d = 0; d < 2; ++d) o[m][d] = (f32x4){0.f, 0.f, 0.f, 0.f};
  float lacc[4][4];
#pragma unroll
  for (int m = 0; m < 4; ++m)
#pragma unroll
    for (int r = 0; r < 4; ++r) lacc[m][r] = 0.f;

  const int kt0 = s * CH;
  for (int kt = kt0; kt < kt0 + CH; kt += 64) {
    __syncthreads();
    {
      const int r = tid >> 2, c0 = (tid & 3) * 8;
      const float* kp = K + (size_t)(b * Tk + kt + r) * ks + h * 32 + c0;
      float4 a = *(const float4*)kp;
      float4 bb = *(const float4*)(kp + 4);
      U16B uk;
      uk.h[0] = (__bf16)a.x;  uk.h[1] = (__bf16)a.y;
      uk.h[2] = (__bf16)a.z;  uk.h[3] = (__bf16)a.w;
      uk.h[4] = (__bf16)bb.x; uk.h[5] = (__bf16)bb.y;
      uk.h[6] = (__bf16)bb.z; uk.h[7] = (__bf16)bb.w;
      *(uint4*)&Kb[r * 32 + c0] = uk.u;
      const float* vp = V + (size_t)(b * Tk + kt + r) * vs + h * 32 + c0;
      float4 va = *(const float4*)vp;
      float4 vb = *(const float4*)(vp + 4);
      U16B uv;
      uv.h[0] = (__bf16)va.x; uv.h[1] = (__bf16)va.y;
      uv.h[2] = (__bf16)va.z; uv.h[3] = (__bf16)va.w;
      uv.h[4] = (__bf16)vb.x; uv.h[5] = (__bf16)vb.y;
      uv.h[6] = (__bf16)vb.z; uv.h[7] = (__bf16)vb.w;
#pragma unroll
      for (int j = 0; j < 8; ++j) Vt[(c0 + j) * 68 + r] = uv.s[j];
    }
    __syncthreads();

    bf16x8 kf[4];
#pragma unroll
    for (int ksb = 0; ksb < 4; ++ksb) {
      U16B u;
      u.u = *(const uint4*)&Kb[(ksb * 16 + l15) * 32 + l16 * 8];
      kf[ksb] = u.h;
    }
    bf16x8 vf[2][2];
#pragma unroll
    for (int kc = 0; kc < 2; ++kc)
#pragma unroll
      for (int d = 0; d < 2; ++d) {
        const unsigned short* vp =
            &Vt[(l15 + 16 * d) * 68 + kc * 32 + l16 * 8];
        U16B u;
        *(uint2*)&u.s[0] = *(const uint2*)vp;
        *(uint2*)&u.s[4] = *(const uint2*)(vp + 4);
        vf[kc][d] = u.h;
      }

#pragma unroll
    for (int m = 0; m < 4; ++m) {
      const f32x4 zf = {0.f, 0.f, 0.f, 0.f};
      f32x4 sf[4];
#pragma unroll
      for (int ksb = 0; ksb < 4; ++ksb)
        sf[ksb] = __builtin_amdgcn_mfma_f32_16x16x32_bf16(qf[m], kf[ksb], zf,
                                                          0, 0, 0);
      float pv[4][4];
      float ps[4] = {0.f, 0.f, 0.f, 0.f};
#pragma unroll
      for (int ksb = 0; ksb < 4; ++ksb)
#pragma unroll
        for (int r = 0; r < 4; ++r) {
          float p = expf(sf[ksb][r]);
          pv[ksb][r] = p;
          ps[r] += p;
        }
#pragma unroll
      for (int r = 0; r < 4; ++r) {
        float v = ps[r];
        v += __shfl_xor(v, 1);
        v += __shfl_xor(v, 2);
        v += __shfl_xor(v, 4);
        v += __shfl_xor(v, 8);
        lacc[m][r] += v;
      }
#pragma unroll
      for (int ksb = 0; ksb < 4; ++ksb)
#pragma unroll
        for (int r = 0; r < 4; ++r)
          Pl[w][(l16 * 4 + r) * 72 + ksb * 16 + l15] = pv[ksb][r];
      asm volatile("s_waitcnt lgkmcnt(0)" ::: "memory");
      bf16x8 pa[2];
#pragma unroll
      for (int kc = 0; kc < 2; ++kc) {
        const float* pr = &Pl[w][l15 * 72 + l16 * 8 + kc * 32];
        float4 p0 = *(const float4*)pr;
        float4 p1 = *(const float4*)(pr + 4);
        U16B u;
        u.h[0] = (__bf16)p0.x; u.h[1] = (__bf16)p0.y;
        u.h[2] = (__bf16)p0.z; u.h[3] = (__bf16)p0.w;
        u.h[4] = (__bf16)p1.x; u.h[5] = (__bf16)p1.y;
        u.h[6] = (__bf16)p1.z; u.h[7] = (__bf16)p1.w;
        pa[kc] = u.h;
      }
#pragma unroll
      for (int kc = 0; kc < 2; ++kc)
#pragma unroll
        for (int d = 0; d < 2; ++d)
          o[m][d] = __builtin_amdgcn_mfma_f32_16x16x32_bf16(pa[kc], vf[kc][d],
                                                            o[m][d], 0, 0, 0);
    }
  }

  const size_t ob = (size_t)bx * 8192;
#pragma unroll
  for (int m = 0; m < 4; ++m) {
    int qrow = w * 64 + m * 16 + l16 * 4;
#pragma unroll
    for (int r = 0; r < 4; ++r) {
#pragma unroll
      for (int d = 0; d < 2; ++d)
        opart[ob + (qrow + r) * 32 + d * 16 + l15] = o[m][d][r];
      if (l15 == 0) lbuf[(size_t)bx * 256 + qrow + r] = lacc[m][r];
    }
  }
}

// ---------------- combine S partials -> O ----------------------------------
__global__ __launch_bounds__(256) void k_attn_comb(
    const float* __restrict__ opart, const float* __restrict__ lbuf,
    float* __restrict__ O, int S) {
  const int bx = blockIdx.x;
  const int qt = bx & 7, h = (bx >> 3) & 3, b = bx >> 5;
  const int tid = threadIdx.x;
  const int qq = tid >> 3, g = tid & 7;
  const int q = qt * 32 + qq;
  const int pb = (b * 4 + h) * S;
  float L = 0.f;
  float4 o4 = make_float4(0.f, 0.f, 0.f, 0.f);
  for (int s = 0; s < S; ++s) {
    L += lbuf[(size_t)(pb + s) * 256 + q];
    float4 p4 = *(const float4*)(opart + (size_t)(pb + s) * 8192 + q * 32 + g * 4);
    o4.x += p4.x;
    o4.y += p4.y;
    o4.z += p4.z;
    o4.w += p4.w;
  }
  float inv = 1.f / L;
  size_t orow = (size_t)(b * 256 + q);
  float4 res = make_float4(o4.x * inv, o4.y * inv, o4.z * inv, o4.w * inv);
  *(float4*)(O + orow * WD + h * 32 + g * 4) = res;
}

// ---------------- GEMM: D[M,N] = act(LN?(A)[M,K] @ W[K,N] + bias) + res ----
// 16-row tiles (grid.x = M/16), col chunks of NV*64 (grid.y). block = 256.
// act: 0 none, 1 gelu, 2 tanh. LN fusion requires K==128.
template <int NV>
__global__ __launch_bounds__(256) void k_gemm(
    const float* __restrict__ A, int lda, const float* __restrict__ Wt,
    int ldw, const float* __restrict__ bias, const float* __restrict__ res,
    int ldres, float* __restrict__ D, int ldd, int K, int act,
    const float* __restrict__ lnS, const float* __restrict__ lnB, int keep,
    int skip) {
  __shared__ float alds[16 * 132];
  const int tid = threadIdx.x;
  const int row0 = blockIdx.x * 16;
  const int col0 = blockIdx.y * NV * 64;
  const int w = tid >> 6, l = tid & 63;
  float acc[4][NV];
#pragma unroll
  for (int r = 0; r < 4; ++r)
#pragma unroll
    for (int j = 0; j < NV; ++j) acc[r][j] = 0.f;
  for (int kt = 0; kt < K; kt += 128) {
    __syncthreads();
    for (int i = tid; i < 16 * 128; i += 256) {
      int r = i >> 7, cc = i & 127;
      int grow = row0 + r;
      int srow = (grow / keep) * (keep + skip) + skip + grow % keep;
      alds[r * 132 + cc] = A[(size_t)srow * lda + kt + cc];
    }
    __syncthreads();
    if (lnS != nullptr && kt == 0) {
      const int r = tid >> 4, part = tid & 15;
      float s = 0.f, sq = 0.f;
#pragma unroll
      for (int c = part * 8; c < part * 8 + 8; ++c) {
        float v = alds[r * 132 + c];
        s += v;
        sq += v * v;
      }
      s += __shfl_xor(s, 1);  sq += __shfl_xor(sq, 1);
      s += __shfl_xor(s, 2);  sq += __shfl_xor(sq, 2);
      s += __shfl_xor(s, 4);  sq += __shfl_xor(sq, 4);
      s += __shfl_xor(s, 8);  sq += __shfl_xor(sq, 8);
      float m = s * (1.f / 128.f);
      float var = fmaxf(sq * (1.f / 128.f) - m * m, 0.f);
      float rinv = 1.0f / sqrtf(var + 1e-5f);
#pragma unroll
      for (int c = part * 8; c < part * 8 + 8; ++c)
        alds[r * 132 + c] = (alds[r * 132 + c] - m) * rinv * lnS[c] + lnB[c];
      __syncthreads();
    }
    for (int k2 = 0; k2 < 128; k2 += 4) {
      float wv[4][NV];
#pragma unroll
      for (int u = 0; u < 4; ++u)
#pragma unroll
        for (int j = 0; j < NV; ++j)
          wv[u][j] = Wt[(size_t)(kt + k2 + u) * ldw + col0 + l + 64 * j];
#pragma unroll
      for (int u = 0; u < 4; ++u)
#pragma unroll
        for (int r = 0; r < 4; ++r) {
          float a = alds[(w * 4 + r) * 132 + k2 + u];
#pragma unroll
          for (int j = 0; j < NV; ++j) acc[r][j] += a * wv[u][j];
        }
    }
  }
#pragma unroll
  for (int r = 0; r < 4; ++r) {
    size_t row = row0 + w * 4 + r;
#pragma unroll
    for (int j = 0; j < NV; ++j) {
      int col = col0 + l + 64 * j;
      float x = acc[r][j] + bias[col];
      if (act == 1) x = 0.5f * x * (1.0f + erff(x * 0.7071067811865476f));
      else if (act == 2) x = tanhf(x);
      if (res != nullptr) x += res[row * ldres + col];
      D[row * ldd + col] = x;
    }
  }
}

}  // namespace

// ---------------------------------------------------------------------------
extern "C" void kernel_launch(void* const* d_in, const int* in_sizes, int n_in,
                              void* d_out, int out_size, void* d_ws,
                              size_t ws_size, hipStream_t stream) {
  const float* pts      = (const float*)d_in[0];
  const float* pe_w     = (const float*)d_in[1];
  const float* pe_b     = (const float*)d_in[2];
  const float* conv1_w  = (const float*)d_in[3];
  const float* conv1_b  = (const float*)d_in[4];
  const float* conv2_w  = (const float*)d_in[5];
  const float* conv2_b  = (const float*)d_in[6];
  const float* otok     = (const float*)d_in[7];
  const float* ln_pre_s = (const float*)d_in[8];
  const float* ln_pre_b = (const float*)d_in[9];
  const float* c_ln1_s  = (const float*)d_in[10];
  const float* c_ln1_b  = (const float*)d_in[11];
  const float* c_ln2_s  = (const float*)d_in[12];
  const float* c_ln2_b  = (const float*)d_in[13];
  const float* c_q_w    = (const float*)d_in[14];
  const float* c_q_b    = (const float*)d_in[15];
  const float* c_kv_w   = (const float*)d_in[16];
  const float* c_kv_b   = (const float*)d_in[17];
  const float* c_proj_w = (const float*)d_in[18];
  const float* c_proj_b = (const float*)d_in[19];
  const float* c_ln3_s  = (const float*)d_in[20];
  const float* c_ln3_b  = (const float*)d_in[21];
  const float* c_mlp1_w = (const float*)d_in[22];
  const float* c_mlp1_b = (const float*)d_in[23];
  const float* c_mlp2_w = (const float*)d_in[24];
  const float* c_mlp2_b = (const float*)d_in[25];
  const float* s_ln1_s  = (const float*)d_in[26];
  const float* s_ln1_b  = (const float*)d_in[27];
  const float* s_qkv_w  = (const float*)d_in[28];
  const float* s_qkv_b  = (const float*)d_in[29];
  const float* s_proj_w = (const float*)d_in[30];
  const float* s_proj_b = (const float*)d_in[31];
  const float* s_ln2_s  = (const float*)d_in[32];
  const float* s_ln2_b  = (const float*)d_in[33];
  const float* s_mlp1_w = (const float*)d_in[34];
  const float* s_mlp1_b = (const float*)d_in[35];
  const float* s_mlp2_w = (const float*)d_in[36];
  const float* s_mlp2_b = (const float*)d_in[37];
  const float* lnpost_s = (const float*)d_in[38];
  const float* lnpost_b = (const float*)d_in[39];
  const float* out_w    = (const float*)d_in[40];
  const float* out_b    = (const float*)d_in[41];

  char* ws = (char*)d_ws;
  constexpr size_t SZ_EMB = (size_t)65536 * 128 * 4;  // 32 MB
  float* emb  = (float*)(ws);
  float* kbuf = (float*)(ws + SZ_EMB);
  float* vbuf = (float*)(ws + 2 * SZ_EMB);
  int*   idx  = (int*)(ws + 3 * SZ_EMB);
  float* dtok = (float*)(ws + 3 * SZ_EMB + 65536);
  float* hbuf = (float*)(ws + 3 * SZ_EMB + 65536 + 524288);
  float* qbuf = (float*)(ws + 3 * SZ_EMB + 65536 + 524288 + 2 * 1048576);
  float* att  = (float*)(ws + 3 * SZ_EMB + 65536 + 524288 + 3 * 1048576);
  float* mid  = (float*)(ws + 3 * SZ_EMB + 65536 + 524288 + 4 * 1048576);
  char*  qkvp = ws + 3 * SZ_EMB + 65536 + 524288 + 4 * 1048576 + 4194304;
  float* qkv  = (float*)qkvp;
  float* w1t  = (float*)(qkvp + 3145728);            // 130*8*128 f = 532480 B
  float* w2t  = (float*)(qkvp + 3145728 + 532480);   // 128*8*128 f = 524288 B
  // attention partials overlay the emb region (emb dead after k_kvln):
  float* opart = (float*)(ws);
  float* lbuf  = (float*)(ws + 24 * 1024 * 1024);

  const int IDK = 1 << 28;

  // 1) dataset_emb + weight transposes (independent)
  k_posenc<<<2048, 256, 0, stream>>>(pts, pe_w, pe_b, emb);
  k_tr_w<<<(128 * 130 * 8 + 255) / 256, 256, 0, stream>>>(conv1_w, w1t, 1040);
  k_tr_w<<<(128 * 128 * 8 + 255) / 256, 256, 0, stream>>>(conv2_w, w2t, 1024);
  // 2) ball query
  k_ballquery<<<1024, 64, 0, stream>>>(pts, idx);
  // 3) gather + conv stack -> data_tokens
  k_gconv<<<512, 256, 0, stream>>>(pts, emb, idx, w1t, conv1_b, w2t, conv2_b,
                                   dtok);
  // 4) concat + ln_pre -> h
  k_concat_ln<<<2048, 64, 0, stream>>>(dtok, otok, ln_pre_s, ln_pre_b, hbuf);
  // 5) K,V from dataset_emb (fused LN) [last reader of emb]
  k_kvln<<<1024, 256, 0, stream>>>(emb, c_ln2_s, c_ln2_b, c_kv_w, c_kv_b, kbuf,
                                   vbuf);
  // 6) cross attention block (MFMA, S=16 chunks of 512 keys)
  k_gemm<2><<<dim3(128, 1), 256, 0, stream>>>(
      hbuf, 128, c_q_w, 128, c_q_b, nullptr, 0, qbuf, 128, 128, 0, c_ln1_s,
      c_ln1_b, IDK, 0);
  k_attn_mfma<<<512, 256, 0, stream>>>(qbuf, 128, kbuf, 128, vbuf, 128, opart,
                                       lbuf, 8192, 16, 512);
  k_attn_comb<<<256, 256, 0, stream>>>(opart, lbuf, att, 16);
  k_gemm<2><<<dim3(128, 1), 256, 0, stream>>>(
      att, 128, c_proj_w, 128, c_proj_b, hbuf, 128, hbuf, 128, 128, 0, nullptr,
      nullptr, IDK, 0);
  k_gemm<2><<<dim3(128, 4), 256, 0, stream>>>(
      hbuf, 128, c_mlp1_w, 512, c_mlp1_b, nullptr, 0, mid, 512, 128, 1,
      c_ln3_s, c_ln3_b, IDK, 0);
  k_gemm<2><<<dim3(128, 1), 256, 0, stream>>>(
      mid, 512, c_mlp2_w, 128, c_mlp2_b, hbuf, 128, hbuf, 128, 512, 0, nullptr,
      nullptr, IDK, 0);
  // 7) self-attention blocks (MFMA, S=4 chunks of 64 keys)
  for (int i = 0; i < 3; ++i) {
    k_gemm<2><<<dim3(128, 3), 256, 0, stream>>>(
        hbuf, 128, s_qkv_w + (size_t)i * 128 * 384, 384, s_qkv_b + i * 384,
        nullptr, 0, qkv, 384, 128, 0, s_ln1_s + i * 128, s_ln1_b + i * 128,
        IDK, 0);
    k_attn_mfma<<<128, 256, 0, stream>>>(qkv, 384, qkv + 128, 384, qkv + 256,
                                         384, opart, lbuf, 256, 4, 64);
    k_attn_comb<<<256, 256, 0, stream>>>(opart, lbuf, att, 4);
    k_gemm<2><<<dim3(128, 1), 256, 0, stream>>>(
        att, 128, s_proj_w + (size_t)i * 16384, 128, s_proj_b + i * 128, hbuf,
        128, hbuf, 128, 128, 0, nullptr, nullptr, IDK, 0);
    k_gemm<2><<<dim3(128, 4), 256, 0, stream>>>(
        hbuf, 128, s_mlp1_w + (size_t)i * 65536, 512, s_mlp1_b + i * 512,
        nullptr, 0, mid, 512, 128, 1, s_ln2_s + i * 128, s_ln2_b + i * 128,
        IDK, 0);
    k_gemm<2><<<dim3(128, 1), 256, 0, stream>>>(
        mid, 512, s_mlp2_w + (size_t)i * 65536, 128, s_mlp2_b + i * 128, hbuf,
        128, hbuf, 128, 512, 0, nullptr, nullptr, IDK, 0);
  }
  // 8) final LN (last 128 tokens of each batch) + output head with tanh
  k_gemm<2><<<dim3(64, 1), 256, 0, stream>>>(
      hbuf, 128, out_w, 128, out_b, nullptr, 0, (float*)d_out, 128, 128, 2,
      lnpost_s, lnpost_b, 128, 128);
}

// Round 5
// 614.558 us; speedup vs baseline: 2.6314x; 1.1179x over previous
//
#include <hip/hip_runtime.h>
#include <math.h>

// ---------------------------------------------------------------------------
// PointCloudPerceiverChannelsEncoder — round 4:
//  - kv/q projections -> bf16 MFMA LN-GEMM (consumed as bf16 in attn anyway)
//  - f32 gemms: NV=1 (2-4x grid), float4 LDS broadcast inner loop
//  - gconv: circular-dup h elimination, slot-contiguous LDS, packed weights,
//    ballquery fused in
// ---------------------------------------------------------------------------

namespace {

constexpr int NP = 8192;
constexpr int WD = 128;
constexpr int POSD = 62;
constexpr float R2C = 0.04f;
constexpr float QSCALE = 0.17677669529663687f;    // 1/sqrt(32)
constexpr float HALFPI = 1.5707963705062866f;

typedef __bf16 bf16x8 __attribute__((ext_vector_type(8)));
typedef float f32x4 __attribute__((ext_vector_type(4)));
union U16B { uint4 u; bf16x8 h; unsigned short s[8]; };

// ---------------- posenc + pe GEMM: emb[65536][128] -------------------------
__global__ __launch_bounds__(256) void k_posenc(
    const float* __restrict__ pts, const float* __restrict__ pew,
    const float* __restrict__ peb, float* __restrict__ emb) {
  __shared__ float posT[62][36];
  const int tid = threadIdx.x;
  const int base = blockIdx.x * 32;
  for (int i = tid; i < 32 * POSD; i += 256) {
    int p = i / POSD, j = i % POSD;
    const float* pp = pts + (size_t)(base + p) * 2;
    float v;
    if (j < 2) {
      v = pp[j];
    } else if (j < 32) {
      int t = j - 2;
      v = sinf(pp[t & 1] * (float)(1 << (t >> 1)));
    } else {
      int t = j - 32;
      v = sinf(pp[t & 1] * (float)(1 << (t >> 1)) + HALFPI);
    }
    posT[j][p] = v;
  }
  __syncthreads();
  const int c = tid & 127, pg = tid >> 7;
  float acc[16];
  const float bias = peb[c];
#pragma unroll
  for (int k = 0; k < 16; ++k) acc[k] = bias;
  for (int j = 0; j < POSD; ++j) {
    float w = pew[j * WD + c];
    const float4 p0 = *(const float4*)&posT[j][pg * 16];
    const float4 p1 = *(const float4*)&posT[j][pg * 16 + 4];
    const float4 p2 = *(const float4*)&posT[j][pg * 16 + 8];
    const float4 p3 = *(const float4*)&posT[j][pg * 16 + 12];
    acc[0] += p0.x * w;  acc[1] += p0.y * w;
    acc[2] += p0.z * w;  acc[3] += p0.w * w;
    acc[4] += p1.x * w;  acc[5] += p1.y * w;
    acc[6] += p1.z * w;  acc[7] += p1.w * w;
    acc[8] += p2.x * w;  acc[9] += p2.y * w;
    acc[10] += p2.z * w; acc[11] += p2.w * w;
    acc[12] += p3.x * w; acc[13] += p3.y * w;
    acc[14] += p3.z * w; acc[15] += p3.w * w;
  }
#pragma unroll
  for (int k = 0; k < 16; ++k)
    emb[(size_t)(base + pg * 16 + k) * WD + c] = acc[k];
}

// ---------------- prep: conv weight repack + q/kv weight bf16 transpose ----
// w1p[(cin*128+c)*8+p] = w1[(c*130+cin)*8+p]; similarly w2p (128 cin).
// wqt[n*128+k] = bf16(wq[k*128+n]); wkvt[n*128+k] = bf16(wkv[k*256+n]).
__global__ __launch_bounds__(256) void k_prep(
    const float* __restrict__ w1, const float* __restrict__ w2,
    const float* __restrict__ wq, const float* __restrict__ wkv,
    float* __restrict__ w1p, float* __restrict__ w2p,
    __bf16* __restrict__ wqt, __bf16* __restrict__ wkvt) {
  int i = blockIdx.x * 256 + threadIdx.x;
  if (i < 133120) {
    int cin = i >> 10, c = (i >> 3) & 127, p = i & 7;
    w1p[i] = w1[((size_t)c * 130 + cin) * 8 + p];
  } else if (i < 264192) {
    int j = i - 133120;
    int cin = j >> 10, c = (j >> 3) & 127, p = j & 7;
    w2p[j] = w2[((size_t)c * 128 + cin) * 8 + p];
  } else if (i < 280576) {
    int j = i - 264192;
    int n = j >> 7, k = j & 127;
    wqt[j] = (__bf16)wq[k * 128 + n];
  } else if (i < 313344) {
    int j = i - 280576;
    int n = j >> 7, k = j & 127;
    wkvt[j] = (__bf16)wkv[k * 256 + n];
  }
}

// ---------------- gather + conv1 + conv2 + mean (ballquery fused) ----------
// 2 points/block, 256 threads. conv1: 8 distinct h (out[8]==out[0]);
// conv2: 9 distinct h (out[9]==out[0], double-counted in mean).
__global__ __launch_bounds__(256) void k_gconv(
    const float* __restrict__ pts, const float* __restrict__ emb,
    const float* __restrict__ w1p, const float* __restrict__ b1,
    const float* __restrict__ w2p, const float* __restrict__ b2,
    float* __restrict__ dtok) {
  const int blk = blockIdx.x;          // b*64 + ip
  const int b = blk >> 6;
  const int i0 = (blk & 63) * 2;
  const int tid = threadIdx.x;
  const int c = tid & 127, sp = tid >> 7;
  const int wv = tid >> 6, lane = tid & 63;
  __shared__ float ft[2][132][8];      // [pt][cin][slot]
  __shared__ float y1t[2][128][12];    // [pt][cin][h 0..8]
  __shared__ int sid[2][8];
  // ---- inline ball query: waves 0,1 scan points i0, i0+1
  if (wv < 2) {
    const int i = i0 + wv;
    const float cx = pts[((size_t)b * NP + i) * 2];
    const float cy = pts[((size_t)b * NP + i) * 2 + 1];
    int cnt = 0;
    for (int j0 = 0; j0 < NP; j0 += 64) {
      int j = j0 + lane;
      float dx = pts[((size_t)b * NP + j) * 2] - cx;
      float dy = pts[((size_t)b * NP + j) * 2 + 1] - cy;
      float d2 = __fadd_rn(__fmul_rn(dx, dx), __fmul_rn(dy, dy));
      bool ok = !(d2 > R2C);
      unsigned long long m = __ballot(ok);
      int ord = cnt + __popcll(m & ((1ull << lane) - 1ull));
      if (ok && ord < 8) sid[wv][ord] = j;
      cnt += (int)__popcll(m);
      if (cnt >= 8) break;
    }
    if (lane < 8 && lane >= cnt) sid[wv][lane] = sid[wv][0];
  }
  __syncthreads();
  // ---- gather features (slot-contiguous layout)
  for (int it = tid; it < 16 * 128; it += 256) {
    int pr = it >> 7, cc = it & 127;
    int spx = pr >> 3, s = pr & 7;
    ft[spx][2 + cc][s] = emb[((size_t)b * NP + sid[spx][s]) * WD + cc];
  }
  if (tid < 32) {
    int spx = tid >> 4, s = (tid >> 1) & 7, d = tid & 1;
    ft[spx][d][s] = pts[((size_t)b * NP + sid[spx][s]) * 2 + d] -
                    pts[((size_t)b * NP + i0 + spx) * 2 + d];
  }
  __syncthreads();
  // ---- conv1: out[h] = sum_p w[p]*x[(h+p+4)&7], h = 0..7
  float acc[8];
  {
    const float bb = b1[c];
#pragma unroll
    for (int h = 0; h < 8; ++h) acc[h] = bb;
  }
  for (int cin = 0; cin < 130; ++cin) {
    const float* wr = w1p + ((size_t)cin * 128 + c) * 8;
    const float4 w03 = *(const float4*)wr;
    const float4 w47 = *(const float4*)(wr + 4);
    const float wvv[8] = {w03.x, w03.y, w03.z, w03.w,
                          w47.x, w47.y, w47.z, w47.w};
    const float4 f03 = *(const float4*)&ft[sp][cin][0];
    const float4 f47 = *(const float4*)&ft[sp][cin][4];
    const float fr[8] = {f03.x, f03.y, f03.z, f03.w,
                         f47.x, f47.y, f47.z, f47.w};
#pragma unroll
    for (int p = 0; p < 8; ++p)
#pragma unroll
      for (int h = 0; h < 8; ++h) acc[h] += wvv[p] * fr[(h + p + 4) & 7];
  }
#pragma unroll
  for (int h = 0; h < 8; ++h) {
    float x = acc[h];
    y1t[sp][c][h] = x / (1.f + expf(-x));   // silu
  }
  y1t[sp][c][8] = y1t[sp][c][0];            // circular duplicate (bitwise)
  __syncthreads();
  // ---- conv2: out[h] = sum_p w[p]*y[(h+p+5)%9], h = 0..8 (out[9]==out[0])
  float a2[9];
  {
    const float bb = b2[c];
#pragma unroll
    for (int h = 0; h < 9; ++h) a2[h] = bb;
  }
  for (int cin = 0; cin < 128; ++cin) {
    const float* wr = w2p + ((size_t)cin * 128 + c) * 8;
    const float4 w03 = *(const float4*)wr;
    const float4 w47 = *(const float4*)(wr + 4);
    const float wvv[8] = {w03.x, w03.y, w03.z, w03.w,
                          w47.x, w47.y, w47.z, w47.w};
    const float4 g03 = *(const float4*)&y1t[sp][cin][0];
    const float4 g47 = *(const float4*)&y1t[sp][cin][4];
    const float g8 = y1t[sp][cin][8];
    const float g[9] = {g03.x, g03.y, g03.z, g03.w,
                        g47.x, g47.y, g47.z, g47.w, g8};
#pragma unroll
    for (int p = 0; p < 8; ++p)
#pragma unroll
      for (int h = 0; h < 9; ++h) a2[h] += wvv[p] * g[(h + p + 5) % 9];
  }
  float s = 0.f;
#pragma unroll
  for (int h = 0; h < 9; ++h) {
    float x = a2[h];
    s += x / (1.f + expf(-x));
  }
  {
    float x = a2[0];
    s += x / (1.f + expf(-x));   // h=9 duplicate, same order as reference
  }
  dtok[((size_t)b * 128 + i0 + sp) * WD + c] = s / 10.0f;
}

// ---------------- concat(data_tokens, latents) + ln_pre -> h ---------------
__global__ __launch_bounds__(64) void k_concat_ln(
    const float* __restrict__ dtok, const float* __restrict__ otok,
    const float* __restrict__ g, const float* __restrict__ bta,
    float* __restrict__ h0) {
  const int row = blockIdx.x;
  const int b = row >> 8, t = row & 255;
  const int lane = threadIdx.x;
  const float* src = (t < 128) ? (dtok + ((size_t)b * 128 + t) * WD)
                               : (otok + (size_t)(t - 128) * WD);
  const float2 x2 = *(const float2*)(src + lane * 2);
  float s = x2.x + x2.y;
  float sq = x2.x * x2.x + x2.y * x2.y;
#pragma unroll
  for (int o = 1; o < 64; o <<= 1) {
    s += __shfl_xor(s, o);
    sq += __shfl_xor(sq, o);
  }
  float m = s * (1.f / 128.f);
  float var = fmaxf(sq * (1.f / 128.f) - m * m, 0.f);
  float r = 1.0f / sqrtf(var + 1e-5f);
  int c = lane * 2;
  float2 o2;
  o2.x = (x2.x - m) * r * g[c] + bta[c];
  o2.y = (x2.y - m) * r * g[c + 1] + bta[c + 1];
  *(float2*)(h0 + (size_t)row * WD + c) = o2;
}

// ---------------- bf16 MFMA LN-GEMM: D = LN(A)[M][128] @ W[128][N] + bias --
// BM=32, BN=128. grid (M/32, N/128). wt = bf16 pre-transposed [n][k=128].
// Dual output: if D1 != null, blockIdx.y==0 -> D0, ==1 -> D1 (local cols).
__global__ __launch_bounds__(256) void k_lngemm(
    const float* __restrict__ A, int lda, const __bf16* __restrict__ wt,
    const float* __restrict__ bias, float* __restrict__ D0,
    float* __restrict__ D1, int ldd, const float* __restrict__ lnS,
    const float* __restrict__ lnB) {
  __shared__ unsigned short Ab[32][136];
  __shared__ unsigned short Bt[128][136];
  const int tid = threadIdx.x;
  const int row0 = blockIdx.x * 32;
  const int nblk = blockIdx.y;
  // stage B: n-row = tid>>1, half = tid&1
  {
    const int n = tid >> 1, hf = tid & 1;
    const __bf16* src = wt + ((size_t)(nblk * 128 + n) * 128 + hf * 64);
#pragma unroll
    for (int q8 = 0; q8 < 8; ++q8)
      *(uint4*)&Bt[n][hf * 64 + q8 * 8] = *(const uint4*)(src + q8 * 8);
  }
  // stage A with LN: row = tid>>3, seg = tid&7 (16 cols each)
  {
    const int r = tid >> 3, seg = tid & 7;
    const float* ap = A + (size_t)(row0 + r) * lda + seg * 16;
    float4 v0 = *(const float4*)ap;
    float4 v1 = *(const float4*)(ap + 4);
    float4 v2 = *(const float4*)(ap + 8);
    float4 v3 = *(const float4*)(ap + 12);
    float s = v0.x + v0.y + v0.z + v0.w + v1.x + v1.y + v1.z + v1.w +
              v2.x + v2.y + v2.z + v2.w + v3.x + v3.y + v3.z + v3.w;
    float sq = v0.x * v0.x + v0.y * v0.y + v0.z * v0.z + v0.w * v0.w +
               v1.x * v1.x + v1.y * v1.y + v1.z * v1.z + v1.w * v1.w +
               v2.x * v2.x + v2.y * v2.y + v2.z * v2.z + v2.w * v2.w +
               v3.x * v3.x + v3.y * v3.y + v3.z * v3.z + v3.w * v3.w;
    s += __shfl_xor(s, 1);  sq += __shfl_xor(sq, 1);
    s += __shfl_xor(s, 2);  sq += __shfl_xor(sq, 2);
    s += __shfl_xor(s, 4);  sq += __shfl_xor(sq, 4);
    const float m = s * (1.f / 128.f);
    const float var = fmaxf(sq * (1.f / 128.f) - m * m, 0.f);
    const float rinv = 1.0f / sqrtf(var + 1e-5f);
    float xv[16] = {v0.x, v0.y, v0.z, v0.w, v1.x, v1.y, v1.z, v1.w,
                    v2.x, v2.y, v2.z, v2.w, v3.x, v3.y, v3.z, v3.w};
    U16B u0, u1;
#pragma unroll
    for (int j = 0; j < 16; ++j) {
      int col = seg * 16 + j;
      float y = (xv[j] - m) * rinv * lnS[col] + lnB[col];
      if (j < 8) u0.h[j] = (__bf16)y; else u1.h[j - 8] = (__bf16)y;
    }
    *(uint4*)&Ab[r][seg * 16] = u0.u;
    *(uint4*)&Ab[r][seg * 16 + 8] = u1.u;
  }
  __syncthreads();
  // compute: wave w: row-tile rt = w>>1, col-half ch = w&1 (4 col-tiles)
  const int w = tid >> 6, lane = tid & 63;
  const int l15 = lane & 15, l16 = lane >> 4;
  const int rt = w >> 1, ch = w & 1;
  f32x4 acc[4];
#pragma unroll
  for (int j = 0; j < 4; ++j) acc[j] = (f32x4){0.f, 0.f, 0.f, 0.f};
#pragma unroll
  for (int kk = 0; kk < 4; ++kk) {
    U16B ua;
    ua.u = *(const uint4*)&Ab[rt * 16 + l15][kk * 32 + l16 * 8];
#pragma unroll
    for (int ct4 = 0; ct4 < 4; ++ct4) {
      U16B ub;
      ub.u = *(const uint4*)&Bt[(ch * 4 + ct4) * 16 + l15][kk * 32 + l16 * 8];
      acc[ct4] = __builtin_amdgcn_mfma_f32_16x16x32_bf16(ua.h, ub.h, acc[ct4],
                                                         0, 0, 0);
    }
  }
  float* Dp = (D1 != nullptr && nblk == 1) ? D1 : D0;
  const int cbase = (D1 != nullptr) ? 0 : nblk * 128;
#pragma unroll
  for (int ct4 = 0; ct4 < 4; ++ct4) {
    int colL = (ch * 4 + ct4) * 16 + l15;
    float bv = bias[nblk * 128 + colL];
#pragma unroll
    for (int r = 0; r < 4; ++r) {
      int row = row0 + rt * 16 + l16 * 4 + r;
      Dp[(size_t)row * ldd + cbase + colL] = acc[ct4][r] + bv;
    }
  }
}

// ---------------- MFMA bf16 flash attention (maxless), split-K -------------
__global__ __launch_bounds__(256) void k_attn_mfma(
    const float* __restrict__ Q, int qs, const float* __restrict__ K, int ks,
    const float* __restrict__ V, int vs, float* __restrict__ opart,
    float* __restrict__ lbuf, int Tk, int S, int CH) {
  const int bx = blockIdx.x;
  const int s = bx % S;
  const int bh = bx / S;
  const int h = bh & 3, b = bh >> 2;
  const int tid = threadIdx.x;
  const int w = tid >> 6, lane = tid & 63;
  const int l15 = lane & 15, l16 = lane >> 4;

  __shared__ unsigned short Kb[64 * 32];
  __shared__ unsigned short Vt[32 * 68];
  __shared__ float Pl[4][16 * 72];

  bf16x8 qf[4];
#pragma unroll
  for (int m = 0; m < 4; ++m) {
    const float* qp = Q + (size_t)(b * 256 + w * 64 + m * 16 + l15) * qs +
                      h * 32 + l16 * 8;
    float4 a = *(const float4*)qp;
    float4 bq = *(const float4*)(qp + 4);
    U16B u;
    u.h[0] = (__bf16)(a.x * QSCALE);
    u.h[1] = (__bf16)(a.y * QSCALE);
    u.h[2] = (__bf16)(a.z * QSCALE);
    u.h[3] = (__bf16)(a.w * QSCALE);
    u.h[4] = (__bf16)(bq.x * QSCALE);
    u.h[5] = (__bf16)(bq.y * QSCALE);
    u.h[6] = (__bf16)(bq.z * QSCALE);
    u.h[7] = (__bf16)(bq.w * QSCALE);
    qf[m] = u.h;
  }

  f32x4 o[4][2];
#pragma unroll
  for (int m = 0; m < 4; ++m)
#pragma unroll
    for (int d = 0; d < 2; ++d) o[m][d] = (f32x4){0.f, 0.f, 0.f, 0.f};
  float lacc[4][4];
#pragma unroll
  for (int m = 0; m < 4; ++m)
#pragma unroll
    for (int r = 0; r < 4; ++r) lacc[m][r] = 0.f;

  const int kt0 = s * CH;
  for (int kt = kt0; kt < kt0 + CH; kt += 64) {
    __syncthreads();
    {
      const int r = tid >> 2, c0 = (tid & 3) * 8;
      const float* kp = K + (size_t)(b * Tk + kt + r) * ks + h * 32 + c0;
      float4 a = *(const float4*)kp;
      float4 bb = *(const float4*)(kp + 4);
      U16B uk;
      uk.h[0] = (__bf16)a.x;  uk.h[1] = (__bf16)a.y;
      uk.h[2] = (__bf16)a.z;  uk.h[3] = (__bf16)a.w;
      uk.h[4] = (__bf16)bb.x; uk.h[5] = (__bf16)bb.y;
      uk.h[6] = (__bf16)bb.z; uk.h[7] = (__bf16)bb.w;
      *(uint4*)&Kb[r * 32 + c0] = uk.u;
      const float* vp = V + (size_t)(b * Tk + kt + r) * vs + h * 32 + c0;
      float4 va = *(const float4*)vp;
      float4 vb = *(const float4*)(vp + 4);
      U16B uv;
      uv.h[0] = (__bf16)va.x; uv.h[1] = (__bf16)va.y;
      uv.h[2] = (__bf16)va.z; uv.h[3] = (__bf16)va.w;
      uv.h[4] = (__bf16)vb.x; uv.h[5] = (__bf16)vb.y;
      uv.h[6] = (__bf16)vb.z; uv.h[7] = (__bf16)vb.w;
#pragma unroll
      for (int j = 0; j < 8; ++j) Vt[(c0 + j) * 68 + r] = uv.s[j];
    }
    __syncthreads();

    bf16x8 kf[4];
#pragma unroll
    for (int ksb = 0; ksb < 4; ++ksb) {
      U16B u;
      u.u = *(const uint4*)&Kb[(ksb * 16 + l15) * 32 + l16 * 8];
      kf[ksb] = u.h;
    }
    bf16x8 vf[2][2];
#pragma unroll
    for (int kc = 0; kc < 2; ++kc)
#pragma unroll
      for (int d = 0; d < 2; ++d) {
        const unsigned short* vp =
            &Vt[(l15 + 16 * d) * 68 + kc * 32 + l16 * 8];
        U16B u;
        *(uint2*)&u.s[0] = *(const uint2*)vp;
        *(uint2*)&u.s[4] = *(const uint2*)(vp + 4);
        vf[kc][d] = u.h;
      }

#pragma unroll
    for (int m = 0; m < 4; ++m) {
      const f32x4 zf = {0.f, 0.f, 0.f, 0.f};
      f32x4 sf[4];
#pragma unroll
      for (int ksb = 0; ksb < 4; ++ksb)
        sf[ksb] = __builtin_amdgcn_mfma_f32_16x16x32_bf16(qf[m], kf[ksb], zf,
                                                          0, 0, 0);
      float pv[4][4];
      float ps[4] = {0.f, 0.f, 0.f, 0.f};
#pragma unroll
      for (int ksb = 0; ksb < 4; ++ksb)
#pragma unroll
        for (int r = 0; r < 4; ++r) {
          float p = expf(sf[ksb][r]);
          pv[ksb][r] = p;
          ps[r] += p;
        }
#pragma unroll
      for (int r = 0; r < 4; ++r) {
        float v = ps[r];
        v += __shfl_xor(v, 1);
        v += __shfl_xor(v, 2);
        v += __shfl_xor(v, 4);
        v += __shfl_xor(v, 8);
        lacc[m][r] += v;
      }
#pragma unroll
      for (int ksb = 0; ksb < 4; ++ksb)
#pragma unroll
        for (int r = 0; r < 4; ++r)
          Pl[w][(l16 * 4 + r) * 72 + ksb * 16 + l15] = pv[ksb][r];
      asm volatile("s_waitcnt lgkmcnt(0)" ::: "memory");
      bf16x8 pa[2];
#pragma unroll
      for (int kc = 0; kc < 2; ++kc) {
        const float* pr = &Pl[w][l15 * 72 + l16 * 8 + kc * 32];
        float4 p0 = *(const float4*)pr;
        float4 p1 = *(const float4*)(pr + 4);
        U16B u;
        u.h[0] = (__bf16)p0.x; u.h[1] = (__bf16)p0.y;
        u.h[2] = (__bf16)p0.z; u.h[3] = (__bf16)p0.w;
        u.h[4] = (__bf16)p1.x; u.h[5] = (__bf16)p1.y;
        u.h[6] = (__bf16)p1.z; u.h[7] = (__bf16)p1.w;
        pa[kc] = u.h;
      }
#pragma unroll
      for (int kc = 0; kc < 2; ++kc)
#pragma unroll
        for (int d = 0; d < 2; ++d)
          o[m][d] = __builtin_amdgcn_mfma_f32_16x16x32_bf16(pa[kc], vf[kc][d],
                                                            o[m][d], 0, 0, 0);
    }
  }

  const size_t ob = (size_t)bx * 8192;
#pragma unroll
  for (int m = 0; m < 4; ++m) {
    int qrow = w * 64 + m * 16 + l16 * 4;
#pragma unroll
    for (int r = 0; r < 4; ++r) {
#pragma unroll
      for (int d = 0; d < 2; ++d)
        opart[ob + (qrow + r) * 32 + d * 16 + l15] = o[m][d][r];
      if (l15 == 0) lbuf[(size_t)bx * 256 + qrow + r] = lacc[m][r];
    }
  }
}

// ---------------- combine S partials -> O ----------------------------------
__global__ __launch_bounds__(256) void k_attn_comb(
    const float* __restrict__ opart, const float* __restrict__ lbuf,
    float* __restrict__ O, int S) {
  const int bx = blockIdx.x;
  const int qt = bx & 7, h = (bx >> 3) & 3, b = bx >> 5;
  const int tid = threadIdx.x;
  const int qq = tid >> 3, g = tid & 7;
  const int q = qt * 32 + qq;
  const int pb = (b * 4 + h) * S;
  float L = 0.f;
  float4 o4 = make_float4(0.f, 0.f, 0.f, 0.f);
  for (int s = 0; s < S; ++s) {
    L += lbuf[(size_t)(pb + s) * 256 + q];
    float4 p4 = *(const float4*)(opart + (size_t)(pb + s) * 8192 + q * 32 + g * 4);
    o4.x += p4.x;
    o4.y += p4.y;
    o4.z += p4.z;
    o4.w += p4.w;
  }
  float inv = 1.f / L;
  size_t orow = (size_t)(b * 256 + q);
  float4 res = make_float4(o4.x * inv, o4.y * inv, o4.z * inv, o4.w * inv);
  *(float4*)(O + orow * WD + h * 32 + g * 4) = res;
}

// ---------------- f32 GEMM: D = act(LN?(A)[M,K] @ W[K,N] + bias) + res -----
// 16-row tiles (grid.x = M/16), 64-col chunks (grid.y = N/64). block = 256.
__global__ __launch_bounds__(256) void k_gemm(
    const float* __restrict__ A, int lda, const float* __restrict__ Wt,
    int ldw, const float* __restrict__ bias, const float* __restrict__ res,
    int ldres, float* __restrict__ D, int ldd, int K, int act,
    const float* __restrict__ lnS, const float* __restrict__ lnB, int keep,
    int skip) {
  __shared__ float alds[16 * 132];
  const int tid = threadIdx.x;
  const int row0 = blockIdx.x * 16;
  const int col0 = blockIdx.y * 64;
  const int w = tid >> 6, l = tid & 63;
  float acc[4] = {0.f, 0.f, 0.f, 0.f};
  for (int kt = 0; kt < K; kt += 128) {
    __syncthreads();
    for (int i = tid; i < 16 * 128; i += 256) {
      int r = i >> 7, cc = i & 127;
      int grow = row0 + r;
      int srow = (grow / keep) * (keep + skip) + skip + grow % keep;
      alds[r * 132 + cc] = A[(size_t)srow * lda + kt + cc];
    }
    __syncthreads();
    if (lnS != nullptr && kt == 0) {
      const int r = tid >> 4, part = tid & 15;
      float s = 0.f, sq = 0.f;
#pragma unroll
      for (int c = part * 8; c < part * 8 + 8; ++c) {
        float v = alds[r * 132 + c];
        s += v;
        sq += v * v;
      }
      s += __shfl_xor(s, 1);  sq += __shfl_xor(sq, 1);
      s += __shfl_xor(s, 2);  sq += __shfl_xor(sq, 2);
      s += __shfl_xor(s, 4);  sq += __shfl_xor(sq, 4);
      s += __shfl_xor(s, 8);  sq += __shfl_xor(sq, 8);
      float m = s * (1.f / 128.f);
      float var = fmaxf(sq * (1.f / 128.f) - m * m, 0.f);
      float rinv = 1.0f / sqrtf(var + 1e-5f);
#pragma unroll
      for (int c = part * 8; c < part * 8 + 8; ++c)
        alds[r * 132 + c] = (alds[r * 132 + c] - m) * rinv * lnS[c] + lnB[c];
      __syncthreads();
    }
    for (int k2 = 0; k2 < 128; k2 += 4) {
      float wv[4];
#pragma unroll
      for (int u = 0; u < 4; ++u)
        wv[u] = Wt[(size_t)(kt + k2 + u) * ldw + col0 + l];
#pragma unroll
      for (int r = 0; r < 4; ++r) {
        const float4 av = *(const float4*)&alds[(w * 4 + r) * 132 + k2];
        acc[r] += av.x * wv[0] + av.y * wv[1] + av.z * wv[2] + av.w * wv[3];
      }
    }
  }
#pragma unroll
  for (int r = 0; r < 4; ++r) {
    size_t row = row0 + w * 4 + r;
    int col = col0 + l;
    float x = acc[r] + bias[col];
    if (act == 1) x = 0.5f * x * (1.0f + erff(x * 0.7071067811865476f));
    else if (act == 2) x = tanhf(x);
    if (res != nullptr) x += res[row * ldres + col];
    D[row * ldd + col] = x;
  }
}

}  // namespace

// ---------------------------------------------------------------------------
extern "C" void kernel_launch(void* const* d_in, const int* in_sizes, int n_in,
                              void* d_out, int out_size, void* d_ws,
                              size_t ws_size, hipStream_t stream) {
  const float* pts      = (const float*)d_in[0];
  const float* pe_w     = (const float*)d_in[1];
  const float* pe_b     = (const float*)d_in[2];
  const float* conv1_w  = (const float*)d_in[3];
  const float* conv1_b  = (const float*)d_in[4];
  const float* conv2_w  = (const float*)d_in[5];
  const float* conv2_b  = (const float*)d_in[6];
  const float* otok     = (const float*)d_in[7];
  const float* ln_pre_s = (const float*)d_in[8];
  const float* ln_pre_b = (const float*)d_in[9];
  const float* c_ln1_s  = (const float*)d_in[10];
  const float* c_ln1_b  = (const float*)d_in[11];
  const float* c_ln2_s  = (const float*)d_in[12];
  const float* c_ln2_b  = (const float*)d_in[13];
  const float* c_q_w    = (const float*)d_in[14];
  const float* c_q_b    = (const float*)d_in[15];
  const float* c_kv_w   = (const float*)d_in[16];
  const float* c_kv_b   = (const float*)d_in[17];
  const float* c_proj_w = (const float*)d_in[18];
  const float* c_proj_b = (const float*)d_in[19];
  const float* c_ln3_s  = (const float*)d_in[20];
  const float* c_ln3_b  = (const float*)d_in[21];
  const float* c_mlp1_w = (const float*)d_in[22];
  const float* c_mlp1_b = (const float*)d_in[23];
  const float* c_mlp2_w = (const float*)d_in[24];
  const float* c_mlp2_b = (const float*)d_in[25];
  const float* s_ln1_s  = (const float*)d_in[26];
  const float* s_ln1_b  = (const float*)d_in[27];
  const float* s_qkv_w  = (const float*)d_in[28];
  const float* s_qkv_b  = (const float*)d_in[29];
  const float* s_proj_w = (const float*)d_in[30];
  const float* s_proj_b = (const float*)d_in[31];
  const float* s_ln2_s  = (const float*)d_in[32];
  const float* s_ln2_b  = (const float*)d_in[33];
  const float* s_mlp1_w = (const float*)d_in[34];
  const float* s_mlp1_b = (const float*)d_in[35];
  const float* s_mlp2_w = (const float*)d_in[36];
  const float* s_mlp2_b = (const float*)d_in[37];
  const float* lnpost_s = (const float*)d_in[38];
  const float* lnpost_b = (const float*)d_in[39];
  const float* out_w    = (const float*)d_in[40];
  const float* out_b    = (const float*)d_in[41];

  char* ws = (char*)d_ws;
  constexpr size_t SZ_EMB = (size_t)65536 * 128 * 4;  // 32 MB
  float* emb  = (float*)(ws);
  float* kbuf = (float*)(ws + SZ_EMB);
  float* vbuf = (float*)(ws + 2 * SZ_EMB);
  float* dtok = (float*)(ws + 3 * SZ_EMB + 65536);
  float* hbuf = (float*)(ws + 3 * SZ_EMB + 65536 + 524288);
  float* qbuf = (float*)(ws + 3 * SZ_EMB + 65536 + 524288 + 2 * 1048576);
  float* att  = (float*)(ws + 3 * SZ_EMB + 65536 + 524288 + 3 * 1048576);
  float* mid  = (float*)(ws + 3 * SZ_EMB + 65536 + 524288 + 4 * 1048576);
  char*  qkvp = ws + 3 * SZ_EMB + 65536 + 524288 + 4 * 1048576 + 4194304;
  float* qkv  = (float*)qkvp;
  float* w1p  = (float*)(qkvp + 3145728);                      // 532480 B
  float* w2p  = (float*)(qkvp + 3145728 + 532480);             // 524288 B
  __bf16* wqt  = (__bf16*)(qkvp + 3145728 + 532480 + 524288);  // 32768 B
  __bf16* wkvt = (__bf16*)(qkvp + 3145728 + 532480 + 524288 + 32768);
  // attention partials overlay the emb region (emb dead after gconv/kvln):
  float* opart = (float*)(ws);
  float* lbuf  = (float*)(ws + 24 * 1024 * 1024);

  const int IDK = 1 << 28;

  // 1) weight prep + dataset_emb
  k_prep<<<1224, 256, 0, stream>>>(conv1_w, conv2_w, c_q_w, c_kv_w, w1p, w2p,
                                   wqt, wkvt);
  k_posenc<<<2048, 256, 0, stream>>>(pts, pe_w, pe_b, emb);
  // 2) K,V from dataset_emb (bf16 MFMA LN-GEMM)
  k_lngemm<<<dim3(2048, 2), 256, 0, stream>>>(emb, 128, wkvt, c_kv_b, kbuf,
                                              vbuf, 128, c_ln2_s, c_ln2_b);
  // 3) ballquery + gather + conv stack -> data_tokens [last reader of emb]
  k_gconv<<<512, 256, 0, stream>>>(pts, emb, w1p, conv1_b, w2p, conv2_b, dtok);
  // 4) concat + ln_pre -> h
  k_concat_ln<<<2048, 64, 0, stream>>>(dtok, otok, ln_pre_s, ln_pre_b, hbuf);
  // 5) cross attention block (MFMA, S=16 chunks of 512 keys)
  k_lngemm<<<dim3(64, 1), 256, 0, stream>>>(hbuf, 128, wqt, c_q_b, qbuf,
                                            nullptr, 128, c_ln1_s, c_ln1_b);
  k_attn_mfma<<<512, 256, 0, stream>>>(qbuf, 128, kbuf, 128, vbuf, 128, opart,
                                       lbuf, 8192, 16, 512);
  k_attn_comb<<<256, 256, 0, stream>>>(opart, lbuf, att, 16);
  k_gemm<<<dim3(128, 2), 256, 0, stream>>>(att, 128, c_proj_w, 128, c_proj_b,
                                           hbuf, 128, hbuf, 128, 128, 0,
                                           nullptr, nullptr, IDK, 0);
  k_gemm<<<dim3(128, 8), 256, 0, stream>>>(hbuf, 128, c_mlp1_w, 512, c_mlp1_b,
                                           nullptr, 0, mid, 512, 128, 1,
                                           c_ln3_s, c_ln3_b, IDK, 0);
  k_gemm<<<dim3(128, 2), 256, 0, stream>>>(mid, 512, c_mlp2_w, 128, c_mlp2_b,
                                           hbuf, 128, hbuf, 128, 512, 0,
                                           nullptr, nullptr, IDK, 0);
  // 6) self-attention blocks (MFMA, S=4 chunks of 64 keys)
  for (int i = 0; i < 3; ++i) {
    k_gemm<<<dim3(128, 6), 256, 0, stream>>>(
        hbuf, 128, s_qkv_w + (size_t)i * 128 * 384, 384, s_qkv_b + i * 384,
        nullptr, 0, qkv, 384, 128, 0, s_ln1_s + i * 128, s_ln1_b + i * 128,
        IDK, 0);
    k_attn_mfma<<<128, 256, 0, stream>>>(qkv, 384, qkv + 128, 384, qkv + 256,
                                         384, opart, lbuf, 256, 4, 64);
    k_attn_comb<<<256, 256, 0, stream>>>(opart, lbuf, att, 4);
    k_gemm<<<dim3(128, 2), 256, 0, stream>>>(
        att, 128, s_proj_w + (size_t)i * 16384, 128, s_proj_b + i * 128, hbuf,
        128, hbuf, 128, 128, 0, nullptr, nullptr, IDK, 0);
    k_gemm<<<dim3(128, 8), 256, 0, stream>>>(
        hbuf, 128, s_mlp1_w + (size_t)i * 65536, 512, s_mlp1_b + i * 512,
        nullptr, 0, mid, 512, 128, 1, s_ln2_s + i * 128, s_ln2_b + i * 128,
        IDK, 0);
    k_gemm<<<dim3(128, 2), 256, 0, stream>>>(
        mid, 512, s_mlp2_w + (size_t)i * 65536, 128, s_mlp2_b + i * 128, hbuf,
        128, hbuf, 128, 512, 0, nullptr, nullptr, IDK, 0);
  }
  // 7) final LN (last 128 tokens of each batch) + output head with tanh
  k_gemm<<<dim3(64, 2), 256, 0, stream>>>(hbuf, 128, out_w, 128, out_b,
                                          nullptr, 0, (float*)d_out, 128, 128,
                                          2, lnpost_s, lnpost_b, 128, 128);
}

// Round 6
// 366.277 us; speedup vs baseline: 4.4150x; 1.6779x over previous
//
#include <hip/hip_runtime.h>
#include <math.h>

// ---------------------------------------------------------------------------
// PointCloudPerceiverChannelsEncoder — round 5: everything matmul-shaped on
// MFMA. gconv via LDS im2col + bf16 MFMA; all transformer GEMMs via k_bgemm
// (bf16 MFMA, LN/gelu/tanh/residual fused, pre-transposed bf16 weights).
// ---------------------------------------------------------------------------

namespace {

constexpr int NP = 8192;
constexpr int WD = 128;
constexpr int POSD = 62;
constexpr float R2C = 0.04f;
constexpr float QSCALE = 0.17677669529663687f;    // 1/sqrt(32)
constexpr float HALFPI = 1.5707963705062866f;

typedef __bf16 bf16x8 __attribute__((ext_vector_type(8)));
typedef float f32x4 __attribute__((ext_vector_type(4)));
union U16B { uint4 u; bf16x8 h; unsigned short s[8]; };

// bf16 weight arena element offsets (ushort units)
constexpr size_t AO_WQ     = 0;        // [128][128]
constexpr size_t AO_WKV    = 16384;    // [256][128]
constexpr size_t AO_WPROJC = 49152;    // [128][128]
constexpr size_t AO_WMLP1C = 65536;    // [512][128]
constexpr size_t AO_WMLP2C = 131072;   // [128][512]
constexpr size_t AO_WQKVS  = 196608;   // 3 x [384][128]
constexpr size_t AO_WPROJS = 344064;   // 3 x [128][128]
constexpr size_t AO_WMLP1S = 393216;   // 3 x [512][128]
constexpr size_t AO_WMLP2S = 589824;   // 3 x [128][512]
constexpr size_t AO_WOUT   = 786432;   // [128][128]
constexpr size_t AO_W1B    = 802816;   // [128][1056] (1040 + zero pad)
constexpr size_t AO_W2B    = 937984;   // [128][1024]
constexpr size_t AO_TOT    = 1069056;

// ---------------- posenc + pe GEMM: emb[65536][128] -------------------------
__global__ __launch_bounds__(256) void k_posenc(
    const float* __restrict__ pts, const float* __restrict__ pew,
    const float* __restrict__ peb, float* __restrict__ emb) {
  __shared__ float posT[62][36];
  const int tid = threadIdx.x;
  const int base = blockIdx.x * 32;
  for (int i = tid; i < 32 * POSD; i += 256) {
    int p = i / POSD, j = i % POSD;
    const float* pp = pts + (size_t)(base + p) * 2;
    float v;
    if (j < 2) {
      v = pp[j];
    } else if (j < 32) {
      int t = j - 2;
      v = sinf(pp[t & 1] * (float)(1 << (t >> 1)));
    } else {
      int t = j - 32;
      v = sinf(pp[t & 1] * (float)(1 << (t >> 1)) + HALFPI);
    }
    posT[j][p] = v;
  }
  __syncthreads();
  const int c = tid & 127, pg = tid >> 7;
  float acc[16];
  const float bias = peb[c];
#pragma unroll
  for (int k = 0; k < 16; ++k) acc[k] = bias;
  for (int j = 0; j < POSD; ++j) {
    float w = pew[j * WD + c];
    const float4 p0 = *(const float4*)&posT[j][pg * 16];
    const float4 p1 = *(const float4*)&posT[j][pg * 16 + 4];
    const float4 p2 = *(const float4*)&posT[j][pg * 16 + 8];
    const float4 p3 = *(const float4*)&posT[j][pg * 16 + 12];
    acc[0] += p0.x * w;  acc[1] += p0.y * w;
    acc[2] += p0.z * w;  acc[3] += p0.w * w;
    acc[4] += p1.x * w;  acc[5] += p1.y * w;
    acc[6] += p1.z * w;  acc[7] += p1.w * w;
    acc[8] += p2.x * w;  acc[9] += p2.y * w;
    acc[10] += p2.z * w; acc[11] += p2.w * w;
    acc[12] += p3.x * w; acc[13] += p3.y * w;
    acc[14] += p3.z * w; acc[15] += p3.w * w;
  }
#pragma unroll
  for (int k = 0; k < 16; ++k)
    emb[(size_t)(base + pg * 16 + k) * WD + c] = acc[k];
}

// ---------------- mega-prep: all weights -> bf16 arena ----------------------
__global__ __launch_bounds__(256) void k_prep(
    const float* __restrict__ wq, const float* __restrict__ wkv,
    const float* __restrict__ wprojc, const float* __restrict__ wmlp1c,
    const float* __restrict__ wmlp2c, const float* __restrict__ wqkvs,
    const float* __restrict__ wprojs, const float* __restrict__ wmlp1s,
    const float* __restrict__ wmlp2s, const float* __restrict__ wout,
    const float* __restrict__ w1, const float* __restrict__ w2,
    unsigned short* __restrict__ dst) {
  const size_t i = (size_t)blockIdx.x * 256 + threadIdx.x;
  if (i >= AO_TOT) return;
  float v;
  if (i < AO_WKV) {                       // wq [128n][128k]
    size_t j = i;            v = wq[(j & 127) * 128 + (j >> 7)];
  } else if (i < AO_WPROJC) {             // wkv [256n][128k]
    size_t j = i - AO_WKV;   v = wkv[(j & 127) * 256 + (j >> 7)];
  } else if (i < AO_WMLP1C) {             // proj_c [128][128]
    size_t j = i - AO_WPROJC; v = wprojc[(j & 127) * 128 + (j >> 7)];
  } else if (i < AO_WMLP2C) {             // mlp1_c [512n][128k]
    size_t j = i - AO_WMLP1C; v = wmlp1c[(j & 127) * 512 + (j >> 7)];
  } else if (i < AO_WQKVS) {              // mlp2_c [128n][512k]
    size_t j = i - AO_WMLP2C; v = wmlp2c[(j & 511) * 128 + (j >> 9)];
  } else if (i < AO_WPROJS) {             // qkv_s: 3 x [384n][128k]
    size_t j = i - AO_WQKVS;
    size_t L = j / 49152, jj = j % 49152;
    v = wqkvs[L * 49152 + (jj & 127) * 384 + (jj >> 7)];
  } else if (i < AO_WMLP1S) {             // proj_s: 3 x [128][128]
    size_t j = i - AO_WPROJS;
    size_t L = j / 16384, jj = j % 16384;
    v = wprojs[L * 16384 + (jj & 127) * 128 + (jj >> 7)];
  } else if (i < AO_WMLP2S) {             // mlp1_s: 3 x [512n][128k]
    size_t j = i - AO_WMLP1S;
    size_t L = j / 65536, jj = j % 65536;
    v = wmlp1s[L * 65536 + (jj & 127) * 512 + (jj >> 7)];
  } else if (i < AO_WOUT) {               // mlp2_s: 3 x [128n][512k]
    size_t j = i - AO_WMLP2S;
    size_t L = j / 65536, jj = j % 65536;
    v = wmlp2s[L * 65536 + (jj & 511) * 128 + (jj >> 9)];
  } else if (i < AO_W1B) {                // out [128][128]
    size_t j = i - AO_WOUT;  v = wout[(j & 127) * 128 + (j >> 7)];
  } else if (i < AO_W2B) {                // conv1 [c][1056], pad zeros
    size_t j = i - AO_W1B;
    size_t c = j / 1056, k = j % 1056;
    v = (k < 1040) ? w1[c * 1040 + k] : 0.f;
  } else {                                // conv2 [c][1024]
    size_t j = i - AO_W2B;   v = w2[(j >> 10) * 1024 + (j & 1023)];
  }
  __bf16 bv = (__bf16)v;
  dst[i] = *(unsigned short*)&bv;
}

// ---------------- gconv via MFMA (ballquery fused), 2 points/block ----------
__global__ __launch_bounds__(256) void k_gconv_mfma(
    const float* __restrict__ pts, const float* __restrict__ emb,
    const unsigned short* __restrict__ w1b, const float* __restrict__ b1,
    const unsigned short* __restrict__ w2b, const float* __restrict__ b2,
    float* __restrict__ dtok) {
  const int blk = blockIdx.x;          // b*64 + ip
  const int b = blk >> 6;
  const int i0 = (blk & 63) * 2;
  const int tid = threadIdx.x;
  const int w = tid >> 6, lane = tid & 63;
  const int l15 = lane & 15, l16 = lane >> 4;
  // LDS overlay: [0,8448) ft / later y1(8192); [8448,42240) Bt1 / later Bt2
  __shared__ __align__(16) char raw[42240];
  __shared__ int sid[2][8];
  float (*ft)[132][8] = (float(*)[132][8])raw;               // [2][132][8]
  unsigned short (*Bt1)[1056] = (unsigned short(*)[1056])(raw + 8448);
  unsigned short (*y1)[128][16] = (unsigned short(*)[128][16])raw;
  unsigned short (*Bt2)[512] = (unsigned short(*)[512])(raw + 8448);

  // ---- ball query (waves 0,1)
  if (w < 2) {
    const int i = i0 + w;
    const float cx = pts[((size_t)b * NP + i) * 2];
    const float cy = pts[((size_t)b * NP + i) * 2 + 1];
    int cnt = 0;
    for (int j0 = 0; j0 < NP; j0 += 64) {
      int j = j0 + lane;
      float dx = pts[((size_t)b * NP + j) * 2] - cx;
      float dy = pts[((size_t)b * NP + j) * 2 + 1] - cy;
      float d2 = __fadd_rn(__fmul_rn(dx, dx), __fmul_rn(dy, dy));
      bool ok = !(d2 > R2C);
      unsigned long long m = __ballot(ok);
      int ord = cnt + __popcll(m & ((1ull << lane) - 1ull));
      if (ok && ord < 8) sid[w][ord] = j;
      cnt += (int)__popcll(m);
      if (cnt >= 8) break;
    }
    if (lane < 8 && lane >= cnt) sid[w][lane] = sid[w][0];
  }
  __syncthreads();
  // ---- gather features into ft
  for (int it = tid; it < 16 * 128; it += 256) {
    int pr = it >> 7, cc = it & 127;
    int spx = pr >> 3, s = pr & 7;
    ft[spx][2 + cc][s] = emb[((size_t)b * NP + sid[spx][s]) * WD + cc];
  }
  if (tid < 32) {
    int spx = tid >> 4, s = (tid >> 1) & 7, d = tid & 1;
    ft[spx][d][s] = pts[((size_t)b * NP + sid[spx][s]) * 2 + d] -
                    pts[((size_t)b * NP + i0 + spx) * 2 + d];
  }
  __syncthreads();
  // ---- build Bt1[n=(pt,h)][k=(cin,p)] = ft[pt][cin][(h+p+4)&7]
  {
    const int n = tid >> 4, g = tid & 15;
    const int pt = n >> 3, h = n & 7;
#pragma unroll
    for (int it = 0; it < 9; ++it) {
      int cin = g + it * 16;
      if (cin < 130) {
        const float4 f03 = *(const float4*)&ft[pt][cin][0];
        const float4 f47 = *(const float4*)&ft[pt][cin][4];
        const float fr[8] = {f03.x, f03.y, f03.z, f03.w,
                             f47.x, f47.y, f47.z, f47.w};
        U16B u;
#pragma unroll
        for (int p = 0; p < 8; ++p) u.h[p] = (__bf16)fr[(h + p + 4) & 7];
        *(uint4*)&Bt1[n][cin * 8] = u.u;
      } else if (cin < 132) {
        uint4 z; z.x = z.y = z.z = z.w = 0;
        *(uint4*)&Bt1[n][cin * 8] = z;
      }
    }
  }
  __syncthreads();
  // ---- conv1 MFMA: M=128 (c), N=16, K=1056
  f32x4 acc1[2];
  acc1[0] = (f32x4){0.f, 0.f, 0.f, 0.f};
  acc1[1] = (f32x4){0.f, 0.f, 0.f, 0.f};
  {
    const unsigned short* w1r = w1b + (size_t)(w * 32 + l15) * 1056;
#pragma unroll 3
    for (int ks = 0; ks < 33; ++ks) {
      const int k0 = ks * 32 + l16 * 8;
      U16B a0, a1, bb;
      a0.u = *(const uint4*)(w1r + k0);
      a1.u = *(const uint4*)(w1r + 16 * 1056 + k0);
      bb.u = *(const uint4*)&Bt1[l15][k0];
      acc1[0] = __builtin_amdgcn_mfma_f32_16x16x32_bf16(a0.h, bb.h, acc1[0],
                                                        0, 0, 0);
      acc1[1] = __builtin_amdgcn_mfma_f32_16x16x32_bf16(a1.h, bb.h, acc1[1],
                                                        0, 0, 0);
    }
  }
  __syncthreads();   // all Bt1 reads done before y1 (ft region) writes? y1
                     // does not overlap Bt1, but ft must be dead: it is.
  // ---- silu + write y1[pt][c][h], dup h=8
  {
    const int pt = l15 >> 3, h = l15 & 7;
#pragma unroll
    for (int t = 0; t < 2; ++t)
#pragma unroll
      for (int r = 0; r < 4; ++r) {
        int c = w * 32 + t * 16 + l16 * 4 + r;
        float x = acc1[t][r] + b1[c];
        float sy = x / (1.f + expf(-x));
        __bf16 bh = (__bf16)sy;
        unsigned short bits = *(unsigned short*)&bh;
        y1[pt][c][h] = bits;
        if (h == 0) y1[pt][c][8] = bits;
      }
  }
  // ---- conv2 MFMA over two K-halves: M=128, N=32 (18 used), K=1024
  f32x4 acc2[2][2];
#pragma unroll
  for (int t = 0; t < 2; ++t)
#pragma unroll
    for (int nt = 0; nt < 2; ++nt) acc2[t][nt] = (f32x4){0.f, 0.f, 0.f, 0.f};
  for (int hf = 0; hf < 2; ++hf) {
    __syncthreads();
    // build Bt2[n2][(c1loc,p)] = y1[pt][c1][(h2+p+5)%9]
    {
      const int n2 = tid >> 3, g = tid & 7;
      const int pt = n2 / 9, h2 = n2 % 9;
#pragma unroll
      for (int it = 0; it < 8; ++it) {
        int c1loc = g + it * 8;
        if (n2 < 18) {
          int c1 = hf * 64 + c1loc;
          U16B u0, u1;
          u0.u = *(const uint4*)&y1[pt][c1][0];
          u1.u = *(const uint4*)&y1[pt][c1][8];
          unsigned short yv[9];
#pragma unroll
          for (int j = 0; j < 8; ++j) yv[j] = u0.s[j];
          yv[8] = u1.s[0];
          U16B o;
#pragma unroll
          for (int p = 0; p < 8; ++p) o.s[p] = yv[(h2 + p + 5) % 9];
          *(uint4*)&Bt2[n2][c1loc * 8] = o.u;
        } else {
          uint4 z; z.x = z.y = z.z = z.w = 0;
          *(uint4*)&Bt2[n2][c1loc * 8] = z;
        }
      }
    }
    __syncthreads();
    const unsigned short* w2r = w2b + (size_t)(w * 32 + l15) * 1024 + hf * 512;
#pragma unroll 4
    for (int ks = 0; ks < 16; ++ks) {
      const int k0 = ks * 32 + l16 * 8;
      U16B a0, a1, b0, b1u;
      a0.u = *(const uint4*)(w2r + k0);
      a1.u = *(const uint4*)(w2r + 16 * 1024 + k0);
      b0.u = *(const uint4*)&Bt2[l15][k0];
      b1u.u = *(const uint4*)&Bt2[16 + l15][k0];
      acc2[0][0] = __builtin_amdgcn_mfma_f32_16x16x32_bf16(a0.h, b0.h,
                                                           acc2[0][0], 0, 0, 0);
      acc2[0][1] = __builtin_amdgcn_mfma_f32_16x16x32_bf16(a0.h, b1u.h,
                                                           acc2[0][1], 0, 0, 0);
      acc2[1][0] = __builtin_amdgcn_mfma_f32_16x16x32_bf16(a1.h, b0.h,
                                                           acc2[1][0], 0, 0, 0);
      acc2[1][1] = __builtin_amdgcn_mfma_f32_16x16x32_bf16(a1.h, b1u.h,
                                                           acc2[1][1], 0, 0, 0);
    }
  }
  // ---- epilogue: silu + weighted mean over 10 h (h2=0 twice)
  float s0[2][4], s1[2][4];
#pragma unroll
  for (int t = 0; t < 2; ++t)
#pragma unroll
    for (int r = 0; r < 4; ++r) { s0[t][r] = 0.f; s1[t][r] = 0.f; }
#pragma unroll
  for (int t = 0; t < 2; ++t)
#pragma unroll
    for (int nt = 0; nt < 2; ++nt) {
      const int n2 = nt * 16 + l15;
      if (n2 < 18) {
        const float wgt = (n2 % 9 == 0) ? 2.f : 1.f;
#pragma unroll
        for (int r = 0; r < 4; ++r) {
          int c = w * 32 + t * 16 + l16 * 4 + r;
          float x = acc2[t][nt][r] + b2[c];
          float sv = wgt * (x / (1.f + expf(-x)));
          if (n2 < 9) s0[t][r] += sv; else s1[t][r] += sv;
        }
      }
    }
#pragma unroll
  for (int t = 0; t < 2; ++t)
#pragma unroll
    for (int r = 0; r < 4; ++r) {
      float a = s0[t][r], bq = s1[t][r];
      a += __shfl_xor(a, 1);  bq += __shfl_xor(bq, 1);
      a += __shfl_xor(a, 2);  bq += __shfl_xor(bq, 2);
      a += __shfl_xor(a, 4);  bq += __shfl_xor(bq, 4);
      a += __shfl_xor(a, 8);  bq += __shfl_xor(bq, 8);
      if (l15 == 0) {
        int c = w * 32 + t * 16 + l16 * 4 + r;
        dtok[((size_t)b * 128 + i0) * WD + c] = a / 10.0f;
        dtok[((size_t)b * 128 + i0 + 1) * WD + c] = bq / 10.0f;
      }
    }
}

// ---------------- concat(data_tokens, latents) + ln_pre -> h ---------------
__global__ __launch_bounds__(64) void k_concat_ln(
    const float* __restrict__ dtok, const float* __restrict__ otok,
    const float* __restrict__ g, const float* __restrict__ bta,
    float* __restrict__ h0) {
  const int row = blockIdx.x;
  const int b = row >> 8, t = row & 255;
  const int lane = threadIdx.x;
  const float* src = (t < 128) ? (dtok + ((size_t)b * 128 + t) * WD)
                               : (otok + (size_t)(t - 128) * WD);
  const float2 x2 = *(const float2*)(src + lane * 2);
  float s = x2.x + x2.y;
  float sq = x2.x * x2.x + x2.y * x2.y;
#pragma unroll
  for (int o = 1; o < 64; o <<= 1) {
    s += __shfl_xor(s, o);
    sq += __shfl_xor(sq, o);
  }
  float m = s * (1.f / 128.f);
  float var = fmaxf(sq * (1.f / 128.f) - m * m, 0.f);
  float r = 1.0f / sqrtf(var + 1e-5f);
  int c = lane * 2;
  float2 o2;
  o2.x = (x2.x - m) * r * g[c] + bta[c];
  o2.y = (x2.y - m) * r * g[c + 1] + bta[c + 1];
  *(float2*)(h0 + (size_t)row * WD + c) = o2;
}

// ---------------- bf16 MFMA LN-GEMM for KV (dual output) -------------------
__global__ __launch_bounds__(256) void k_lngemm(
    const float* __restrict__ A, int lda, const unsigned short* __restrict__ wt,
    const float* __restrict__ bias, float* __restrict__ D0,
    float* __restrict__ D1, int ldd, const float* __restrict__ lnS,
    const float* __restrict__ lnB) {
  __shared__ unsigned short Ab[32][136];
  __shared__ unsigned short Bt[128][136];
  const int tid = threadIdx.x;
  const int row0 = blockIdx.x * 32;
  const int nblk = blockIdx.y;
  {
    const int n = tid >> 1, hf = tid & 1;
    const unsigned short* src = wt + ((size_t)(nblk * 128 + n) * 128 + hf * 64);
#pragma unroll
    for (int q8 = 0; q8 < 8; ++q8)
      *(uint4*)&Bt[n][hf * 64 + q8 * 8] = *(const uint4*)(src + q8 * 8);
  }
  {
    const int r = tid >> 3, seg = tid & 7;
    const float* ap = A + (size_t)(row0 + r) * lda + seg * 16;
    float4 v0 = *(const float4*)ap;
    float4 v1 = *(const float4*)(ap + 4);
    float4 v2 = *(const float4*)(ap + 8);
    float4 v3 = *(const float4*)(ap + 12);
    float s = v0.x + v0.y + v0.z + v0.w + v1.x + v1.y + v1.z + v1.w +
              v2.x + v2.y + v2.z + v2.w + v3.x + v3.y + v3.z + v3.w;
    float sq = v0.x * v0.x + v0.y * v0.y + v0.z * v0.z + v0.w * v0.w +
               v1.x * v1.x + v1.y * v1.y + v1.z * v1.z + v1.w * v1.w +
               v2.x * v2.x + v2.y * v2.y + v2.z * v2.z + v2.w * v2.w +
               v3.x * v3.x + v3.y * v3.y + v3.z * v3.z + v3.w * v3.w;
    s += __shfl_xor(s, 1);  sq += __shfl_xor(sq, 1);
    s += __shfl_xor(s, 2);  sq += __shfl_xor(sq, 2);
    s += __shfl_xor(s, 4);  sq += __shfl_xor(sq, 4);
    const float m = s * (1.f / 128.f);
    const float var = fmaxf(sq * (1.f / 128.f) - m * m, 0.f);
    const float rinv = 1.0f / sqrtf(var + 1e-5f);
    float xv[16] = {v0.x, v0.y, v0.z, v0.w, v1.x, v1.y, v1.z, v1.w,
                    v2.x, v2.y, v2.z, v2.w, v3.x, v3.y, v3.z, v3.w};
    U16B u0, u1;
#pragma unroll
    for (int j = 0; j < 16; ++j) {
      int col = seg * 16 + j;
      float y = (xv[j] - m) * rinv * lnS[col] + lnB[col];
      if (j < 8) u0.h[j] = (__bf16)y; else u1.h[j - 8] = (__bf16)y;
    }
    *(uint4*)&Ab[r][seg * 16] = u0.u;
    *(uint4*)&Ab[r][seg * 16 + 8] = u1.u;
  }
  __syncthreads();
  const int w = tid >> 6, lane = tid & 63;
  const int l15 = lane & 15, l16 = lane >> 4;
  const int rt = w >> 1, ch = w & 1;
  f32x4 acc[4];
#pragma unroll
  for (int j = 0; j < 4; ++j) acc[j] = (f32x4){0.f, 0.f, 0.f, 0.f};
#pragma unroll
  for (int kk = 0; kk < 4; ++kk) {
    U16B ua;
    ua.u = *(const uint4*)&Ab[rt * 16 + l15][kk * 32 + l16 * 8];
#pragma unroll
    for (int ct4 = 0; ct4 < 4; ++ct4) {
      U16B ub;
      ub.u = *(const uint4*)&Bt[(ch * 4 + ct4) * 16 + l15][kk * 32 + l16 * 8];
      acc[ct4] = __builtin_amdgcn_mfma_f32_16x16x32_bf16(ua.h, ub.h, acc[ct4],
                                                         0, 0, 0);
    }
  }
  float* Dp = (nblk == 1) ? D1 : D0;
#pragma unroll
  for (int ct4 = 0; ct4 < 4; ++ct4) {
    int colL = (ch * 4 + ct4) * 16 + l15;
    float bv = bias[nblk * 128 + colL];
#pragma unroll
    for (int r = 0; r < 4; ++r) {
      int row = row0 + rt * 16 + l16 * 4 + r;
      Dp[(size_t)row * ldd + colL] = acc[ct4][r] + bv;
    }
  }
}

// ---------------- universal bf16 MFMA GEMM ---------------------------------
// D[M,N] = act(LN?(A)[M,K] @ Wbf16 + bias) + res. BM=32, BN=128.
// grid (M/32, N/128). wt layout [n][K] bf16. LN requires K==128.
// act: 0 none, 1 gelu(exact), 2 tanh. A row map: keep/skip (IDK = identity).
__global__ __launch_bounds__(256) void k_bgemm(
    const float* __restrict__ A, int lda, const unsigned short* __restrict__ wt,
    const float* __restrict__ bias, const float* __restrict__ res, int ldres,
    float* __restrict__ D, int ldd, int K, int act,
    const float* __restrict__ lnS, const float* __restrict__ lnB, int keep,
    int skip) {
  __shared__ unsigned short Ab[32][136];
  __shared__ unsigned short Bt[128][136];
  const int tid = threadIdx.x;
  const int row0 = blockIdx.x * 32;
  const int col0 = blockIdx.y * 128;
  const int w = tid >> 6, lane = tid & 63;
  const int l15 = lane & 15, l16 = lane >> 4;
  const int rt = w >> 1, ch = w & 1;
  f32x4 acc[4];
#pragma unroll
  for (int j = 0; j < 4; ++j) acc[j] = (f32x4){0.f, 0.f, 0.f, 0.f};
  for (int kt = 0; kt < K; kt += 128) {
    if (kt) __syncthreads();
    {
      const int n = tid >> 1, hf = tid & 1;
      const unsigned short* src = wt + (size_t)(col0 + n) * K + kt + hf * 64;
#pragma unroll
      for (int q8 = 0; q8 < 8; ++q8)
        *(uint4*)&Bt[n][hf * 64 + q8 * 8] = *(const uint4*)(src + q8 * 8);
    }
    {
      const int r = tid >> 3, seg = tid & 7;
      const int grow = row0 + r;
      const int srow = (grow / keep) * (keep + skip) + skip + grow % keep;
      const float* ap = A + (size_t)srow * lda + kt + seg * 16;
      float4 v0 = *(const float4*)ap;
      float4 v1 = *(const float4*)(ap + 4);
      float4 v2 = *(const float4*)(ap + 8);
      float4 v3 = *(const float4*)(ap + 12);
      float xv[16] = {v0.x, v0.y, v0.z, v0.w, v1.x, v1.y, v1.z, v1.w,
                      v2.x, v2.y, v2.z, v2.w, v3.x, v3.y, v3.z, v3.w};
      if (lnS != nullptr) {
        float s = 0.f, sq = 0.f;
#pragma unroll
        for (int j = 0; j < 16; ++j) { s += xv[j]; sq += xv[j] * xv[j]; }
        s += __shfl_xor(s, 1);  sq += __shfl_xor(sq, 1);
        s += __shfl_xor(s, 2);  sq += __shfl_xor(sq, 2);
        s += __shfl_xor(s, 4);  sq += __shfl_xor(sq, 4);
        const float m = s * (1.f / 128.f);
        const float var = fmaxf(sq * (1.f / 128.f) - m * m, 0.f);
        const float rinv = 1.0f / sqrtf(var + 1e-5f);
#pragma unroll
        for (int j = 0; j < 16; ++j) {
          int col = seg * 16 + j;
          xv[j] = (xv[j] - m) * rinv * lnS[col] + lnB[col];
        }
      }
      U16B u0, u1;
#pragma unroll
      for (int j = 0; j < 8; ++j) {
        u0.h[j] = (__bf16)xv[j];
        u1.h[j] = (__bf16)xv[8 + j];
      }
      *(uint4*)&Ab[r][seg * 16] = u0.u;
      *(uint4*)&Ab[r][seg * 16 + 8] = u1.u;
    }
    __syncthreads();
#pragma unroll
    for (int kk = 0; kk < 4; ++kk) {
      U16B ua;
      ua.u = *(const uint4*)&Ab[rt * 16 + l15][kk * 32 + l16 * 8];
#pragma unroll
      for (int ct = 0; ct < 4; ++ct) {
        U16B ub;
        ub.u = *(const uint4*)&Bt[(ch * 4 + ct) * 16 + l15][kk * 32 + l16 * 8];
        acc[ct] = __builtin_amdgcn_mfma_f32_16x16x32_bf16(ua.h, ub.h, acc[ct],
                                                          0, 0, 0);
      }
    }
  }
#pragma unroll
  for (int ct = 0; ct < 4; ++ct) {
    const int colL = (ch * 4 + ct) * 16 + l15;
    const int col = col0 + colL;
    const float bv = bias[col];
#pragma unroll
    for (int r = 0; r < 4; ++r) {
      const int row = row0 + rt * 16 + l16 * 4 + r;
      float x = acc[ct][r] + bv;
      if (act == 1) x = 0.5f * x * (1.0f + erff(x * 0.7071067811865476f));
      else if (act == 2) x = tanhf(x);
      if (res != nullptr) x += res[(size_t)row * ldres + col];
      D[(size_t)row * ldd + col] = x;
    }
  }
}

// ---------------- MFMA bf16 flash attention (maxless), split-K -------------
__global__ __launch_bounds__(256) void k_attn_mfma(
    const float* __restrict__ Q, int qs, const float* __restrict__ K, int ks,
    const float* __restrict__ V, int vs, float* __restrict__ opart,
    float* __restrict__ lbuf, int Tk, int S, int CH) {
  const int bx = blockIdx.x;
  const int s = bx % S;
  const int bh = bx / S;
  const int h = bh & 3, b = bh >> 2;
  const int tid = threadIdx.x;
  const int w = tid >> 6, lane = tid & 63;
  const int l15 = lane & 15, l16 = lane >> 4;

  __shared__ unsigned short Kb[64 * 32];
  __shared__ unsigned short Vt[32 * 68];
  __shared__ float Pl[4][16 * 72];

  bf16x8 qf[4];
#pragma unroll
  for (int m = 0; m < 4; ++m) {
    const float* qp = Q + (size_t)(b * 256 + w * 64 + m * 16 + l15) * qs +
                      h * 32 + l16 * 8;
    float4 a = *(const float4*)qp;
    float4 bq = *(const float4*)(qp + 4);
    U16B u;
    u.h[0] = (__bf16)(a.x * QSCALE);
    u.h[1] = (__bf16)(a.y * QSCALE);
    u.h[2] = (__bf16)(a.z * QSCALE);
    u.h[3] = (__bf16)(a.w * QSCALE);
    u.h[4] = (__bf16)(bq.x * QSCALE);
    u.h[5] = (__bf16)(bq.y * QSCALE);
    u.h[6] = (__bf16)(bq.z * QSCALE);
    u.h[7] = (__bf16)(bq.w * QSCALE);
    qf[m] = u.h;
  }

  f32x4 o[4][2];
#pragma unroll
  for (int m = 0; m < 4; ++m)
#pragma unroll
    for (int d = 0; d < 2; ++d) o[m][d] = (f32x4){0.f, 0.f, 0.f, 0.f};
  float lacc[4][4];
#pragma unroll
  for (int m = 0; m < 4; ++m)
#pragma unroll
    for (int r = 0; r < 4; ++r) lacc[m][r] = 0.f;

  const int kt0 = s * CH;
  for (int kt = kt0; kt < kt0 + CH; kt += 64) {
    __syncthreads();
    {
      const int r = tid >> 2, c0 = (tid & 3) * 8;
      const float* kp = K + (size_t)(b * Tk + kt + r) * ks + h * 32 + c0;
      float4 a = *(const float4*)kp;
      float4 bb = *(const float4*)(kp + 4);
      U16B uk;
      uk.h[0] = (__bf16)a.x;  uk.h[1] = (__bf16)a.y;
      uk.h[2] = (__bf16)a.z;  uk.h[3] = (__bf16)a.w;
      uk.h[4] = (__bf16)bb.x; uk.h[5] = (__bf16)bb.y;
      uk.h[6] = (__bf16)bb.z; uk.h[7] = (__bf16)bb.w;
      *(uint4*)&Kb[r * 32 + c0] = uk.u;
      const float* vp = V + (size_t)(b * Tk + kt + r) * vs + h * 32 + c0;
      float4 va = *(const float4*)vp;
      float4 vb = *(const float4*)(vp + 4);
      U16B uv;
      uv.h[0] = (__bf16)va.x; uv.h[1] = (__bf16)va.y;
      uv.h[2] = (__bf16)va.z; uv.h[3] = (__bf16)va.w;
      uv.h[4] = (__bf16)vb.x; uv.h[5] = (__bf16)vb.y;
      uv.h[6] = (__bf16)vb.z; uv.h[7] = (__bf16)vb.w;
#pragma unroll
      for (int j = 0; j < 8; ++j) Vt[(c0 + j) * 68 + r] = uv.s[j];
    }
    __syncthreads();

    bf16x8 kf[4];
#pragma unroll
    for (int ksb = 0; ksb < 4; ++ksb) {
      U16B u;
      u.u = *(const uint4*)&Kb[(ksb * 16 + l15) * 32 + l16 * 8];
      kf[ksb] = u.h;
    }
    bf16x8 vf[2][2];
#pragma unroll
    for (int kc = 0; kc < 2; ++kc)
#pragma unroll
      for (int d = 0; d < 2; ++d) {
        const unsigned short* vp =
            &Vt[(l15 + 16 * d) * 68 + kc * 32 + l16 * 8];
        U16B u;
        *(uint2*)&u.s[0] = *(const uint2*)vp;
        *(uint2*)&u.s[4] = *(const uint2*)(vp + 4);
        vf[kc][d] = u.h;
      }

#pragma unroll
    for (int m = 0; m < 4; ++m) {
      const f32x4 zf = {0.f, 0.f, 0.f, 0.f};
      f32x4 sf[4];
#pragma unroll
      for (int ksb = 0; ksb < 4; ++ksb)
        sf[ksb] = __builtin_amdgcn_mfma_f32_16x16x32_bf16(qf[m], kf[ksb], zf,
                                                          0, 0, 0);
      float pv[4][4];
      float ps[4] = {0.f, 0.f, 0.f, 0.f};
#pragma unroll
      for (int ksb = 0; ksb < 4; ++ksb)
#pragma unroll
        for (int r = 0; r < 4; ++r) {
          float p = expf(sf[ksb][r]);
          pv[ksb][r] = p;
          ps[r] += p;
        }
#pragma unroll
      for (int r = 0; r < 4; ++r) {
        float v = ps[r];
        v += __shfl_xor(v, 1);
        v += __shfl_xor(v, 2);
        v += __shfl_xor(v, 4);
        v += __shfl_xor(v, 8);
        lacc[m][r] += v;
      }
#pragma unroll
      for (int ksb = 0; ksb < 4; ++ksb)
#pragma unroll
        for (int r = 0; r < 4; ++r)
          Pl[w][(l16 * 4 + r) * 72 + ksb * 16 + l15] = pv[ksb][r];
      asm volatile("s_waitcnt lgkmcnt(0)" ::: "memory");
      bf16x8 pa[2];
#pragma unroll
      for (int kc = 0; kc < 2; ++kc) {
        const float* pr = &Pl[w][l15 * 72 + l16 * 8 + kc * 32];
        float4 p0 = *(const float4*)pr;
        float4 p1 = *(const float4*)(pr + 4);
        U16B u;
        u.h[0] = (__bf16)p0.x; u.h[1] = (__bf16)p0.y;
        u.h[2] = (__bf16)p0.z; u.h[3] = (__bf16)p0.w;
        u.h[4] = (__bf16)p1.x; u.h[5] = (__bf16)p1.y;
        u.h[6] = (__bf16)p1.z; u.h[7] = (__bf16)p1.w;
        pa[kc] = u.h;
      }
#pragma unroll
      for (int kc = 0; kc < 2; ++kc)
#pragma unroll
        for (int d = 0; d < 2; ++d)
          o[m][d] = __builtin_amdgcn_mfma_f32_16x16x32_bf16(pa[kc], vf[kc][d],
                                                            o[m][d], 0, 0, 0);
    }
  }

  const size_t ob = (size_t)bx * 8192;
#pragma unroll
  for (int m = 0; m < 4; ++m) {
    int qrow = w * 64 + m * 16 + l16 * 4;
#pragma unroll
    for (int r = 0; r < 4; ++r) {
#pragma unroll
      for (int d = 0; d < 2; ++d)
        opart[ob + (qrow + r) * 32 + d * 16 + l15] = o[m][d][r];
      if (l15 == 0) lbuf[(size_t)bx * 256 + qrow + r] = lacc[m][r];
    }
  }
}

// ---------------- combine S partials -> O ----------------------------------
__global__ __launch_bounds__(256) void k_attn_comb(
    const float* __restrict__ opart, const float* __restrict__ lbuf,
    float* __restrict__ O, int S) {
  const int bx = blockIdx.x;
  const int qt = bx & 7, h = (bx >> 3) & 3, b = bx >> 5;
  const int tid = threadIdx.x;
  const int qq = tid >> 3, g = tid & 7;
  const int q = qt * 32 + qq;
  const int pb = (b * 4 + h) * S;
  float L = 0.f;
  float4 o4 = make_float4(0.f, 0.f, 0.f, 0.f);
  for (int s = 0; s < S; ++s) {
    L += lbuf[(size_t)(pb + s) * 256 + q];
    float4 p4 = *(const float4*)(opart + (size_t)(pb + s) * 8192 + q * 32 + g * 4);
    o4.x += p4.x;
    o4.y += p4.y;
    o4.z += p4.z;
    o4.w += p4.w;
  }
  float inv = 1.f / L;
  size_t orow = (size_t)(b * 256 + q);
  float4 res = make_float4(o4.x * inv, o4.y * inv, o4.z * inv, o4.w * inv);
  *(float4*)(O + orow * WD + h * 32 + g * 4) = res;
}

}  // namespace

// ---------------------------------------------------------------------------
extern "C" void kernel_launch(void* const* d_in, const int* in_sizes, int n_in,
                              void* d_out, int out_size, void* d_ws,
                              size_t ws_size, hipStream_t stream) {
  const float* pts      = (const float*)d_in[0];
  const float* pe_w     = (const float*)d_in[1];
  const float* pe_b     = (const float*)d_in[2];
  const float* conv1_w  = (const float*)d_in[3];
  const float* conv1_b  = (const float*)d_in[4];
  const float* conv2_w  = (const float*)d_in[5];
  const float* conv2_b  = (const float*)d_in[6];
  const float* otok     = (const float*)d_in[7];
  const float* ln_pre_s = (const float*)d_in[8];
  const float* ln_pre_b = (const float*)d_in[9];
  const float* c_ln1_s  = (const float*)d_in[10];
  const float* c_ln1_b  = (const float*)d_in[11];
  const float* c_ln2_s  = (const float*)d_in[12];
  const float* c_ln2_b  = (const float*)d_in[13];
  const float* c_q_w    = (const float*)d_in[14];
  const float* c_q_b    = (const float*)d_in[15];
  const float* c_kv_w   = (const float*)d_in[16];
  const float* c_kv_b   = (const float*)d_in[17];
  const float* c_proj_w = (const float*)d_in[18];
  const float* c_proj_b = (const float*)d_in[19];
  const float* c_ln3_s  = (const float*)d_in[20];
  const float* c_ln3_b  = (const float*)d_in[21];
  const float* c_mlp1_w = (const float*)d_in[22];
  const float* c_mlp1_b = (const float*)d_in[23];
  const float* c_mlp2_w = (const float*)d_in[24];
  const float* c_mlp2_b = (const float*)d_in[25];
  const float* s_ln1_s  = (const float*)d_in[26];
  const float* s_ln1_b  = (const float*)d_in[27];
  const float* s_qkv_w  = (const float*)d_in[28];
  const float* s_qkv_b  = (const float*)d_in[29];
  const float* s_proj_w = (const float*)d_in[30];
  const float* s_proj_b = (const float*)d_in[31];
  const float* s_ln2_s  = (const float*)d_in[32];
  const float* s_ln2_b  = (const float*)d_in[33];
  const float* s_mlp1_w = (const float*)d_in[34];
  const float* s_mlp1_b = (const float*)d_in[35];
  const float* s_mlp2_w = (const float*)d_in[36];
  const float* s_mlp2_b = (const float*)d_in[37];
  const float* lnpost_s = (const float*)d_in[38];
  const float* lnpost_b = (const float*)d_in[39];
  const float* out_w    = (const float*)d_in[40];
  const float* out_b    = (const float*)d_in[41];

  char* ws = (char*)d_ws;
  constexpr size_t SZ_EMB = (size_t)65536 * 128 * 4;  // 32 MB
  float* emb  = (float*)(ws);
  float* kbuf = (float*)(ws + SZ_EMB);
  float* vbuf = (float*)(ws + 2 * SZ_EMB);
  char*  b3   = ws + 3 * SZ_EMB;
  float* dtok = (float*)(b3);                       //  512 KB
  float* hbuf = (float*)(b3 + 524288);              // 1 MB
  float* qbuf = (float*)(b3 + 524288 + 1048576);    // 1 MB
  float* att  = (float*)(b3 + 524288 + 2097152);    // 1 MB
  float* mid  = (float*)(b3 + 524288 + 3145728);    // 4 MB
  float* qkv  = (float*)(b3 + 524288 + 7340032);    // 3 MB
  unsigned short* arena = (unsigned short*)(b3 + 524288 + 10485760);
  // attention partials overlay the emb region (emb dead after gconv/kvln):
  float* opart = (float*)(ws);
  float* lbuf  = (float*)(ws + 24 * 1024 * 1024);

  const int IDK = 1 << 28;

  // 1) weight prep (all bf16) + dataset_emb
  k_prep<<<(int)((AO_TOT + 255) / 256), 256, 0, stream>>>(
      c_q_w, c_kv_w, c_proj_w, c_mlp1_w, c_mlp2_w, s_qkv_w, s_proj_w,
      s_mlp1_w, s_mlp2_w, out_w, conv1_w, conv2_w, arena);
  k_posenc<<<2048, 256, 0, stream>>>(pts, pe_w, pe_b, emb);
  // 2) K,V from dataset_emb (bf16 MFMA LN-GEMM)
  k_lngemm<<<dim3(2048, 2), 256, 0, stream>>>(emb, 128, arena + AO_WKV,
                                              c_kv_b, kbuf, vbuf, 128,
                                              c_ln2_s, c_ln2_b);
  // 3) ballquery + gather + MFMA conv stack [last reader of emb]
  k_gconv_mfma<<<512, 256, 0, stream>>>(pts, emb, arena + AO_W1B, conv1_b,
                                        arena + AO_W2B, conv2_b, dtok);
  // 4) concat + ln_pre -> h
  k_concat_ln<<<2048, 64, 0, stream>>>(dtok, otok, ln_pre_s, ln_pre_b, hbuf);
  // 5) cross attention block
  k_bgemm<<<dim3(64, 1), 256, 0, stream>>>(hbuf, 128, arena + AO_WQ, c_q_b,
                                           nullptr, 0, qbuf, 128, 128, 0,
                                           c_ln1_s, c_ln1_b, IDK, 0);
  k_attn_mfma<<<512, 256, 0, stream>>>(qbuf, 128, kbuf, 128, vbuf, 128, opart,
                                       lbuf, 8192, 16, 512);
  k_attn_comb<<<256, 256, 0, stream>>>(opart, lbuf, att, 16);
  k_bgemm<<<dim3(64, 1), 256, 0, stream>>>(att, 128, arena + AO_WPROJC,
                                           c_proj_b, hbuf, 128, hbuf, 128,
                                           128, 0, nullptr, nullptr, IDK, 0);
  k_bgemm<<<dim3(64, 4), 256, 0, stream>>>(hbuf, 128, arena + AO_WMLP1C,
                                           c_mlp1_b, nullptr, 0, mid, 512,
                                           128, 1, c_ln3_s, c_ln3_b, IDK, 0);
  k_bgemm<<<dim3(64, 1), 256, 0, stream>>>(mid, 512, arena + AO_WMLP2C,
                                           c_mlp2_b, hbuf, 128, hbuf, 128,
                                           512, 0, nullptr, nullptr, IDK, 0);
  // 6) self-attention blocks
  for (int i = 0; i < 3; ++i) {
    k_bgemm<<<dim3(64, 3), 256, 0, stream>>>(
        hbuf, 128, arena + AO_WQKVS + (size_t)i * 49152, s_qkv_b + i * 384,
        nullptr, 0, qkv, 384, 128, 0, s_ln1_s + i * 128, s_ln1_b + i * 128,
        IDK, 0);
    k_attn_mfma<<<128, 256, 0, stream>>>(qkv, 384, qkv + 128, 384, qkv + 256,
                                         384, opart, lbuf, 256, 4, 64);
    k_attn_comb<<<256, 256, 0, stream>>>(opart, lbuf, att, 4);
    k_bgemm<<<dim3(64, 1), 256, 0, stream>>>(
        att, 128, arena + AO_WPROJS + (size_t)i * 16384, s_proj_b + i * 128,
        hbuf, 128, hbuf, 128, 128, 0, nullptr, nullptr, IDK, 0);
    k_bgemm<<<dim3(64, 4), 256, 0, stream>>>(
        hbuf, 128, arena + AO_WMLP1S + (size_t)i * 65536, s_mlp1_b + i * 512,
        nullptr, 0, mid, 512, 128, 1, s_ln2_s + i * 128, s_ln2_b + i * 128,
        IDK, 0);
    k_bgemm<<<dim3(64, 1), 256, 0, stream>>>(
        mid, 512, arena + AO_WMLP2S + (size_t)i * 65536, s_mlp2_b + i * 128,
        hbuf, 128, hbuf, 128, 512, 0, nullptr, nullptr, IDK, 0);
  }
  // 7) final LN (last 128 tokens per batch) + output head with tanh
  k_bgemm<<<dim3(32, 1), 256, 0, stream>>>(hbuf, 128, arena + AO_WOUT, out_b,
                                           nullptr, 0, (float*)d_out, 128,
                                           128, 2, lnpost_s, lnpost_b, 128,
                                           128);
}

// Round 7
// 323.361 us; speedup vs baseline: 5.0010x; 1.1327x over previous
//
#include <hip/hip_runtime.h>
#include <math.h>

// ---------------------------------------------------------------------------
// PointCloudPerceiverChannelsEncoder — round 6: de-VALU'd attention.
//  - K/V buffers bf16 (no cvt in attn; K fragments direct from L2, no LDS)
//  - __expf (v_exp_f32) for softmax/silu
//  - row-sum l via MFMA ones-fragment (replaces shfl reduce)
//  - P LDS buffer in bf16 (half LDS, conflict-light)
//  - cross split S=32 (4 blocks/CU)
// ---------------------------------------------------------------------------

namespace {

constexpr int NP = 8192;
constexpr int WD = 128;
constexpr int POSD = 62;
constexpr float R2C = 0.04f;
constexpr float QSCALE = 0.17677669529663687f;    // 1/sqrt(32)
constexpr float HALFPI = 1.5707963705062866f;

typedef __bf16 bf16x8 __attribute__((ext_vector_type(8)));
typedef float f32x4 __attribute__((ext_vector_type(4)));
union U16B { uint4 u; bf16x8 h; unsigned short s[8]; };

// bf16 weight arena element offsets (ushort units)
constexpr size_t AO_WQ     = 0;        // [128][128]
constexpr size_t AO_WKV    = 16384;    // [256][128]
constexpr size_t AO_WPROJC = 49152;    // [128][128]
constexpr size_t AO_WMLP1C = 65536;    // [512][128]
constexpr size_t AO_WMLP2C = 131072;   // [128][512]
constexpr size_t AO_WQKVS  = 196608;   // 3 x [384][128]
constexpr size_t AO_WPROJS = 344064;   // 3 x [128][128]
constexpr size_t AO_WMLP1S = 393216;   // 3 x [512][128]
constexpr size_t AO_WMLP2S = 589824;   // 3 x [128][512]
constexpr size_t AO_WOUT   = 786432;   // [128][128]
constexpr size_t AO_W1B    = 802816;   // [128][1056] (1040 + zero pad)
constexpr size_t AO_W2B    = 937984;   // [128][1024]
constexpr size_t AO_TOT    = 1069056;

// ---------------- posenc + pe GEMM: emb[65536][128] -------------------------
__global__ __launch_bounds__(256) void k_posenc(
    const float* __restrict__ pts, const float* __restrict__ pew,
    const float* __restrict__ peb, float* __restrict__ emb) {
  __shared__ float posT[62][36];
  const int tid = threadIdx.x;
  const int base = blockIdx.x * 32;
  for (int i = tid; i < 32 * POSD; i += 256) {
    int p = i / POSD, j = i % POSD;
    const float* pp = pts + (size_t)(base + p) * 2;
    float v;
    if (j < 2) {
      v = pp[j];
    } else if (j < 32) {
      int t = j - 2;
      v = sinf(pp[t & 1] * (float)(1 << (t >> 1)));
    } else {
      int t = j - 32;
      v = sinf(pp[t & 1] * (float)(1 << (t >> 1)) + HALFPI);
    }
    posT[j][p] = v;
  }
  __syncthreads();
  const int c = tid & 127, pg = tid >> 7;
  float acc[16];
  const float bias = peb[c];
#pragma unroll
  for (int k = 0; k < 16; ++k) acc[k] = bias;
  for (int j = 0; j < POSD; ++j) {
    float w = pew[j * WD + c];
    const float4 p0 = *(const float4*)&posT[j][pg * 16];
    const float4 p1 = *(const float4*)&posT[j][pg * 16 + 4];
    const float4 p2 = *(const float4*)&posT[j][pg * 16 + 8];
    const float4 p3 = *(const float4*)&posT[j][pg * 16 + 12];
    acc[0] += p0.x * w;  acc[1] += p0.y * w;
    acc[2] += p0.z * w;  acc[3] += p0.w * w;
    acc[4] += p1.x * w;  acc[5] += p1.y * w;
    acc[6] += p1.z * w;  acc[7] += p1.w * w;
    acc[8] += p2.x * w;  acc[9] += p2.y * w;
    acc[10] += p2.z * w; acc[11] += p2.w * w;
    acc[12] += p3.x * w; acc[13] += p3.y * w;
    acc[14] += p3.z * w; acc[15] += p3.w * w;
  }
#pragma unroll
  for (int k = 0; k < 16; ++k)
    emb[(size_t)(base + pg * 16 + k) * WD + c] = acc[k];
}

// ---------------- mega-prep: all weights -> bf16 arena ----------------------
__global__ __launch_bounds__(256) void k_prep(
    const float* __restrict__ wq, const float* __restrict__ wkv,
    const float* __restrict__ wprojc, const float* __restrict__ wmlp1c,
    const float* __restrict__ wmlp2c, const float* __restrict__ wqkvs,
    const float* __restrict__ wprojs, const float* __restrict__ wmlp1s,
    const float* __restrict__ wmlp2s, const float* __restrict__ wout,
    const float* __restrict__ w1, const float* __restrict__ w2,
    unsigned short* __restrict__ dst) {
  const size_t i = (size_t)blockIdx.x * 256 + threadIdx.x;
  if (i >= AO_TOT) return;
  float v;
  if (i < AO_WKV) {
    size_t j = i;            v = wq[(j & 127) * 128 + (j >> 7)];
  } else if (i < AO_WPROJC) {
    size_t j = i - AO_WKV;   v = wkv[(j & 127) * 256 + (j >> 7)];
  } else if (i < AO_WMLP1C) {
    size_t j = i - AO_WPROJC; v = wprojc[(j & 127) * 128 + (j >> 7)];
  } else if (i < AO_WMLP2C) {
    size_t j = i - AO_WMLP1C; v = wmlp1c[(j & 127) * 512 + (j >> 7)];
  } else if (i < AO_WQKVS) {
    size_t j = i - AO_WMLP2C; v = wmlp2c[(j & 511) * 128 + (j >> 9)];
  } else if (i < AO_WPROJS) {
    size_t j = i - AO_WQKVS;
    size_t L = j / 49152, jj = j % 49152;
    v = wqkvs[L * 49152 + (jj & 127) * 384 + (jj >> 7)];
  } else if (i < AO_WMLP1S) {
    size_t j = i - AO_WPROJS;
    size_t L = j / 16384, jj = j % 16384;
    v = wprojs[L * 16384 + (jj & 127) * 128 + (jj >> 7)];
  } else if (i < AO_WMLP2S) {
    size_t j = i - AO_WMLP1S;
    size_t L = j / 65536, jj = j % 65536;
    v = wmlp1s[L * 65536 + (jj & 127) * 512 + (jj >> 7)];
  } else if (i < AO_WOUT) {
    size_t j = i - AO_WMLP2S;
    size_t L = j / 65536, jj = j % 65536;
    v = wmlp2s[L * 65536 + (jj & 511) * 128 + (jj >> 9)];
  } else if (i < AO_W1B) {
    size_t j = i - AO_WOUT;  v = wout[(j & 127) * 128 + (j >> 7)];
  } else if (i < AO_W2B) {
    size_t j = i - AO_W1B;
    size_t c = j / 1056, k = j % 1056;
    v = (k < 1040) ? w1[c * 1040 + k] : 0.f;
  } else {
    size_t j = i - AO_W2B;   v = w2[(j >> 10) * 1024 + (j & 1023)];
  }
  __bf16 bv = (__bf16)v;
  dst[i] = *(unsigned short*)&bv;
}

// ---------------- gconv via MFMA (ballquery fused), 2 points/block ----------
__global__ __launch_bounds__(256) void k_gconv_mfma(
    const float* __restrict__ pts, const float* __restrict__ emb,
    const unsigned short* __restrict__ w1b, const float* __restrict__ b1,
    const unsigned short* __restrict__ w2b, const float* __restrict__ b2,
    float* __restrict__ dtok) {
  const int blk = blockIdx.x;          // b*64 + ip
  const int b = blk >> 6;
  const int i0 = (blk & 63) * 2;
  const int tid = threadIdx.x;
  const int w = tid >> 6, lane = tid & 63;
  const int l15 = lane & 15, l16 = lane >> 4;
  __shared__ __align__(16) char raw[42240];
  __shared__ int sid[2][8];
  float (*ft)[132][8] = (float(*)[132][8])raw;
  unsigned short (*Bt1)[1056] = (unsigned short(*)[1056])(raw + 8448);
  unsigned short (*y1)[128][16] = (unsigned short(*)[128][16])raw;
  unsigned short (*Bt2)[512] = (unsigned short(*)[512])(raw + 8448);

  if (w < 2) {
    const int i = i0 + w;
    const float cx = pts[((size_t)b * NP + i) * 2];
    const float cy = pts[((size_t)b * NP + i) * 2 + 1];
    int cnt = 0;
    for (int j0 = 0; j0 < NP; j0 += 64) {
      int j = j0 + lane;
      float dx = pts[((size_t)b * NP + j) * 2] - cx;
      float dy = pts[((size_t)b * NP + j) * 2 + 1] - cy;
      float d2 = __fadd_rn(__fmul_rn(dx, dx), __fmul_rn(dy, dy));
      bool ok = !(d2 > R2C);
      unsigned long long m = __ballot(ok);
      int ord = cnt + __popcll(m & ((1ull << lane) - 1ull));
      if (ok && ord < 8) sid[w][ord] = j;
      cnt += (int)__popcll(m);
      if (cnt >= 8) break;
    }
    if (lane < 8 && lane >= cnt) sid[w][lane] = sid[w][0];
  }
  __syncthreads();
  for (int it = tid; it < 16 * 128; it += 256) {
    int pr = it >> 7, cc = it & 127;
    int spx = pr >> 3, s = pr & 7;
    ft[spx][2 + cc][s] = emb[((size_t)b * NP + sid[spx][s]) * WD + cc];
  }
  if (tid < 32) {
    int spx = tid >> 4, s = (tid >> 1) & 7, d = tid & 1;
    ft[spx][d][s] = pts[((size_t)b * NP + sid[spx][s]) * 2 + d] -
                    pts[((size_t)b * NP + i0 + spx) * 2 + d];
  }
  __syncthreads();
  {
    const int n = tid >> 4, g = tid & 15;
    const int pt = n >> 3, h = n & 7;
#pragma unroll
    for (int it = 0; it < 9; ++it) {
      int cin = g + it * 16;
      if (cin < 130) {
        const float4 f03 = *(const float4*)&ft[pt][cin][0];
        const float4 f47 = *(const float4*)&ft[pt][cin][4];
        const float fr[8] = {f03.x, f03.y, f03.z, f03.w,
                             f47.x, f47.y, f47.z, f47.w};
        U16B u;
#pragma unroll
        for (int p = 0; p < 8; ++p) u.h[p] = (__bf16)fr[(h + p + 4) & 7];
        *(uint4*)&Bt1[n][cin * 8] = u.u;
      } else if (cin < 132) {
        uint4 z; z.x = z.y = z.z = z.w = 0;
        *(uint4*)&Bt1[n][cin * 8] = z;
      }
    }
  }
  __syncthreads();
  f32x4 acc1[2];
  acc1[0] = (f32x4){0.f, 0.f, 0.f, 0.f};
  acc1[1] = (f32x4){0.f, 0.f, 0.f, 0.f};
  {
    const unsigned short* w1r = w1b + (size_t)(w * 32 + l15) * 1056;
#pragma unroll 3
    for (int ks = 0; ks < 33; ++ks) {
      const int k0 = ks * 32 + l16 * 8;
      U16B a0, a1, bb;
      a0.u = *(const uint4*)(w1r + k0);
      a1.u = *(const uint4*)(w1r + 16 * 1056 + k0);
      bb.u = *(const uint4*)&Bt1[l15][k0];
      acc1[0] = __builtin_amdgcn_mfma_f32_16x16x32_bf16(a0.h, bb.h, acc1[0],
                                                        0, 0, 0);
      acc1[1] = __builtin_amdgcn_mfma_f32_16x16x32_bf16(a1.h, bb.h, acc1[1],
                                                        0, 0, 0);
    }
  }
  __syncthreads();
  {
    const int pt = l15 >> 3, h = l15 & 7;
#pragma unroll
    for (int t = 0; t < 2; ++t)
#pragma unroll
      for (int r = 0; r < 4; ++r) {
        int c = w * 32 + t * 16 + l16 * 4 + r;
        float x = acc1[t][r] + b1[c];
        float sy = x / (1.f + __expf(-x));
        __bf16 bh = (__bf16)sy;
        unsigned short bits = *(unsigned short*)&bh;
        y1[pt][c][h] = bits;
        if (h == 0) y1[pt][c][8] = bits;
      }
  }
  f32x4 acc2[2][2];
#pragma unroll
  for (int t = 0; t < 2; ++t)
#pragma unroll
    for (int nt = 0; nt < 2; ++nt) acc2[t][nt] = (f32x4){0.f, 0.f, 0.f, 0.f};
  for (int hf = 0; hf < 2; ++hf) {
    __syncthreads();
    {
      const int n2 = tid >> 3, g = tid & 7;
      const int pt = n2 / 9, h2 = n2 % 9;
#pragma unroll
      for (int it = 0; it < 8; ++it) {
        int c1loc = g + it * 8;
        if (n2 < 18) {
          int c1 = hf * 64 + c1loc;
          U16B u0, u1;
          u0.u = *(const uint4*)&y1[pt][c1][0];
          u1.u = *(const uint4*)&y1[pt][c1][8];
          unsigned short yv[9];
#pragma unroll
          for (int j = 0; j < 8; ++j) yv[j] = u0.s[j];
          yv[8] = u1.s[0];
          U16B o;
#pragma unroll
          for (int p = 0; p < 8; ++p) o.s[p] = yv[(h2 + p + 5) % 9];
          *(uint4*)&Bt2[n2][c1loc * 8] = o.u;
        } else {
          uint4 z; z.x = z.y = z.z = z.w = 0;
          *(uint4*)&Bt2[n2][c1loc * 8] = z;
        }
      }
    }
    __syncthreads();
    const unsigned short* w2r = w2b + (size_t)(w * 32 + l15) * 1024 + hf * 512;
#pragma unroll 4
    for (int ks = 0; ks < 16; ++ks) {
      const int k0 = ks * 32 + l16 * 8;
      U16B a0, a1, b0, b1u;
      a0.u = *(const uint4*)(w2r + k0);
      a1.u = *(const uint4*)(w2r + 16 * 1024 + k0);
      b0.u = *(const uint4*)&Bt2[l15][k0];
      b1u.u = *(const uint4*)&Bt2[16 + l15][k0];
      acc2[0][0] = __builtin_amdgcn_mfma_f32_16x16x32_bf16(a0.h, b0.h,
                                                           acc2[0][0], 0, 0, 0);
      acc2[0][1] = __builtin_amdgcn_mfma_f32_16x16x32_bf16(a0.h, b1u.h,
                                                           acc2[0][1], 0, 0, 0);
      acc2[1][0] = __builtin_amdgcn_mfma_f32_16x16x32_bf16(a1.h, b0.h,
                                                           acc2[1][0], 0, 0, 0);
      acc2[1][1] = __builtin_amdgcn_mfma_f32_16x16x32_bf16(a1.h, b1u.h,
                                                           acc2[1][1], 0, 0, 0);
    }
  }
  float s0[2][4], s1[2][4];
#pragma unroll
  for (int t = 0; t < 2; ++t)
#pragma unroll
    for (int r = 0; r < 4; ++r) { s0[t][r] = 0.f; s1[t][r] = 0.f; }
#pragma unroll
  for (int t = 0; t < 2; ++t)
#pragma unroll
    for (int nt = 0; nt < 2; ++nt) {
      const int n2 = nt * 16 + l15;
      if (n2 < 18) {
        const float wgt = (n2 % 9 == 0) ? 2.f : 1.f;
#pragma unroll
        for (int r = 0; r < 4; ++r) {
          int c = w * 32 + t * 16 + l16 * 4 + r;
          float x = acc2[t][nt][r] + b2[c];
          float sv = wgt * (x / (1.f + __expf(-x)));
          if (n2 < 9) s0[t][r] += sv; else s1[t][r] += sv;
        }
      }
    }
#pragma unroll
  for (int t = 0; t < 2; ++t)
#pragma unroll
    for (int r = 0; r < 4; ++r) {
      float a = s0[t][r], bq = s1[t][r];
      a += __shfl_xor(a, 1);  bq += __shfl_xor(bq, 1);
      a += __shfl_xor(a, 2);  bq += __shfl_xor(bq, 2);
      a += __shfl_xor(a, 4);  bq += __shfl_xor(bq, 4);
      a += __shfl_xor(a, 8);  bq += __shfl_xor(bq, 8);
      if (l15 == 0) {
        int c = w * 32 + t * 16 + l16 * 4 + r;
        dtok[((size_t)b * 128 + i0) * WD + c] = a / 10.0f;
        dtok[((size_t)b * 128 + i0 + 1) * WD + c] = bq / 10.0f;
      }
    }
}

// ---------------- concat(data_tokens, latents) + ln_pre -> h ---------------
__global__ __launch_bounds__(64) void k_concat_ln(
    const float* __restrict__ dtok, const float* __restrict__ otok,
    const float* __restrict__ g, const float* __restrict__ bta,
    float* __restrict__ h0) {
  const int row = blockIdx.x;
  const int b = row >> 8, t = row & 255;
  const int lane = threadIdx.x;
  const float* src = (t < 128) ? (dtok + ((size_t)b * 128 + t) * WD)
                               : (otok + (size_t)(t - 128) * WD);
  const float2 x2 = *(const float2*)(src + lane * 2);
  float s = x2.x + x2.y;
  float sq = x2.x * x2.x + x2.y * x2.y;
#pragma unroll
  for (int o = 1; o < 64; o <<= 1) {
    s += __shfl_xor(s, o);
    sq += __shfl_xor(sq, o);
  }
  float m = s * (1.f / 128.f);
  float var = fmaxf(sq * (1.f / 128.f) - m * m, 0.f);
  float r = 1.0f / sqrtf(var + 1e-5f);
  int c = lane * 2;
  float2 o2;
  o2.x = (x2.x - m) * r * g[c] + bta[c];
  o2.y = (x2.y - m) * r * g[c + 1] + bta[c + 1];
  *(float2*)(h0 + (size_t)row * WD + c) = o2;
}

// ---------------- bf16 MFMA LN-GEMM for KV: bf16 outputs -------------------
// grid (M/32, 2). nblk 0 -> K, 1 -> V. Output [row][128] bf16.
__global__ __launch_bounds__(256) void k_lngemm(
    const float* __restrict__ A, int lda, const unsigned short* __restrict__ wt,
    const float* __restrict__ bias, unsigned short* __restrict__ kb,
    unsigned short* __restrict__ vb, const float* __restrict__ lnS,
    const float* __restrict__ lnB) {
  __shared__ unsigned short Ab[32][136];
  __shared__ unsigned short Bt[128][136];
  const int tid = threadIdx.x;
  const int row0 = blockIdx.x * 32;
  const int nblk = blockIdx.y;
  {
    const int n = tid >> 1, hf = tid & 1;
    const unsigned short* src = wt + ((size_t)(nblk * 128 + n) * 128 + hf * 64);
#pragma unroll
    for (int q8 = 0; q8 < 8; ++q8)
      *(uint4*)&Bt[n][hf * 64 + q8 * 8] = *(const uint4*)(src + q8 * 8);
  }
  {
    const int r = tid >> 3, seg = tid & 7;
    const float* ap = A + (size_t)(row0 + r) * lda + seg * 16;
    float4 v0 = *(const float4*)ap;
    float4 v1 = *(const float4*)(ap + 4);
    float4 v2 = *(const float4*)(ap + 8);
    float4 v3 = *(const float4*)(ap + 12);
    float s = v0.x + v0.y + v0.z + v0.w + v1.x + v1.y + v1.z + v1.w +
              v2.x + v2.y + v2.z + v2.w + v3.x + v3.y + v3.z + v3.w;
    float sq = v0.x * v0.x + v0.y * v0.y + v0.z * v0.z + v0.w * v0.w +
               v1.x * v1.x + v1.y * v1.y + v1.z * v1.z + v1.w * v1.w +
               v2.x * v2.x + v2.y * v2.y + v2.z * v2.z + v2.w * v2.w +
               v3.x * v3.x + v3.y * v3.y + v3.z * v3.z + v3.w * v3.w;
    s += __shfl_xor(s, 1);  sq += __shfl_xor(sq, 1);
    s += __shfl_xor(s, 2);  sq += __shfl_xor(sq, 2);
    s += __shfl_xor(s, 4);  sq += __shfl_xor(sq, 4);
    const float m = s * (1.f / 128.f);
    const float var = fmaxf(sq * (1.f / 128.f) - m * m, 0.f);
    const float rinv = 1.0f / sqrtf(var + 1e-5f);
    float xv[16] = {v0.x, v0.y, v0.z, v0.w, v1.x, v1.y, v1.z, v1.w,
                    v2.x, v2.y, v2.z, v2.w, v3.x, v3.y, v3.z, v3.w};
    U16B u0, u1;
#pragma unroll
    for (int j = 0; j < 16; ++j) {
      int col = seg * 16 + j;
      float y = (xv[j] - m) * rinv * lnS[col] + lnB[col];
      if (j < 8) u0.h[j] = (__bf16)y; else u1.h[j - 8] = (__bf16)y;
    }
    *(uint4*)&Ab[r][seg * 16] = u0.u;
    *(uint4*)&Ab[r][seg * 16 + 8] = u1.u;
  }
  __syncthreads();
  const int w = tid >> 6, lane = tid & 63;
  const int l15 = lane & 15, l16 = lane >> 4;
  const int rt = w >> 1, ch = w & 1;
  f32x4 acc[4];
#pragma unroll
  for (int j = 0; j < 4; ++j) acc[j] = (f32x4){0.f, 0.f, 0.f, 0.f};
#pragma unroll
  for (int kk = 0; kk < 4; ++kk) {
    U16B ua;
    ua.u = *(const uint4*)&Ab[rt * 16 + l15][kk * 32 + l16 * 8];
#pragma unroll
    for (int ct4 = 0; ct4 < 4; ++ct4) {
      U16B ub;
      ub.u = *(const uint4*)&Bt[(ch * 4 + ct4) * 16 + l15][kk * 32 + l16 * 8];
      acc[ct4] = __builtin_amdgcn_mfma_f32_16x16x32_bf16(ua.h, ub.h, acc[ct4],
                                                         0, 0, 0);
    }
  }
  unsigned short* Dp = (nblk == 1) ? vb : kb;
#pragma unroll
  for (int ct4 = 0; ct4 < 4; ++ct4) {
    int colL = (ch * 4 + ct4) * 16 + l15;
    float bv = bias[nblk * 128 + colL];
#pragma unroll
    for (int r = 0; r < 4; ++r) {
      int row = row0 + rt * 16 + l16 * 4 + r;
      __bf16 ov = (__bf16)(acc[ct4][r] + bv);
      Dp[(size_t)row * 128 + colL] = *(unsigned short*)&ov;
    }
  }
}

// ---------------- universal bf16 MFMA GEMM (f32 in/out) --------------------
__global__ __launch_bounds__(256) void k_bgemm(
    const float* __restrict__ A, int lda, const unsigned short* __restrict__ wt,
    const float* __restrict__ bias, const float* __restrict__ res, int ldres,
    float* __restrict__ D, int ldd, int K, int act,
    const float* __restrict__ lnS, const float* __restrict__ lnB, int keep,
    int skip) {
  __shared__ unsigned short Ab[32][136];
  __shared__ unsigned short Bt[128][136];
  const int tid = threadIdx.x;
  const int row0 = blockIdx.x * 32;
  const int col0 = blockIdx.y * 128;
  const int w = tid >> 6, lane = tid & 63;
  const int l15 = lane & 15, l16 = lane >> 4;
  const int rt = w >> 1, ch = w & 1;
  f32x4 acc[4];
#pragma unroll
  for (int j = 0; j < 4; ++j) acc[j] = (f32x4){0.f, 0.f, 0.f, 0.f};
  for (int kt = 0; kt < K; kt += 128) {
    if (kt) __syncthreads();
    {
      const int n = tid >> 1, hf = tid & 1;
      const unsigned short* src = wt + (size_t)(col0 + n) * K + kt + hf * 64;
#pragma unroll
      for (int q8 = 0; q8 < 8; ++q8)
        *(uint4*)&Bt[n][hf * 64 + q8 * 8] = *(const uint4*)(src + q8 * 8);
    }
    {
      const int r = tid >> 3, seg = tid & 7;
      const int grow = row0 + r;
      const int srow = (grow / keep) * (keep + skip) + skip + grow % keep;
      const float* ap = A + (size_t)srow * lda + kt + seg * 16;
      float4 v0 = *(const float4*)ap;
      float4 v1 = *(const float4*)(ap + 4);
      float4 v2 = *(const float4*)(ap + 8);
      float4 v3 = *(const float4*)(ap + 12);
      float xv[16] = {v0.x, v0.y, v0.z, v0.w, v1.x, v1.y, v1.z, v1.w,
                      v2.x, v2.y, v2.z, v2.w, v3.x, v3.y, v3.z, v3.w};
      if (lnS != nullptr) {
        float s = 0.f, sq = 0.f;
#pragma unroll
        for (int j = 0; j < 16; ++j) { s += xv[j]; sq += xv[j] * xv[j]; }
        s += __shfl_xor(s, 1);  sq += __shfl_xor(sq, 1);
        s += __shfl_xor(s, 2);  sq += __shfl_xor(sq, 2);
        s += __shfl_xor(s, 4);  sq += __shfl_xor(sq, 4);
        const float m = s * (1.f / 128.f);
        const float var = fmaxf(sq * (1.f / 128.f) - m * m, 0.f);
        const float rinv = 1.0f / sqrtf(var + 1e-5f);
#pragma unroll
        for (int j = 0; j < 16; ++j) {
          int col = seg * 16 + j;
          xv[j] = (xv[j] - m) * rinv * lnS[col] + lnB[col];
        }
      }
      U16B u0, u1;
#pragma unroll
      for (int j = 0; j < 8; ++j) {
        u0.h[j] = (__bf16)xv[j];
        u1.h[j] = (__bf16)xv[8 + j];
      }
      *(uint4*)&Ab[r][seg * 16] = u0.u;
      *(uint4*)&Ab[r][seg * 16 + 8] = u1.u;
    }
    __syncthreads();
#pragma unroll
    for (int kk = 0; kk < 4; ++kk) {
      U16B ua;
      ua.u = *(const uint4*)&Ab[rt * 16 + l15][kk * 32 + l16 * 8];
#pragma unroll
      for (int ct = 0; ct < 4; ++ct) {
        U16B ub;
        ub.u = *(const uint4*)&Bt[(ch * 4 + ct) * 16 + l15][kk * 32 + l16 * 8];
        acc[ct] = __builtin_amdgcn_mfma_f32_16x16x32_bf16(ua.h, ub.h, acc[ct],
                                                          0, 0, 0);
      }
    }
  }
#pragma unroll
  for (int ct = 0; ct < 4; ++ct) {
    const int colL = (ch * 4 + ct) * 16 + l15;
    const int col = col0 + colL;
    const float bv = bias[col];
#pragma unroll
    for (int r = 0; r < 4; ++r) {
      const int row = row0 + rt * 16 + l16 * 4 + r;
      float x = acc[ct][r] + bv;
      if (act == 1) x = 0.5f * x * (1.0f + erff(x * 0.7071067811865476f));
      else if (act == 2) x = tanhf(x);
      if (res != nullptr) x += res[(size_t)row * ldres + col];
      D[(size_t)row * ldd + col] = x;
    }
  }
}

// ---------------- MFMA bf16 flash attention (maxless), split-K -------------
// KVB=1: K,V are bf16 [Tk][128]; K fragments direct from global (no LDS).
// KVB=0: K,V f32, strided (self-attn path).
template <int KVB>
__global__ __launch_bounds__(256) void k_attn_mfma(
    const float* __restrict__ Q, int qs, const void* __restrict__ Kp, int ks,
    const void* __restrict__ Vp, int vs, float* __restrict__ opart,
    float* __restrict__ lbuf, int Tk, int S, int CH) {
  const int bx = blockIdx.x;
  const int s = bx % S;
  const int bh = bx / S;
  const int h = bh & 3, b = bh >> 2;
  const int tid = threadIdx.x;
  const int w = tid >> 6, lane = tid & 63;
  const int l15 = lane & 15, l16 = lane >> 4;

  __shared__ unsigned short Kb[64 * 32];          // only used by KVB=0
  __shared__ unsigned short Vt[32 * 68];          // V^T bf16
  __shared__ unsigned short Pl[4][16 * 72];       // per-wave P bf16

  bf16x8 qf[4];
#pragma unroll
  for (int m = 0; m < 4; ++m) {
    const float* qp = Q + (size_t)(b * 256 + w * 64 + m * 16 + l15) * qs +
                      h * 32 + l16 * 8;
    float4 a = *(const float4*)qp;
    float4 bq = *(const float4*)(qp + 4);
    U16B u;
    u.h[0] = (__bf16)(a.x * QSCALE);
    u.h[1] = (__bf16)(a.y * QSCALE);
    u.h[2] = (__bf16)(a.z * QSCALE);
    u.h[3] = (__bf16)(a.w * QSCALE);
    u.h[4] = (__bf16)(bq.x * QSCALE);
    u.h[5] = (__bf16)(bq.y * QSCALE);
    u.h[6] = (__bf16)(bq.z * QSCALE);
    u.h[7] = (__bf16)(bq.w * QSCALE);
    qf[m] = u.h;
  }
  U16B uones;
#pragma unroll
  for (int j = 0; j < 8; ++j) uones.h[j] = (__bf16)1.0f;
  const bf16x8 ones = uones.h;

  f32x4 o[4][2];
#pragma unroll
  for (int m = 0; m < 4; ++m)
#pragma unroll
    for (int d = 0; d < 2; ++d) o[m][d] = (f32x4){0.f, 0.f, 0.f, 0.f};
  f32x4 lsum[4];
#pragma unroll
  for (int m = 0; m < 4; ++m) lsum[4 - 4 + m] = (f32x4){0.f, 0.f, 0.f, 0.f};

  const int kt0 = s * CH;
  for (int kt = kt0; kt < kt0 + CH; kt += 64) {
    __syncthreads();
    if (KVB) {
      // stage V only (bf16 row-major -> transposed LDS)
      const int r = tid >> 2, c0 = (tid & 3) * 8;
      const unsigned short* vp =
          (const unsigned short*)Vp + (size_t)(b * Tk + kt + r) * vs + h * 32 + c0;
      U16B uv;
      uv.u = *(const uint4*)vp;
#pragma unroll
      for (int j = 0; j < 8; ++j) Vt[(c0 + j) * 68 + r] = uv.s[j];
    } else {
      const int r = tid >> 2, c0 = (tid & 3) * 8;
      const float* kp = (const float*)Kp + (size_t)(b * Tk + kt + r) * ks +
                        h * 32 + c0;
      float4 a = *(const float4*)kp;
      float4 bb = *(const float4*)(kp + 4);
      U16B uk;
      uk.h[0] = (__bf16)a.x;  uk.h[1] = (__bf16)a.y;
      uk.h[2] = (__bf16)a.z;  uk.h[3] = (__bf16)a.w;
      uk.h[4] = (__bf16)bb.x; uk.h[5] = (__bf16)bb.y;
      uk.h[6] = (__bf16)bb.z; uk.h[7] = (__bf16)bb.w;
      *(uint4*)&Kb[r * 32 + c0] = uk.u;
      const float* vp = (const float*)Vp + (size_t)(b * Tk + kt + r) * vs +
                        h * 32 + c0;
      float4 va = *(const float4*)vp;
      float4 vb = *(const float4*)(vp + 4);
      U16B uv;
      uv.h[0] = (__bf16)va.x; uv.h[1] = (__bf16)va.y;
      uv.h[2] = (__bf16)va.z; uv.h[3] = (__bf16)va.w;
      uv.h[4] = (__bf16)vb.x; uv.h[5] = (__bf16)vb.y;
      uv.h[6] = (__bf16)vb.z; uv.h[7] = (__bf16)vb.w;
#pragma unroll
      for (int j = 0; j < 8; ++j) Vt[(c0 + j) * 68 + r] = uv.s[j];
    }
    __syncthreads();

    bf16x8 kf[4];
#pragma unroll
    for (int ksb = 0; ksb < 4; ++ksb) {
      U16B u;
      if (KVB) {
        u.u = *(const uint4*)((const unsigned short*)Kp +
                              (size_t)(b * Tk + kt + ksb * 16 + l15) * ks +
                              h * 32 + l16 * 8);
      } else {
        u.u = *(const uint4*)&Kb[(ksb * 16 + l15) * 32 + l16 * 8];
      }
      kf[ksb] = u.h;
    }
    bf16x8 vf[2][2];
#pragma unroll
    for (int kc = 0; kc < 2; ++kc)
#pragma unroll
      for (int d = 0; d < 2; ++d) {
        const unsigned short* vp =
            &Vt[(l15 + 16 * d) * 68 + kc * 32 + l16 * 8];
        U16B u;
        *(uint2*)&u.s[0] = *(const uint2*)vp;
        *(uint2*)&u.s[4] = *(const uint2*)(vp + 4);
        vf[kc][d] = u.h;
      }

#pragma unroll
    for (int m = 0; m < 4; ++m) {
      const f32x4 zf = {0.f, 0.f, 0.f, 0.f};
      f32x4 sf[4];
#pragma unroll
      for (int ksb = 0; ksb < 4; ++ksb)
        sf[ksb] = __builtin_amdgcn_mfma_f32_16x16x32_bf16(qf[m], kf[ksb], zf,
                                                          0, 0, 0);
      // maxless softmax: p = exp(score) in bf16, straight to per-wave LDS
#pragma unroll
      for (int ksb = 0; ksb < 4; ++ksb)
#pragma unroll
        for (int r = 0; r < 4; ++r) {
          float p = __expf(sf[ksb][r]);
          __bf16 pb = (__bf16)p;
          Pl[w][(l16 * 4 + r) * 72 + ksb * 16 + l15] = *(unsigned short*)&pb;
        }
      asm volatile("s_waitcnt lgkmcnt(0)" ::: "memory");
      bf16x8 pa[2];
#pragma unroll
      for (int kc = 0; kc < 2; ++kc) {
        U16B u;
        u.u = *(const uint4*)&Pl[w][l15 * 72 + kc * 32 + l16 * 8];
        pa[kc] = u.h;
      }
      // l row-sum via MFMA with ones-B (replaces shfl reduce)
      lsum[m] = __builtin_amdgcn_mfma_f32_16x16x32_bf16(pa[0], ones, lsum[m],
                                                        0, 0, 0);
      lsum[m] = __builtin_amdgcn_mfma_f32_16x16x32_bf16(pa[1], ones, lsum[m],
                                                        0, 0, 0);
#pragma unroll
      for (int kc = 0; kc < 2; ++kc)
#pragma unroll
        for (int d = 0; d < 2; ++d)
          o[m][d] = __builtin_amdgcn_mfma_f32_16x16x32_bf16(pa[kc], vf[kc][d],
                                                            o[m][d], 0, 0, 0);
    }
  }

  const size_t ob = (size_t)bx * 8192;
#pragma unroll
  for (int m = 0; m < 4; ++m) {
    int qrow = w * 64 + m * 16 + l16 * 4;
#pragma unroll
    for (int r = 0; r < 4; ++r) {
#pragma unroll
      for (int d = 0; d < 2; ++d)
        opart[ob + (qrow + r) * 32 + d * 16 + l15] = o[m][d][r];
      if (l15 == 0) lbuf[(size_t)bx * 256 + qrow + r] = lsum[m][r];
    }
  }
}

// ---------------- combine S partials -> O ----------------------------------
__global__ __launch_bounds__(256) void k_attn_comb(
    const float* __restrict__ opart, const float* __restrict__ lbuf,
    float* __restrict__ O, int S) {
  const int bx = blockIdx.x;
  const int qt = bx & 7, h = (bx >> 3) & 3, b = bx >> 5;
  const int tid = threadIdx.x;
  const int qq = tid >> 3, g = tid & 7;
  const int q = qt * 32 + qq;
  const int pb = (b * 4 + h) * S;
  float L = 0.f;
  float4 o4 = make_float4(0.f, 0.f, 0.f, 0.f);
  for (int s = 0; s < S; ++s) {
    L += lbuf[(size_t)(pb + s) * 256 + q];
    float4 p4 = *(const float4*)(opart + (size_t)(pb + s) * 8192 + q * 32 + g * 4);
    o4.x += p4.x;
    o4.y += p4.y;
    o4.z += p4.z;
    o4.w += p4.w;
  }
  float inv = 1.f / L;
  size_t orow = (size_t)(b * 256 + q);
  float4 res = make_float4(o4.x * inv, o4.y * inv, o4.z * inv, o4.w * inv);
  *(float4*)(O + orow * WD + h * 32 + g * 4) = res;
}

}  // namespace

// ---------------------------------------------------------------------------
extern "C" void kernel_launch(void* const* d_in, const int* in_sizes, int n_in,
                              void* d_out, int out_size, void* d_ws,
                              size_t ws_size, hipStream_t stream) {
  const float* pts      = (const float*)d_in[0];
  const float* pe_w     = (const float*)d_in[1];
  const float* pe_b     = (const float*)d_in[2];
  const float* conv1_w  = (const float*)d_in[3];
  const float* conv1_b  = (const float*)d_in[4];
  const float* conv2_w  = (const float*)d_in[5];
  const float* conv2_b  = (const float*)d_in[6];
  const float* otok     = (const float*)d_in[7];
  const float* ln_pre_s = (const float*)d_in[8];
  const float* ln_pre_b = (const float*)d_in[9];
  const float* c_ln1_s  = (const float*)d_in[10];
  const float* c_ln1_b  = (const float*)d_in[11];
  const float* c_ln2_s  = (const float*)d_in[12];
  const float* c_ln2_b  = (const float*)d_in[13];
  const float* c_q_w    = (const float*)d_in[14];
  const float* c_q_b    = (const float*)d_in[15];
  const float* c_kv_w   = (const float*)d_in[16];
  const float* c_kv_b   = (const float*)d_in[17];
  const float* c_proj_w = (const float*)d_in[18];
  const float* c_proj_b = (const float*)d_in[19];
  const float* c_ln3_s  = (const float*)d_in[20];
  const float* c_ln3_b  = (const float*)d_in[21];
  const float* c_mlp1_w = (const float*)d_in[22];
  const float* c_mlp1_b = (const float*)d_in[23];
  const float* c_mlp2_w = (const float*)d_in[24];
  const float* c_mlp2_b = (const float*)d_in[25];
  const float* s_ln1_s  = (const float*)d_in[26];
  const float* s_ln1_b  = (const float*)d_in[27];
  const float* s_qkv_w  = (const float*)d_in[28];
  const float* s_qkv_b  = (const float*)d_in[29];
  const float* s_proj_w = (const float*)d_in[30];
  const float* s_proj_b = (const float*)d_in[31];
  const float* s_ln2_s  = (const float*)d_in[32];
  const float* s_ln2_b  = (const float*)d_in[33];
  const float* s_mlp1_w = (const float*)d_in[34];
  const float* s_mlp1_b = (const float*)d_in[35];
  const float* s_mlp2_w = (const float*)d_in[36];
  const float* s_mlp2_b = (const float*)d_in[37];
  const float* lnpost_s = (const float*)d_in[38];
  const float* lnpost_b = (const float*)d_in[39];
  const float* out_w    = (const float*)d_in[40];
  const float* out_b    = (const float*)d_in[41];

  char* ws = (char*)d_ws;
  constexpr size_t MB = 1024 * 1024;
  float* emb  = (float*)(ws);                        // [0, 32MB)
  unsigned short* kbuf = (unsigned short*)(ws + 32 * MB);   // 16 MB bf16
  unsigned short* vbuf = (unsigned short*)(ws + 48 * MB);   // 16 MB bf16
  char*  b3   = ws + 64 * MB;
  float* dtok = (float*)(b3);                        //  512 KB
  float* hbuf = (float*)(b3 + 524288);               // 1 MB
  float* qbuf = (float*)(b3 + 524288 + 1048576);     // 1 MB
  float* att  = (float*)(b3 + 524288 + 2097152);     // 1 MB
  float* mid  = (float*)(b3 + 524288 + 3145728);     // 4 MB
  float* qkv  = (float*)(b3 + 524288 + 7340032);     // 3 MB
  unsigned short* arena = (unsigned short*)(b3 + 524288 + 10485760);  // ~2.1MB
  // attention partials overlay emb (dead after lngemm+gconv): 1024*8192*4=32MB
  float* opart = (float*)(ws);
  float* lbuf  = (float*)(b3 + 16 * MB);             // 1 MB

  const int IDK = 1 << 28;

  // 1) weight prep (all bf16) + dataset_emb
  k_prep<<<(int)((AO_TOT + 255) / 256), 256, 0, stream>>>(
      c_q_w, c_kv_w, c_proj_w, c_mlp1_w, c_mlp2_w, s_qkv_w, s_proj_w,
      s_mlp1_w, s_mlp2_w, out_w, conv1_w, conv2_w, arena);
  k_posenc<<<2048, 256, 0, stream>>>(pts, pe_w, pe_b, emb);
  // 2) K,V (bf16) from dataset_emb
  k_lngemm<<<dim3(2048, 2), 256, 0, stream>>>(emb, 128, arena + AO_WKV,
                                              c_kv_b, kbuf, vbuf, c_ln2_s,
                                              c_ln2_b);
  // 3) ballquery + gather + MFMA conv stack [last reader of emb]
  k_gconv_mfma<<<512, 256, 0, stream>>>(pts, emb, arena + AO_W1B, conv1_b,
                                        arena + AO_W2B, conv2_b, dtok);
  // 4) concat + ln_pre -> h
  k_concat_ln<<<2048, 64, 0, stream>>>(dtok, otok, ln_pre_s, ln_pre_b, hbuf);
  // 5) cross attention block (S=32 chunks of 256 keys)
  k_bgemm<<<dim3(64, 1), 256, 0, stream>>>(hbuf, 128, arena + AO_WQ, c_q_b,
                                           nullptr, 0, qbuf, 128, 128, 0,
                                           c_ln1_s, c_ln1_b, IDK, 0);
  k_attn_mfma<1><<<1024, 256, 0, stream>>>(qbuf, 128, kbuf, 128, vbuf, 128,
                                           opart, lbuf, 8192, 32, 256);
  k_attn_comb<<<256, 256, 0, stream>>>(opart, lbuf, att, 32);
  k_bgemm<<<dim3(64, 1), 256, 0, stream>>>(att, 128, arena + AO_WPROJC,
                                           c_proj_b, hbuf, 128, hbuf, 128,
                                           128, 0, nullptr, nullptr, IDK, 0);
  k_bgemm<<<dim3(64, 4), 256, 0, stream>>>(hbuf, 128, arena + AO_WMLP1C,
                                           c_mlp1_b, nullptr, 0, mid, 512,
                                           128, 1, c_ln3_s, c_ln3_b, IDK, 0);
  k_bgemm<<<dim3(64, 1), 256, 0, stream>>>(mid, 512, arena + AO_WMLP2C,
                                           c_mlp2_b, hbuf, 128, hbuf, 128,
                                           512, 0, nullptr, nullptr, IDK, 0);
  // 6) self-attention blocks (f32 K/V path, S=4 chunks of 64 keys)
  for (int i = 0; i < 3; ++i) {
    k_bgemm<<<dim3(64, 3), 256, 0, stream>>>(
        hbuf, 128, arena + AO_WQKVS + (size_t)i * 49152, s_qkv_b + i * 384,
        nullptr, 0, qkv, 384, 128, 0, s_ln1_s + i * 128, s_ln1_b + i * 128,
        IDK, 0);
    k_attn_mfma<0><<<128, 256, 0, stream>>>(qkv, 384, qkv + 128, 384,
                                            qkv + 256, 384, opart, lbuf, 256,
                                            4, 64);
    k_attn_comb<<<256, 256, 0, stream>>>(opart, lbuf, att, 4);
    k_bgemm<<<dim3(64, 1), 256, 0, stream>>>(
        att, 128, arena + AO_WPROJS + (size_t)i * 16384, s_proj_b + i * 128,
        hbuf, 128, hbuf, 128, 128, 0, nullptr, nullptr, IDK, 0);
    k_bgemm<<<dim3(64, 4), 256, 0, stream>>>(
        hbuf, 128, arena + AO_WMLP1S + (size_t)i * 65536, s_mlp1_b + i * 512,
        nullptr, 0, mid, 512, 128, 1, s_ln2_s + i * 128, s_ln2_b + i * 128,
        IDK, 0);
    k_bgemm<<<dim3(64, 1), 256, 0, stream>>>(
        mid, 512, arena + AO_WMLP2S + (size_t)i * 65536, s_mlp2_b + i * 128,
        hbuf, 128, hbuf, 128, 512, 0, nullptr, nullptr, IDK, 0);
  }
  // 7) final LN (last 128 tokens per batch) + output head with tanh
  k_bgemm<<<dim3(32, 1), 256, 0, stream>>>(hbuf, 128, arena + AO_WOUT, out_b,
                                           nullptr, 0, (float*)d_out, 128,
                                           128, 2, lnpost_s, lnpost_b, 128,
                                           128);
}